// Round 1
// baseline (1169.343 us; speedup 1.0000x reference)
//
#include <hip/hip_runtime.h>
#include <hip/hip_bf16.h>
#include <math.h>

#define SEQL 1024
#define DMODEL 512
#define DI 1024
#define DSTATE 64
#define XDBL_N 160
#define NB 4

// ---------------- generic f32 GEMM: C = act(A @ W^T + bias) ----------------
// A: (M,K) lda given; W: (N,K) row-major; C: (M,N)
// ACT: 0 = none, 1 = softplus
template<int ACT>
__global__ __launch_bounds__(256) void gemm_kernel(
    const float* __restrict__ A, const float* __restrict__ W,
    const float* __restrict__ bias, float* __restrict__ C,
    int M, int N, int K, int lda)
{
    __shared__ float As[16][128];
    __shared__ float Ws[16][128];
    const int tid = threadIdx.x;
    const int bm = blockIdx.y * 128;
    const int bn = blockIdx.x * 128;
    const int tx = tid & 15;
    const int ty = tid >> 4;
    const int lr = tid >> 2;          // 0..63
    const int lc = (tid & 3) << 2;    // 0,4,8,12

    float acc[8][8];
    #pragma unroll
    for (int i = 0; i < 8; ++i)
        #pragma unroll
        for (int j = 0; j < 8; ++j) acc[i][j] = 0.f;

    for (int k0 = 0; k0 < K; k0 += 16) {
        #pragma unroll
        for (int h2 = 0; h2 < 2; ++h2) {
            int r = lr + h2 * 64;
            int gm = bm + r;
            float4 v = make_float4(0.f, 0.f, 0.f, 0.f);
            if (gm < M) v = *(const float4*)(A + (size_t)gm * lda + k0 + lc);
            As[lc + 0][r] = v.x; As[lc + 1][r] = v.y;
            As[lc + 2][r] = v.z; As[lc + 3][r] = v.w;
            int gn = bn + r;
            float4 w = make_float4(0.f, 0.f, 0.f, 0.f);
            if (gn < N) w = *(const float4*)(W + (size_t)gn * K + k0 + lc);
            Ws[lc + 0][r] = w.x; Ws[lc + 1][r] = w.y;
            Ws[lc + 2][r] = w.z; Ws[lc + 3][r] = w.w;
        }
        __syncthreads();
        #pragma unroll
        for (int k = 0; k < 16; ++k) {
            float a[8], b[8];
            *(float4*)&a[0] = *(const float4*)&As[k][ty * 8];
            *(float4*)&a[4] = *(const float4*)&As[k][ty * 8 + 4];
            *(float4*)&b[0] = *(const float4*)&Ws[k][tx * 8];
            *(float4*)&b[4] = *(const float4*)&Ws[k][tx * 8 + 4];
            #pragma unroll
            for (int i = 0; i < 8; ++i)
                #pragma unroll
                for (int j = 0; j < 8; ++j)
                    acc[i][j] = fmaf(a[i], b[j], acc[i][j]);
        }
        __syncthreads();
    }

    #pragma unroll
    for (int i = 0; i < 8; ++i) {
        int gm = bm + ty * 8 + i;
        if (gm >= M) continue;
        #pragma unroll
        for (int j = 0; j < 8; ++j) {
            int gn = bn + tx * 8 + j;
            if (gn >= N) continue;
            float v = acc[i][j];
            if (bias) v += bias[gn];
            if (ACT == 1) v = (v > 20.f) ? v : log1pf(__expf(v));
            C[(size_t)gm * N + gn] = v;
        }
    }
}

// ---------------- reorder: xp(2,S,1024) -> x_both(4,S,512) ----------------
__global__ __launch_bounds__(256) void reorder_kernel(
    const float* __restrict__ xp, float* __restrict__ xboth)
{
    int idx = blockIdx.x * 256 + threadIdx.x;     // over 4*1024*512 = 2^21
    int c  = idx & 511;
    int t  = (idx >> 9) & 1023;
    int b4 = idx >> 19;
    float v;
    if (b4 < 2) v = xp[((size_t)(b4 * SEQL + t)) * DI + c];
    else        v = xp[((size_t)((b4 - 2) * SEQL + (1023 - t))) * DI + 512 + c];
    xboth[idx] = v;
}

// ---------------- depthwise causal conv (k=4) + silu ----------------
__global__ __launch_bounds__(256) void conv_silu_kernel(
    const float* __restrict__ xin, const float* __restrict__ cw,
    const float* __restrict__ cb, float* __restrict__ xc)
{
    int idx = blockIdx.x * 256 + threadIdx.x;     // over 4*1024*1024 = 2^22
    int c = idx & (DI - 1);
    int t = (idx >> 10) & (SEQL - 1);
    int b = idx >> 20;
    float acc = cb[c];
    #pragma unroll
    for (int k = 0; k < 4; ++k) {
        int tt = t - 3 + k;
        if (tt >= 0) acc = fmaf(xin[((size_t)(b * SEQL + tt)) * DI + c], cw[c * 4 + k], acc);
    }
    float s = 1.f / (1.f + __expf(-acc));
    xc[idx] = acc * s;
}

// ---------------- selective scan + fused (y + xc*D)*silu(z) ----------------
// grid 256 blocks x 256 thr. block -> (bb, dblock); wave -> 4 d's; lane=(dd,s4):
// 16 lanes per d, 4 states per lane (s = s4*4+k). yp may alias dtp (wave-local
// read-before-write of each (b,t,d) slot).
__global__ __launch_bounds__(256, 1) void scan_kernel(
    const float* dtp, float* yp,
    const float* __restrict__ xdbl,
    const float* __restrict__ xcp,
    const float* __restrict__ zp,
    const float* __restrict__ A_log,
    const float* __restrict__ Dpar)
{
    const int blk = blockIdx.x;
    const int bb = blk >> 6;
    const int dblock = blk & 63;
    const int wave = threadIdx.x >> 6;
    const int lane = threadIdx.x & 63;
    const int dd = lane >> 4;
    const int s4 = lane & 15;
    const int d = dblock * 16 + wave * 4 + dd;
    const float LOG2E = 1.4426950408889634f;

    float A2[4], h[4];
    #pragma unroll
    for (int k = 0; k < 4; ++k) {
        A2[k] = -__expf(A_log[d * DSTATE + s4 * 4 + k]) * LOG2E;
        h[k] = 0.f;
    }
    const float Dv = Dpar[d];
    const size_t rb = (size_t)bb * SEQL * DI + d;
    const float* Bb = xdbl + (size_t)bb * SEQL * XDBL_N + 32 + s4 * 4;

    float dt0[8], xc0[8], z0[8]; float4 B0[8], C0[8];
    float dt1[8], xc1[8], z1[8]; float4 B1[8], C1[8];

#define LOADC(t0, dt_, xc_, z_, B_, C_)                                \
    { _Pragma("unroll")                                                \
      for (int i = 0; i < 8; ++i) {                                    \
        size_t ro = rb + (size_t)((t0) + i) * DI;                      \
        dt_[i] = dtp[ro];                                              \
        xc_[i] = xcp[ro];                                              \
        z_[i]  = zp[ro];                                               \
        const float* bp = Bb + (size_t)((t0) + i) * XDBL_N;            \
        B_[i] = *(const float4*)bp;                                    \
        C_[i] = *(const float4*)(bp + 64);                             \
      } }

#define COMPC(t0, dt_, xc_, z_, B_, C_)                                \
    { _Pragma("unroll")                                                \
      for (int i = 0; i < 8; ++i) {                                    \
        float dtv = dt_[i];                                            \
        float dtx = dtv * xc_[i];                                      \
        h[0] = fmaf(exp2f(dtv * A2[0]), h[0], dtx * B_[i].x);          \
        h[1] = fmaf(exp2f(dtv * A2[1]), h[1], dtx * B_[i].y);          \
        h[2] = fmaf(exp2f(dtv * A2[2]), h[2], dtx * B_[i].z);          \
        h[3] = fmaf(exp2f(dtv * A2[3]), h[3], dtx * B_[i].w);          \
        float p = h[0] * C_[i].x + h[1] * C_[i].y                      \
                + h[2] * C_[i].z + h[3] * C_[i].w;                     \
        p += __shfl_xor(p, 1);                                         \
        p += __shfl_xor(p, 2);                                         \
        p += __shfl_xor(p, 4);                                         \
        p += __shfl_xor(p, 8);                                         \
        float zv = z_[i];                                              \
        float y2 = (p + xc_[i] * Dv) * (zv / (1.f + __expf(-zv)));     \
        if (s4 == 0) yp[rb + (size_t)((t0) + i) * DI] = y2;            \
      } }

    LOADC(0, dt0, xc0, z0, B0, C0);
    for (int c = 0; c < 128; c += 2) {
        LOADC((c + 1) * 8, dt1, xc1, z1, B1, C1);
        COMPC(c * 8, dt0, xc0, z0, B0, C0);
        if (c + 2 < 128) LOADC((c + 2) * 8, dt0, xc0, z0, B0, C0);
        COMPC((c + 1) * 8, dt1, xc1, z1, B1, C1);
    }
#undef LOADC
#undef COMPC
}

// ---------------- combine: out5(4,S,512) -> combined(2,S,512) ----------------
__global__ __launch_bounds__(256) void combine_kernel(
    const float* __restrict__ out5, float* __restrict__ comb)
{
    int idx = blockIdx.x * 256 + threadIdx.x;     // over 2*1024*512 = 2^20
    int c = idx & 511;
    int t = (idx >> 9) & 1023;
    int b = idx >> 19;
    float vf = out5[((size_t)(b * SEQL + t)) * 512 + c];
    float vb = out5[((size_t)((2 + b) * SEQL + (1023 - t))) * 512 + c];
    comb[idx] = vf + vb;
}

extern "C" void kernel_launch(void* const* d_in, const int* in_sizes, int n_in,
                              void* d_out, int out_size, void* d_ws, size_t ws_size,
                              hipStream_t stream)
{
    const float* x        = (const float*)d_in[0];
    const float* W_in_bi  = (const float*)d_in[1];
    const float* b_in_bi  = (const float*)d_in[2];
    const float* W_out_bi = (const float*)d_in[3];
    const float* b_out_bi = (const float*)d_in[4];
    const float* W_in     = (const float*)d_in[5];
    const float* b_in     = (const float*)d_in[6];
    const float* conv_w   = (const float*)d_in[7];
    const float* conv_b   = (const float*)d_in[8];
    const float* W_x      = (const float*)d_in[9];
    const float* W_dt     = (const float*)d_in[10];
    const float* b_dt     = (const float*)d_in[11];
    const float* A_log    = (const float*)d_in[12];
    const float* D_param  = (const float*)d_in[13];
    const float* W_out    = (const float*)d_in[14];
    const float* b_out    = (const float*)d_in[15];
    float* outp = (float*)d_out;
    char* ws = (char*)d_ws;
    const size_t MB = (size_t)1 << 20;

    // workspace layout (peak ~50.7 MB):
    float* xp    = (float*)(ws + 0);        // 2048x1024 (8MB), dead after reorder
    float* xboth = (float*)(ws + 8 * MB);   // 4096x512  (8MB), dead after G1
    float* xin   = (float*)(ws + 16 * MB);  // 4096x1024 (16MB), dead after conv
    float* zbuf  = (float*)(ws + 32 * MB);  // 4096x1024 (16MB), alive to scan
    float* xdbl  = (float*)(ws + 48 * MB);  // 4096x160  (2.5MB)
    float* xcb   = (float*)(ws + 0);        // 4096x1024 (16MB) over xp+xboth
    float* dtb   = (float*)(ws + 16 * MB);  // 4096x1024 over xin; scan writes y in-place
    float* out5  = (float*)(ws + 0);        // 4096x512 (8MB) over xcb
    float* comb  = (float*)(ws + 8 * MB);   // 2048x512 (4MB)

    dim3 blk(256, 1, 1);
    auto gg = [](int M, int N) {
        return dim3((unsigned)((N + 127) / 128), (unsigned)((M + 127) / 128), 1);
    };

    // xp = x @ W_in_bi^T + b_in_bi
    gemm_kernel<0><<<gg(2048, 1024), blk, 0, stream>>>(x, W_in_bi, b_in_bi, xp, 2048, 1024, 512, 512);
    // x_both
    reorder_kernel<<<dim3(8192), blk, 0, stream>>>(xp, xboth);
    // xz split into xin / z (two N=1024 GEMMs over W_in's row halves)
    gemm_kernel<0><<<gg(4096, 1024), blk, 0, stream>>>(xboth, W_in, b_in, xin, 4096, 1024, 512, 512);
    gemm_kernel<0><<<gg(4096, 1024), blk, 0, stream>>>(xboth, W_in + 1024 * 512, b_in + 1024, zbuf, 4096, 1024, 512, 512);
    // depthwise conv + silu
    conv_silu_kernel<<<dim3(16384), blk, 0, stream>>>(xin, conv_w, conv_b, xcb);
    // x_dbl = xc @ W_x^T
    gemm_kernel<0><<<gg(4096, 160), blk, 0, stream>>>(xcb, W_x, nullptr, xdbl, 4096, 160, 1024, 1024);
    // dt = softplus(dt_raw @ W_dt^T + b_dt)   (A = x_dbl cols 0..31, lda=160)
    gemm_kernel<1><<<gg(4096, 1024), blk, 0, stream>>>(xdbl, W_dt, b_dt, dtb, 4096, 1024, 32, 160);
    // selective scan + fused (y + xc*D)*silu(z), y written over dtb
    scan_kernel<<<dim3(256), blk, 0, stream>>>(dtb, dtb, xdbl, xcb, zbuf, A_log, D_param);
    // out = y @ W_out^T + b_out
    gemm_kernel<0><<<gg(4096, 512), blk, 0, stream>>>(dtb, W_out, b_out, out5, 4096, 512, 1024, 1024);
    // combine forward + flipped backward
    combine_kernel<<<dim3(4096), blk, 0, stream>>>(out5, comb);
    // final = combined @ W_out_bi^T + b_out_bi
    gemm_kernel<0><<<gg(2048, 512), blk, 0, stream>>>(comb, W_out_bi, b_out_bi, outp, 2048, 512, 512, 512);
}

// Round 2
// 1006.218 us; speedup vs baseline: 1.1621x; 1.1621x over previous
//
#include <hip/hip_runtime.h>
#include <hip/hip_bf16.h>
#include <math.h>

#define SEQL 1024
#define DMODEL 512
#define DI 1024
#define DSTATE 64
#define XDBL_N 160

// ---------------- generic f32 GEMM: C = act(A @ W^T + bias) ----------------
// A: (M,K) lda given; W: (N,K) row-major; C: (M,N). Tile 128 x (16*NJ), BK=16.
// Reg-double-buffered staging; LDS pads (18/20) keep all accesses <=2-way.
// ACT: 0 = none, 1 = softplus
template<int ACT, int NJ>
__global__ __launch_bounds__(256, 2) void gemm_kernel(
    const float* __restrict__ A, const float* __restrict__ W,
    const float* __restrict__ bias, float* __restrict__ C,
    int M, int N, int K, int lda)
{
    constexpr int TN = 16 * NJ;
    __shared__ float As[128 * 18];
    __shared__ float Ws[TN * 20];
    const int tid = threadIdx.x;
    const int bm = blockIdx.y * 128;
    const int bn = blockIdx.x * TN;
    const int tx = tid & 15;          // output col = bn + tx + 16j
    const int ty = tid >> 4;          // output rows = bm + ty*8 + i
    const int srow = tid >> 1;        // staging row 0..127
    const int sc = (tid & 1) * 8;     // staging col offset (floats)

    const float* Ap = A + (size_t)(bm + srow) * lda + sc;
    const float* Wp = W + (size_t)(bn + srow) * K + sc;
    const bool aok = (bm + srow) < M;
    const bool wok = (srow < TN) && ((bn + srow) < N);
    const float4 f0 = make_float4(0.f, 0.f, 0.f, 0.f);

    float4 na0 = f0, na1 = f0, nw0 = f0, nw1 = f0;
    if (aok) { na0 = *(const float4*)(Ap + 0); na1 = *(const float4*)(Ap + 4); }
    if (wok) { nw0 = *(const float4*)(Wp + 0); nw1 = *(const float4*)(Wp + 4); }

    float acc[8][NJ];
    #pragma unroll
    for (int i = 0; i < 8; ++i)
        #pragma unroll
        for (int j = 0; j < NJ; ++j) acc[i][j] = 0.f;

    for (int k0 = 0;;) {
        __syncthreads();
        {
            int wa = srow * 18 + sc;
            *(float2*)&As[wa + 0] = make_float2(na0.x, na0.y);
            *(float2*)&As[wa + 2] = make_float2(na0.z, na0.w);
            *(float2*)&As[wa + 4] = make_float2(na1.x, na1.y);
            *(float2*)&As[wa + 6] = make_float2(na1.z, na1.w);
            if (srow < TN) {
                int ww = srow * 20 + sc;
                *(float4*)&Ws[ww + 0] = nw0;
                *(float4*)&Ws[ww + 4] = nw1;
            }
        }
        __syncthreads();
        const int kn = k0 + 16;
        if (kn < K) {
            na0 = f0; na1 = f0;
            if (aok) { na0 = *(const float4*)(Ap + kn); na1 = *(const float4*)(Ap + kn + 4); }
            if (wok) { nw0 = *(const float4*)(Wp + kn); nw1 = *(const float4*)(Wp + kn + 4); }
        }
        #pragma unroll
        for (int k = 0; k < 16; k += 2) {
            float2 a2[8], b2[NJ];
            #pragma unroll
            for (int i = 0; i < 8; ++i)
                a2[i] = *(const float2*)&As[(ty * 8 + i) * 18 + k];
            #pragma unroll
            for (int j = 0; j < NJ; ++j)
                b2[j] = *(const float2*)&Ws[(tx + j * 16) * 20 + k];
            #pragma unroll
            for (int i = 0; i < 8; ++i)
                #pragma unroll
                for (int j = 0; j < NJ; ++j) {
                    acc[i][j] = fmaf(a2[i].x, b2[j].x, acc[i][j]);
                    acc[i][j] = fmaf(a2[i].y, b2[j].y, acc[i][j]);
                }
        }
        k0 = kn;
        if (k0 >= K) break;
    }

    #pragma unroll
    for (int i = 0; i < 8; ++i) {
        int gm = bm + ty * 8 + i;
        if (gm >= M) continue;
        #pragma unroll
        for (int j = 0; j < NJ; ++j) {
            int gn = bn + tx + j * 16;
            if (gn >= N) continue;
            float v = acc[i][j];
            if (bias) v += bias[gn];
            if (ACT == 1) v = (v > 20.f) ? v : log1pf(__expf(v));
            C[(size_t)gm * N + gn] = v;
        }
    }
}

// ---------------- reorder: xp(2,S,1024) -> x_both(4,S,512) ----------------
__global__ __launch_bounds__(256) void reorder_kernel(
    const float* __restrict__ xp, float* __restrict__ xboth)
{
    int idx = blockIdx.x * 256 + threadIdx.x;     // over 4*1024*512 = 2^21
    int c  = idx & 511;
    int t  = (idx >> 9) & 1023;
    int b4 = idx >> 19;
    float v;
    if (b4 < 2) v = xp[((size_t)(b4 * SEQL + t)) * DI + c];
    else        v = xp[((size_t)((b4 - 2) * SEQL + (1023 - t))) * DI + 512 + c];
    xboth[idx] = v;
}

// ---------------- depthwise causal conv (k=4) + silu ----------------
__global__ __launch_bounds__(256) void conv_silu_kernel(
    const float* __restrict__ xin, const float* __restrict__ cw,
    const float* __restrict__ cb, float* __restrict__ xc)
{
    int idx = blockIdx.x * 256 + threadIdx.x;     // over 4*1024*1024 = 2^22
    int c = idx & (DI - 1);
    int t = (idx >> 10) & (SEQL - 1);
    int b = idx >> 20;
    float acc = cb[c];
    #pragma unroll
    for (int k = 0; k < 4; ++k) {
        int tt = t - 3 + k;
        if (tt >= 0) acc = fmaf(xin[((size_t)(b * SEQL + tt)) * DI + c], cw[c * 4 + k], acc);
    }
    float s = 1.f / (1.f + __expf(-acc));
    xc[idx] = acc * s;
}

// ---------------- selective scan + fused (y + xc*D)*silu(z) ----------------
// One wave per (b,d) stream: lane = state s (64 states). 4096 waves total.
// grid 1024 blocks x 256 thr; block -> (bb, 4 d's). yp may alias dtp
// (stores always trail the 16-step-ahead prefetch of the same wave).
__global__ __launch_bounds__(256, 4) void scan_kernel(
    const float* dtp, float* yp,
    const float* __restrict__ xdbl,
    const float* __restrict__ xcp,
    const float* __restrict__ zp,
    const float* __restrict__ A_log,
    const float* __restrict__ Dpar)
{
    const int blk = blockIdx.x;
    const int bb = blk >> 8;
    const int dblk = blk & 255;
    const int wave = threadIdx.x >> 6;
    const int lane = threadIdx.x & 63;
    const int d = dblk * 4 + wave;
    const float LOG2E = 1.4426950408889634f;

    const float A2 = -__expf(A_log[d * DSTATE + lane]) * LOG2E;
    float h = 0.f;
    const float Dv = Dpar[d];
    const size_t rb = (size_t)bb * SEQL * DI + d;
    const float* Bb = xdbl + (size_t)bb * SEQL * XDBL_N + 32 + lane;

    float dt0[8], xc0[8], z0[8], B0[8], C0[8];
    float dt1[8], xc1[8], z1[8], B1[8], C1[8];

#define LOADC(t0, dt_, xc_, z_, B_, C_)                                \
    { _Pragma("unroll")                                                \
      for (int i = 0; i < 8; ++i) {                                    \
        size_t ro = rb + (size_t)((t0) + i) * DI;                      \
        dt_[i] = dtp[ro];                                              \
        xc_[i] = xcp[ro];                                              \
        z_[i]  = zp[ro];                                               \
        const float* bp = Bb + (size_t)((t0) + i) * XDBL_N;            \
        B_[i] = bp[0];                                                 \
        C_[i] = bp[64];                                                \
      } }

#define COMPC(t0, dt_, xc_, z_, B_, C_)                                \
    { _Pragma("unroll")                                                \
      for (int i = 0; i < 8; ++i) {                                    \
        float dtv = dt_[i];                                            \
        float dtx = dtv * xc_[i];                                      \
        h = fmaf(exp2f(dtv * A2), h, dtx * B_[i]);                     \
        float p = h * C_[i];                                           \
        p += __shfl_xor(p, 1);                                         \
        p += __shfl_xor(p, 2);                                         \
        p += __shfl_xor(p, 4);                                         \
        p += __shfl_xor(p, 8);                                         \
        p += __shfl_xor(p, 16);                                        \
        p += __shfl_xor(p, 32);                                        \
        float zv = z_[i];                                              \
        float y2 = (p + xc_[i] * Dv)                                   \
                 * __fdividef(zv, 1.f + __expf(-zv));                  \
        if (lane == 0) yp[rb + (size_t)((t0) + i) * DI] = y2;          \
      } }

    LOADC(0, dt0, xc0, z0, B0, C0);
    for (int c = 0; c < 128; c += 2) {
        LOADC((c + 1) * 8, dt1, xc1, z1, B1, C1);
        COMPC(c * 8, dt0, xc0, z0, B0, C0);
        if (c + 2 < 128) LOADC((c + 2) * 8, dt0, xc0, z0, B0, C0);
        COMPC((c + 1) * 8, dt1, xc1, z1, B1, C1);
    }
#undef LOADC
#undef COMPC
}

// ---------------- combine: out5(4,S,512) -> combined(2,S,512) ----------------
__global__ __launch_bounds__(256) void combine_kernel(
    const float* __restrict__ out5, float* __restrict__ comb)
{
    int idx = blockIdx.x * 256 + threadIdx.x;     // over 2*1024*512 = 2^20
    int c = idx & 511;
    int t = (idx >> 9) & 1023;
    int b = idx >> 19;
    float vf = out5[((size_t)(b * SEQL + t)) * 512 + c];
    float vb = out5[((size_t)((2 + b) * SEQL + (1023 - t))) * 512 + c];
    comb[idx] = vf + vb;
}

extern "C" void kernel_launch(void* const* d_in, const int* in_sizes, int n_in,
                              void* d_out, int out_size, void* d_ws, size_t ws_size,
                              hipStream_t stream)
{
    const float* x        = (const float*)d_in[0];
    const float* W_in_bi  = (const float*)d_in[1];
    const float* b_in_bi  = (const float*)d_in[2];
    const float* W_out_bi = (const float*)d_in[3];
    const float* b_out_bi = (const float*)d_in[4];
    const float* W_in     = (const float*)d_in[5];
    const float* b_in     = (const float*)d_in[6];
    const float* conv_w   = (const float*)d_in[7];
    const float* conv_b   = (const float*)d_in[8];
    const float* W_x      = (const float*)d_in[9];
    const float* W_dt     = (const float*)d_in[10];
    const float* b_dt     = (const float*)d_in[11];
    const float* A_log    = (const float*)d_in[12];
    const float* D_param  = (const float*)d_in[13];
    const float* W_out    = (const float*)d_in[14];
    const float* b_out    = (const float*)d_in[15];
    float* outp = (float*)d_out;
    char* ws = (char*)d_ws;
    const size_t MB = (size_t)1 << 20;

    // workspace layout (peak ~50.7 MB):
    float* xp    = (float*)(ws + 0);        // 2048x1024 (8MB), dead after reorder
    float* xboth = (float*)(ws + 8 * MB);   // 4096x512  (8MB), dead after G2/G3
    float* xin   = (float*)(ws + 16 * MB);  // 4096x1024 (16MB), dead after conv
    float* zbuf  = (float*)(ws + 32 * MB);  // 4096x1024 (16MB), alive to scan
    float* xdbl  = (float*)(ws + 48 * MB);  // 4096x160  (2.5MB)
    float* xcb   = (float*)(ws + 0);        // 4096x1024 (16MB) over xp+xboth
    float* dtb   = (float*)(ws + 16 * MB);  // 4096x1024 over xin; scan writes y in-place
    float* out5  = (float*)(ws + 0);        // 4096x512 (8MB) over xcb
    float* comb  = (float*)(ws + 8 * MB);   // 2048x512 (4MB)

    dim3 blk(256, 1, 1);
    auto g128 = [](int M, int N) {
        return dim3((unsigned)((N + 127) / 128), (unsigned)((M + 127) / 128), 1);
    };
    auto g32 = [](int M, int N) {
        return dim3((unsigned)((N + 31) / 32), (unsigned)((M + 127) / 128), 1);
    };

    // xp = x @ W_in_bi^T + b_in_bi
    gemm_kernel<0, 8><<<g128(2048, 1024), blk, 0, stream>>>(x, W_in_bi, b_in_bi, xp, 2048, 1024, 512, 512);
    // x_both
    reorder_kernel<<<dim3(8192), blk, 0, stream>>>(xp, xboth);
    // xz split into xin / z (two N=1024 GEMMs over W_in's row halves)
    gemm_kernel<0, 8><<<g128(4096, 1024), blk, 0, stream>>>(xboth, W_in, b_in, xin, 4096, 1024, 512, 512);
    gemm_kernel<0, 8><<<g128(4096, 1024), blk, 0, stream>>>(xboth, W_in + 1024 * 512, b_in + 1024, zbuf, 4096, 1024, 512, 512);
    // depthwise conv + silu
    conv_silu_kernel<<<dim3(16384), blk, 0, stream>>>(xin, conv_w, conv_b, xcb);
    // x_dbl = xc @ W_x^T   (N=160 -> TN=32 variant, 5x32 grid cols)
    gemm_kernel<0, 2><<<g32(4096, 160), blk, 0, stream>>>(xcb, W_x, nullptr, xdbl, 4096, 160, 1024, 1024);
    // dt = softplus(dt_raw @ W_dt^T + b_dt)   (A = x_dbl cols 0..31, lda=160)
    gemm_kernel<1, 8><<<g128(4096, 1024), blk, 0, stream>>>(xdbl, W_dt, b_dt, dtb, 4096, 1024, 32, 160);
    // selective scan + fused (y + xc*D)*silu(z), y written over dtb
    scan_kernel<<<dim3(1024), blk, 0, stream>>>(dtb, dtb, xdbl, xcb, zbuf, A_log, D_param);
    // out = y @ W_out^T + b_out   (N=512 -> TN=32 variant for 512-block grid)
    gemm_kernel<0, 2><<<g32(4096, 512), blk, 0, stream>>>(dtb, W_out, b_out, out5, 4096, 512, 1024, 1024);
    // combine forward + flipped backward
    combine_kernel<<<dim3(4096), blk, 0, stream>>>(out5, comb);
    // final = combined @ W_out_bi^T + b_out_bi
    gemm_kernel<0, 2><<<g32(2048, 512), blk, 0, stream>>>(comb, W_out_bi, b_out_bi, outp, 2048, 512, 512, 512);
}

// Round 3
// 824.643 us; speedup vs baseline: 1.4180x; 1.2202x over previous
//
#include <hip/hip_runtime.h>
#include <hip/hip_bf16.h>
#include <math.h>

#define SEQL 1024
#define DMODEL 512
#define DI 1024
#define DSTATE 64
#define XDBL_N 160

// ---------------- generic f32 GEMM: C = act(A @ W^T + bias) ----------------
// A: (M,K) lda given; W: (N,K) row-major; C: (M,N). Tile 128 x (16*NJ), BK=16.
// Reg-double-buffered staging; LDS pads (18/20) keep all accesses <=2-way.
// ACT: 0 = none, 1 = softplus
template<int ACT, int NJ>
__global__ __launch_bounds__(256, 2) void gemm_kernel(
    const float* __restrict__ A, const float* __restrict__ W,
    const float* __restrict__ bias, float* __restrict__ C,
    int M, int N, int K, int lda)
{
    constexpr int TN = 16 * NJ;
    __shared__ float As[128 * 18];
    __shared__ float Ws[TN * 20];
    const int tid = threadIdx.x;
    const int bm = blockIdx.y * 128;
    const int bn = blockIdx.x * TN;
    const int tx = tid & 15;          // output col = bn + tx + 16j
    const int ty = tid >> 4;          // output rows = bm + ty*8 + i
    const int srow = tid >> 1;        // staging row 0..127
    const int sc = (tid & 1) * 8;     // staging col offset (floats)

    const float* Ap = A + (size_t)(bm + srow) * lda + sc;
    const float* Wp = W + (size_t)(bn + srow) * K + sc;
    const bool aok = (bm + srow) < M;
    const bool wok = (srow < TN) && ((bn + srow) < N);
    const float4 f0 = make_float4(0.f, 0.f, 0.f, 0.f);

    float4 na0 = f0, na1 = f0, nw0 = f0, nw1 = f0;
    if (aok) { na0 = *(const float4*)(Ap + 0); na1 = *(const float4*)(Ap + 4); }
    if (wok) { nw0 = *(const float4*)(Wp + 0); nw1 = *(const float4*)(Wp + 4); }

    float acc[8][NJ];
    #pragma unroll
    for (int i = 0; i < 8; ++i)
        #pragma unroll
        for (int j = 0; j < NJ; ++j) acc[i][j] = 0.f;

    for (int k0 = 0;;) {
        __syncthreads();
        {
            int wa = srow * 18 + sc;
            *(float2*)&As[wa + 0] = make_float2(na0.x, na0.y);
            *(float2*)&As[wa + 2] = make_float2(na0.z, na0.w);
            *(float2*)&As[wa + 4] = make_float2(na1.x, na1.y);
            *(float2*)&As[wa + 6] = make_float2(na1.z, na1.w);
            if (srow < TN) {
                int ww = srow * 20 + sc;
                *(float4*)&Ws[ww + 0] = nw0;
                *(float4*)&Ws[ww + 4] = nw1;
            }
        }
        __syncthreads();
        const int kn = k0 + 16;
        if (kn < K) {
            na0 = f0; na1 = f0;
            if (aok) { na0 = *(const float4*)(Ap + kn); na1 = *(const float4*)(Ap + kn + 4); }
            if (wok) { nw0 = *(const float4*)(Wp + kn); nw1 = *(const float4*)(Wp + kn + 4); }
        }
        #pragma unroll
        for (int k = 0; k < 16; k += 2) {
            float2 a2[8], b2[NJ];
            #pragma unroll
            for (int i = 0; i < 8; ++i)
                a2[i] = *(const float2*)&As[(ty * 8 + i) * 18 + k];
            #pragma unroll
            for (int j = 0; j < NJ; ++j)
                b2[j] = *(const float2*)&Ws[(tx + j * 16) * 20 + k];
            #pragma unroll
            for (int i = 0; i < 8; ++i)
                #pragma unroll
                for (int j = 0; j < NJ; ++j) {
                    acc[i][j] = fmaf(a2[i].x, b2[j].x, acc[i][j]);
                    acc[i][j] = fmaf(a2[i].y, b2[j].y, acc[i][j]);
                }
        }
        k0 = kn;
        if (k0 >= K) break;
    }

    #pragma unroll
    for (int i = 0; i < 8; ++i) {
        int gm = bm + ty * 8 + i;
        if (gm >= M) continue;
        #pragma unroll
        for (int j = 0; j < NJ; ++j) {
            int gn = bn + tx + j * 16;
            if (gn >= N) continue;
            float v = acc[i][j];
            if (bias) v += bias[gn];
            if (ACT == 1) v = (v > 20.f) ? v : log1pf(__expf(v));
            C[(size_t)gm * N + gn] = v;
        }
    }
}

// ---------------- reorder: xp(2,S,1024) -> x_both(4,S,512) ----------------
__global__ __launch_bounds__(256) void reorder_kernel(
    const float* __restrict__ xp, float* __restrict__ xboth)
{
    int idx = blockIdx.x * 256 + threadIdx.x;     // over 4*1024*512 = 2^21
    int c  = idx & 511;
    int t  = (idx >> 9) & 1023;
    int b4 = idx >> 19;
    float v;
    if (b4 < 2) v = xp[((size_t)(b4 * SEQL + t)) * DI + c];
    else        v = xp[((size_t)((b4 - 2) * SEQL + (1023 - t))) * DI + 512 + c];
    xboth[idx] = v;
}

// ---------------- depthwise causal conv (k=4) + silu ----------------
__global__ __launch_bounds__(256) void conv_silu_kernel(
    const float* __restrict__ xin, const float* __restrict__ cw,
    const float* __restrict__ cb, float* __restrict__ xc)
{
    int idx = blockIdx.x * 256 + threadIdx.x;     // over 4*1024*1024 = 2^22
    int c = idx & (DI - 1);
    int t = (idx >> 10) & (SEQL - 1);
    int b = idx >> 20;
    float acc = cb[c];
    #pragma unroll
    for (int k = 0; k < 4; ++k) {
        int tt = t - 3 + k;
        if (tt >= 0) acc = fmaf(xin[((size_t)(b * SEQL + tt)) * DI + c], cw[c * 4 + k], acc);
    }
    float s = 1.f / (1.f + __expf(-acc));
    xc[idx] = acc * s;
}

// ============ chunked selective scan ============
// Streams: (b,d) = 4096. Wave layout: 4 d's per wave, lane=(dd,s4):
// 16 lanes per d, 4 states per lane (s = s4*4+k). Time split into 4 chunks
// of 256. part1: chunks 0..2 local scan from h=0 -> store S_c (final state)
// and sum(dt). part2: all 4 chunks; h_in composed from S/sumdt (diagonal
// transition: P_c = exp2(A2*sumdt)); full scan + reduce + fused epilogue.

// ---------------- pass 1: chunk-local final states ----------------
__global__ __launch_bounds__(256, 3) void scan_part1(
    const float* __restrict__ dtp, const float* __restrict__ xcp,
    const float* __restrict__ xdbl, const float* __restrict__ A_log,
    float* __restrict__ Sbuf, float* __restrict__ SDbuf)
{
    const int blk = blockIdx.x;          // (bb*3 + c)*64 + dblock
    const int dblock = blk & 63;
    const int bc = blk >> 6;             // bb*3 + c
    const int bb = bc / 3;
    const int c  = bc - bb * 3;
    const int wave = threadIdx.x >> 6;
    const int lane = threadIdx.x & 63;
    const int dd = lane >> 4;
    const int s4 = lane & 15;
    const int d = dblock * 16 + wave * 4 + dd;
    const float LOG2E = 1.4426950408889634f;

    float A2[4], h[4];
    #pragma unroll
    for (int k = 0; k < 4; ++k) {
        A2[k] = -__expf(A_log[d * DSTATE + s4 * 4 + k]) * LOG2E;
        h[k] = 0.f;
    }
    float sumdt = 0.f;
    const int T0 = c * 256;
    const size_t rb = (size_t)bb * SEQL * DI + (size_t)T0 * DI + d;
    const float* Bb = xdbl + ((size_t)bb * SEQL + T0) * XDBL_N + 32 + s4 * 4;

    float dt0[4], xc0[4]; float4 B0[4];
    float dt1[4], xc1[4]; float4 B1[4];

#define L1(t0, dt_, xc_, B_)                                           \
    { _Pragma("unroll")                                                \
      for (int i = 0; i < 4; ++i) {                                    \
        size_t ro = rb + (size_t)((t0) + i) * DI;                      \
        dt_[i] = dtp[ro];                                              \
        xc_[i] = xcp[ro];                                              \
        B_[i] = *(const float4*)(Bb + (size_t)((t0) + i) * XDBL_N);    \
      } }

#define C1(dt_, xc_, B_)                                               \
    { _Pragma("unroll")                                                \
      for (int i = 0; i < 4; ++i) {                                    \
        float dtv = dt_[i];                                            \
        sumdt += dtv;                                                  \
        float dtx = dtv * xc_[i];                                      \
        h[0] = fmaf(exp2f(dtv * A2[0]), h[0], dtx * B_[i].x);          \
        h[1] = fmaf(exp2f(dtv * A2[1]), h[1], dtx * B_[i].y);          \
        h[2] = fmaf(exp2f(dtv * A2[2]), h[2], dtx * B_[i].z);          \
        h[3] = fmaf(exp2f(dtv * A2[3]), h[3], dtx * B_[i].w);          \
      } }

    L1(0, dt0, xc0, B0);
    for (int g = 0; g < 64; g += 2) {
        L1((g + 1) * 4, dt1, xc1, B1);
        C1(dt0, xc0, B0);
        if (g + 2 < 64) L1((g + 2) * 4, dt0, xc0, B0);
        C1(dt1, xc1, B1);
    }
#undef L1
#undef C1

    const size_t so = ((size_t)bc * 1024 + d) * 64 + s4 * 4;
    *(float4*)&Sbuf[so] = make_float4(h[0], h[1], h[2], h[3]);
    if (s4 == 0) SDbuf[bc * 1024 + d] = sumdt;
}

// ---------------- pass 2: full scan with h_in + reduce + epilogue ----------------
// yp may alias dtp (each wave's stores trail its own prefetched reads;
// blocks touch disjoint (t,d) regions).
__global__ __launch_bounds__(256, 4) void scan_part2(
    const float* dtp, float* yp,
    const float* __restrict__ xdbl,
    const float* __restrict__ xcp,
    const float* __restrict__ zp,
    const float* __restrict__ A_log,
    const float* __restrict__ Dpar,
    const float* __restrict__ Sbuf,
    const float* __restrict__ SDbuf)
{
    const int blk = blockIdx.x;          // (bb*4 + c)*64 + dblock
    const int dblock = blk & 63;
    const int bc = blk >> 6;
    const int bb = bc >> 2;
    const int c  = bc & 3;
    const int wave = threadIdx.x >> 6;
    const int lane = threadIdx.x & 63;
    const int dd = lane >> 4;
    const int s4 = lane & 15;
    const int d = dblock * 16 + wave * 4 + dd;
    const float LOG2E = 1.4426950408889634f;

    float A2[4], h[4];
    #pragma unroll
    for (int k = 0; k < 4; ++k) {
        A2[k] = -__expf(A_log[d * DSTATE + s4 * 4 + k]) * LOG2E;
        h[k] = 0.f;
    }
    // compose h_in from prior chunks' (S, sumdt)
    for (int cc = 0; cc < c; ++cc) {
        const int bcc = bb * 3 + cc;
        const size_t so = ((size_t)bcc * 1024 + d) * 64 + s4 * 4;
        float4 S = *(const float4*)&Sbuf[so];
        float sd = SDbuf[bcc * 1024 + d];
        h[0] = fmaf(exp2f(A2[0] * sd), h[0], S.x);
        h[1] = fmaf(exp2f(A2[1] * sd), h[1], S.y);
        h[2] = fmaf(exp2f(A2[2] * sd), h[2], S.z);
        h[3] = fmaf(exp2f(A2[3] * sd), h[3], S.w);
    }

    const float Dv = Dpar[d];
    const int T0 = c * 256;
    const size_t rb = (size_t)bb * SEQL * DI + (size_t)T0 * DI + d;
    const float* Bb = xdbl + ((size_t)bb * SEQL + T0) * XDBL_N + 32 + s4 * 4;

    float dt0[4], xc0[4], z0[4]; float4 B0[4], C0[4];
    float dt1[4], xc1[4], z1[4]; float4 B1[4], C1[4];

#define LOADC(t0, dt_, xc_, z_, B_, C_)                                \
    { _Pragma("unroll")                                                \
      for (int i = 0; i < 4; ++i) {                                    \
        size_t ro = rb + (size_t)((t0) + i) * DI;                      \
        dt_[i] = dtp[ro];                                              \
        xc_[i] = xcp[ro];                                              \
        z_[i]  = zp[ro];                                               \
        const float* bp = Bb + (size_t)((t0) + i) * XDBL_N;            \
        B_[i] = *(const float4*)bp;                                    \
        C_[i] = *(const float4*)(bp + 64);                             \
      } }

#define COMPC(t0, dt_, xc_, z_, B_, C_)                                \
    { _Pragma("unroll")                                                \
      for (int i = 0; i < 4; ++i) {                                    \
        float dtv = dt_[i];                                            \
        float dtx = dtv * xc_[i];                                      \
        h[0] = fmaf(exp2f(dtv * A2[0]), h[0], dtx * B_[i].x);          \
        h[1] = fmaf(exp2f(dtv * A2[1]), h[1], dtx * B_[i].y);          \
        h[2] = fmaf(exp2f(dtv * A2[2]), h[2], dtx * B_[i].z);          \
        h[3] = fmaf(exp2f(dtv * A2[3]), h[3], dtx * B_[i].w);          \
        float p = h[0] * C_[i].x + h[1] * C_[i].y                      \
                + h[2] * C_[i].z + h[3] * C_[i].w;                     \
        p += __shfl_xor(p, 1);                                         \
        p += __shfl_xor(p, 2);                                         \
        p += __shfl_xor(p, 4);                                         \
        p += __shfl_xor(p, 8);                                         \
        float zv = z_[i];                                              \
        float y2 = (p + xc_[i] * Dv)                                   \
                 * __fdividef(zv, 1.f + __expf(-zv));                  \
        if (s4 == 0) yp[rb + (size_t)((t0) + i) * DI] = y2;            \
      } }

    LOADC(0, dt0, xc0, z0, B0, C0);
    for (int g = 0; g < 64; g += 2) {
        LOADC((g + 1) * 4, dt1, xc1, z1, B1, C1);
        COMPC(g * 4, dt0, xc0, z0, B0, C0);
        if (g + 2 < 64) LOADC((g + 2) * 4, dt0, xc0, z0, B0, C0);
        COMPC((g + 1) * 4, dt1, xc1, z1, B1, C1);
    }
#undef LOADC
#undef COMPC
}

// ---------------- combine: out5(4,S,512) -> combined(2,S,512) ----------------
__global__ __launch_bounds__(256) void combine_kernel(
    const float* __restrict__ out5, float* __restrict__ comb)
{
    int idx = blockIdx.x * 256 + threadIdx.x;     // over 2*1024*512 = 2^20
    int c = idx & 511;
    int t = (idx >> 9) & 1023;
    int b = idx >> 19;
    float vf = out5[((size_t)(b * SEQL + t)) * 512 + c];
    float vb = out5[((size_t)((2 + b) * SEQL + (1023 - t))) * 512 + c];
    comb[idx] = vf + vb;
}

extern "C" void kernel_launch(void* const* d_in, const int* in_sizes, int n_in,
                              void* d_out, int out_size, void* d_ws, size_t ws_size,
                              hipStream_t stream)
{
    const float* x        = (const float*)d_in[0];
    const float* W_in_bi  = (const float*)d_in[1];
    const float* b_in_bi  = (const float*)d_in[2];
    const float* W_out_bi = (const float*)d_in[3];
    const float* b_out_bi = (const float*)d_in[4];
    const float* W_in     = (const float*)d_in[5];
    const float* b_in     = (const float*)d_in[6];
    const float* conv_w   = (const float*)d_in[7];
    const float* conv_b   = (const float*)d_in[8];
    const float* W_x      = (const float*)d_in[9];
    const float* W_dt     = (const float*)d_in[10];
    const float* b_dt     = (const float*)d_in[11];
    const float* A_log    = (const float*)d_in[12];
    const float* D_param  = (const float*)d_in[13];
    const float* W_out    = (const float*)d_in[14];
    const float* b_out    = (const float*)d_in[15];
    float* outp = (float*)d_out;
    char* ws = (char*)d_ws;
    const size_t MB = (size_t)1 << 20;

    // workspace layout (peak ~53.6 MB):
    float* xp    = (float*)(ws + 0);        // 2048x1024 (8MB), dead after reorder
    float* xboth = (float*)(ws + 8 * MB);   // 4096x512  (8MB), dead after G2/G3
    float* xin   = (float*)(ws + 16 * MB);  // 4096x1024 (16MB), dead after conv
    float* zbuf  = (float*)(ws + 32 * MB);  // 4096x1024 (16MB), alive to scan
    float* xdbl  = (float*)(ws + 48 * MB);  // 4096x160 (2.5MB)
    float* xcb   = (float*)(ws + 0);        // 4096x1024 (16MB) over xp+xboth
    float* dtb   = (float*)(ws + 16 * MB);  // 4096x1024 over xin; scan writes y in-place
    float* Sbuf  = (float*)(ws + 48 * MB + 2621440);            // 4x3x1024x64 (3MB)
    float* SDb   = (float*)(ws + 48 * MB + 2621440 + 3145728);  // 4x3x1024 (48KB)
    float* out5  = (float*)(ws + 0);        // 4096x512 (8MB) over xcb
    float* comb  = (float*)(ws + 8 * MB);   // 2048x512 (4MB)

    dim3 blk(256, 1, 1);
    auto g128 = [](int M, int N) {
        return dim3((unsigned)((N + 127) / 128), (unsigned)((M + 127) / 128), 1);
    };
    auto g32 = [](int M, int N) {
        return dim3((unsigned)((N + 31) / 32), (unsigned)((M + 127) / 128), 1);
    };

    // xp = x @ W_in_bi^T + b_in_bi
    gemm_kernel<0, 8><<<g128(2048, 1024), blk, 0, stream>>>(x, W_in_bi, b_in_bi, xp, 2048, 1024, 512, 512);
    // x_both
    reorder_kernel<<<dim3(8192), blk, 0, stream>>>(xp, xboth);
    // xz split into xin / z (two N=1024 GEMMs over W_in's row halves)
    gemm_kernel<0, 8><<<g128(4096, 1024), blk, 0, stream>>>(xboth, W_in, b_in, xin, 4096, 1024, 512, 512);
    gemm_kernel<0, 8><<<g128(4096, 1024), blk, 0, stream>>>(xboth, W_in + 1024 * 512, b_in + 1024, zbuf, 4096, 1024, 512, 512);
    // depthwise conv + silu
    conv_silu_kernel<<<dim3(16384), blk, 0, stream>>>(xin, conv_w, conv_b, xcb);
    // x_dbl = xc @ W_x^T   (N=160 -> TN=32 variant)
    gemm_kernel<0, 2><<<g32(4096, 160), blk, 0, stream>>>(xcb, W_x, nullptr, xdbl, 4096, 160, 1024, 1024);
    // dt = softplus(dt_raw @ W_dt^T + b_dt)   (A = x_dbl cols 0..31, lda=160)
    gemm_kernel<1, 8><<<g128(4096, 1024), blk, 0, stream>>>(xdbl, W_dt, b_dt, dtb, 4096, 1024, 32, 160);
    // chunked scan: pass 1 (chunks 0..2) then pass 2 (all 4 chunks)
    scan_part1<<<dim3(768), blk, 0, stream>>>(dtb, xcb, xdbl, A_log, Sbuf, SDb);
    scan_part2<<<dim3(1024), blk, 0, stream>>>(dtb, dtb, xdbl, xcb, zbuf, A_log, D_param, Sbuf, SDb);
    // out = y @ W_out^T + b_out   (N=512 -> TN=32 variant)
    gemm_kernel<0, 2><<<g32(4096, 512), blk, 0, stream>>>(dtb, W_out, b_out, out5, 4096, 512, 1024, 1024);
    // combine forward + flipped backward
    combine_kernel<<<dim3(4096), blk, 0, stream>>>(out5, comb);
    // final = combined @ W_out_bi^T + b_out_bi
    gemm_kernel<0, 2><<<g32(2048, 512), blk, 0, stream>>>(comb, W_out_bi, b_out_bi, outp, 2048, 512, 512, 512);
}

// Round 4
// 694.822 us; speedup vs baseline: 1.6829x; 1.1868x over previous
//
#include <hip/hip_runtime.h>
#include <hip/hip_bf16.h>
#include <math.h>

#define SEQL 1024
#define DI 1024
#define DSTATE 64
#define XDBL_N 160

typedef short bf16x8 __attribute__((ext_vector_type(8)));
typedef float f32x4 __attribute__((ext_vector_type(4)));

__device__ __forceinline__ unsigned short f2bf(float f) {
    unsigned u = __builtin_bit_cast(unsigned, f);
    u += 0x7FFFu + ((u >> 16) & 1u);
    return (unsigned short)(u >> 16);
}
__device__ __forceinline__ float bf2f(unsigned short h) {
    unsigned u = ((unsigned)h) << 16;
    return __builtin_bit_cast(float, u);
}

// ---------- split-bf16 MFMA GEMM: C = act(A @ W^T + bias) ----------
// A:(M,K) f32 lda; W:(N,K) f32 row-major; C:(M,N) f32.
// A = Ahi+Alo, W = Whi+Wlo (bf16 pairs); C ~= AhiWhi + AloWhi + AhiWlo.
// Tile 128x128, BK=32, 4 waves of 64x64 (4x4 16x16x32 mfma frags).
// M, K must be multiples of 128 / 32 (true for all call sites); N masked.
template<int ACT>
__global__ __launch_bounds__(256) void mgemm_kernel(
    const float* __restrict__ A, const float* __restrict__ W,
    const float* __restrict__ bias, float* __restrict__ C,
    int M, int N, int K, int lda)
{
    __shared__ unsigned short Ah[128 * 40];
    __shared__ unsigned short Al[128 * 40];
    __shared__ unsigned short Bh[128 * 40];
    __shared__ unsigned short Bl[128 * 40];
    const int tid = threadIdx.x;
    const int bm = blockIdx.y * 128, bn = blockIdx.x * 128;
    const int srow = tid >> 1;          // staging row 0..127
    const int sco = (tid & 1) * 16;     // staging col offset (f32 elems)
    const int wv = tid >> 6, lane = tid & 63;
    const int wm = (wv & 1) * 64, wn = (wv >> 1) * 64;
    const int fr = lane & 15, fg = lane >> 4;

    const float* Ap = A + (size_t)(bm + srow) * lda + sco;
    const float* Wp = W + (size_t)(bn + srow) * K + sco;
    const bool wok = (bn + srow) < N;
    const float4 z4 = make_float4(0.f, 0.f, 0.f, 0.f);

    f32x4 acc[4][4];
    #pragma unroll
    for (int i = 0; i < 4; ++i)
        #pragma unroll
        for (int j = 0; j < 4; ++j) acc[i][j] = (f32x4){0.f, 0.f, 0.f, 0.f};

    alignas(16) float pa[16], pw[16];
    #pragma unroll
    for (int q = 0; q < 4; ++q) {
        *(float4*)&pa[q * 4] = *(const float4*)(Ap + q * 4);
        *(float4*)&pw[q * 4] = wok ? *(const float4*)(Wp + q * 4) : z4;
    }

    for (int k0 = 0;;) {
        __syncthreads();
        {
            alignas(16) unsigned short hh[16], ll[16];
            const int base = srow * 40 + sco;
            #pragma unroll
            for (int i = 0; i < 16; ++i) {
                unsigned short h = f2bf(pa[i]);
                hh[i] = h; ll[i] = f2bf(pa[i] - bf2f(h));
            }
            *(uint4*)&Ah[base + 0] = *(uint4*)&hh[0];
            *(uint4*)&Ah[base + 8] = *(uint4*)&hh[8];
            *(uint4*)&Al[base + 0] = *(uint4*)&ll[0];
            *(uint4*)&Al[base + 8] = *(uint4*)&ll[8];
            #pragma unroll
            for (int i = 0; i < 16; ++i) {
                unsigned short h = f2bf(pw[i]);
                hh[i] = h; ll[i] = f2bf(pw[i] - bf2f(h));
            }
            *(uint4*)&Bh[base + 0] = *(uint4*)&hh[0];
            *(uint4*)&Bh[base + 8] = *(uint4*)&hh[8];
            *(uint4*)&Bl[base + 0] = *(uint4*)&ll[0];
            *(uint4*)&Bl[base + 8] = *(uint4*)&ll[8];
        }
        __syncthreads();
        const int kn = k0 + 32;
        if (kn < K) {
            #pragma unroll
            for (int q = 0; q < 4; ++q) {
                *(float4*)&pa[q * 4] = *(const float4*)(Ap + kn + q * 4);
                *(float4*)&pw[q * 4] = wok ? *(const float4*)(Wp + kn + q * 4) : z4;
            }
        }
        bf16x8 fah[4], fal[4], fbh[4], fbl[4];
        #pragma unroll
        for (int i = 0; i < 4; ++i) {
            const int ra = (wm + i * 16 + fr) * 40 + fg * 8;
            const int rb = (wn + i * 16 + fr) * 40 + fg * 8;
            fah[i] = *(const bf16x8*)&Ah[ra];
            fal[i] = *(const bf16x8*)&Al[ra];
            fbh[i] = *(const bf16x8*)&Bh[rb];
            fbl[i] = *(const bf16x8*)&Bl[rb];
        }
        #pragma unroll
        for (int i = 0; i < 4; ++i)
            #pragma unroll
            for (int j = 0; j < 4; ++j) {
                acc[i][j] = __builtin_amdgcn_mfma_f32_16x16x32_bf16(fal[i], fbh[j], acc[i][j], 0, 0, 0);
                acc[i][j] = __builtin_amdgcn_mfma_f32_16x16x32_bf16(fah[i], fbl[j], acc[i][j], 0, 0, 0);
                acc[i][j] = __builtin_amdgcn_mfma_f32_16x16x32_bf16(fah[i], fbh[j], acc[i][j], 0, 0, 0);
            }
        k0 = kn;
        if (k0 >= K) break;
    }

    #pragma unroll
    for (int i = 0; i < 4; ++i) {
        const int gmb = bm + wm + i * 16 + fg * 4;
        #pragma unroll
        for (int j = 0; j < 4; ++j) {
            const int gn = bn + wn + j * 16 + fr;
            if (gn >= N) continue;
            const float bv = bias ? bias[gn] : 0.f;
            #pragma unroll
            for (int r = 0; r < 4; ++r) {
                float v = acc[i][j][r] + bv;
                if (ACT == 1) v = (v > 20.f) ? v : log1pf(__expf(v));
                C[(size_t)(gmb + r) * N + gn] = v;
            }
        }
    }
}

// ---------------- f32 GEMM (accuracy-critical final projection) ----------------
template<int ACT, int NJ>
__global__ __launch_bounds__(256, 2) void gemm_kernel(
    const float* __restrict__ A, const float* __restrict__ W,
    const float* __restrict__ bias, float* __restrict__ C,
    int M, int N, int K, int lda)
{
    constexpr int TN = 16 * NJ;
    __shared__ float As[128 * 18];
    __shared__ float Ws[TN * 20];
    const int tid = threadIdx.x;
    const int bm = blockIdx.y * 128;
    const int bn = blockIdx.x * TN;
    const int tx = tid & 15;
    const int ty = tid >> 4;
    const int srow = tid >> 1;
    const int sc = (tid & 1) * 8;

    const float* Ap = A + (size_t)(bm + srow) * lda + sc;
    const float* Wp = W + (size_t)(bn + srow) * K + sc;
    const bool aok = (bm + srow) < M;
    const bool wok = (srow < TN) && ((bn + srow) < N);
    const float4 f0 = make_float4(0.f, 0.f, 0.f, 0.f);

    float4 na0 = f0, na1 = f0, nw0 = f0, nw1 = f0;
    if (aok) { na0 = *(const float4*)(Ap + 0); na1 = *(const float4*)(Ap + 4); }
    if (wok) { nw0 = *(const float4*)(Wp + 0); nw1 = *(const float4*)(Wp + 4); }

    float acc[8][NJ];
    #pragma unroll
    for (int i = 0; i < 8; ++i)
        #pragma unroll
        for (int j = 0; j < NJ; ++j) acc[i][j] = 0.f;

    for (int k0 = 0;;) {
        __syncthreads();
        {
            int wa = srow * 18 + sc;
            *(float2*)&As[wa + 0] = make_float2(na0.x, na0.y);
            *(float2*)&As[wa + 2] = make_float2(na0.z, na0.w);
            *(float2*)&As[wa + 4] = make_float2(na1.x, na1.y);
            *(float2*)&As[wa + 6] = make_float2(na1.z, na1.w);
            if (srow < TN) {
                int ww = srow * 20 + sc;
                *(float4*)&Ws[ww + 0] = nw0;
                *(float4*)&Ws[ww + 4] = nw1;
            }
        }
        __syncthreads();
        const int kn = k0 + 16;
        if (kn < K) {
            na0 = f0; na1 = f0;
            if (aok) { na0 = *(const float4*)(Ap + kn); na1 = *(const float4*)(Ap + kn + 4); }
            if (wok) { nw0 = *(const float4*)(Wp + kn); nw1 = *(const float4*)(Wp + kn + 4); }
        }
        #pragma unroll
        for (int k = 0; k < 16; k += 2) {
            float2 a2[8], b2[NJ];
            #pragma unroll
            for (int i = 0; i < 8; ++i)
                a2[i] = *(const float2*)&As[(ty * 8 + i) * 18 + k];
            #pragma unroll
            for (int j = 0; j < NJ; ++j)
                b2[j] = *(const float2*)&Ws[(tx + j * 16) * 20 + k];
            #pragma unroll
            for (int i = 0; i < 8; ++i)
                #pragma unroll
                for (int j = 0; j < NJ; ++j) {
                    acc[i][j] = fmaf(a2[i].x, b2[j].x, acc[i][j]);
                    acc[i][j] = fmaf(a2[i].y, b2[j].y, acc[i][j]);
                }
        }
        k0 = kn;
        if (k0 >= K) break;
    }

    #pragma unroll
    for (int i = 0; i < 8; ++i) {
        int gm = bm + ty * 8 + i;
        if (gm >= M) continue;
        #pragma unroll
        for (int j = 0; j < NJ; ++j) {
            int gn = bn + tx + j * 16;
            if (gn >= N) continue;
            float v = acc[i][j];
            if (bias) v += bias[gn];
            if (ACT == 1) v = (v > 20.f) ? v : log1pf(__expf(v));
            C[(size_t)gm * N + gn] = v;
        }
    }
}

// ---------------- reorder: xp(2,S,1024) -> x_both(4,S,512) ----------------
__global__ __launch_bounds__(256) void reorder_kernel(
    const float* __restrict__ xp, float* __restrict__ xboth)
{
    int idx = blockIdx.x * 256 + threadIdx.x;
    int c  = idx & 511;
    int t  = (idx >> 9) & 1023;
    int b4 = idx >> 19;
    float v;
    if (b4 < 2) v = xp[((size_t)(b4 * SEQL + t)) * DI + c];
    else        v = xp[((size_t)((b4 - 2) * SEQL + (1023 - t))) * DI + 512 + c];
    xboth[idx] = v;
}

// ---------------- depthwise causal conv (k=4) + silu ----------------
__global__ __launch_bounds__(256) void conv_silu_kernel(
    const float* __restrict__ xin, const float* __restrict__ cw,
    const float* __restrict__ cb, float* __restrict__ xc)
{
    int idx = blockIdx.x * 256 + threadIdx.x;
    int c = idx & (DI - 1);
    int t = (idx >> 10) & (SEQL - 1);
    int b = idx >> 20;
    float acc = cb[c];
    #pragma unroll
    for (int k = 0; k < 4; ++k) {
        int tt = t - 3 + k;
        if (tt >= 0) acc = fmaf(xin[((size_t)(b * SEQL + tt)) * DI + c], cw[c * 4 + k], acc);
    }
    float s = 1.f / (1.f + __expf(-acc));
    xc[idx] = acc * s;
}

// ============ chunked selective scan (unchanged from round 3) ============
__global__ __launch_bounds__(256, 3) void scan_part1(
    const float* __restrict__ dtp, const float* __restrict__ xcp,
    const float* __restrict__ xdbl, const float* __restrict__ A_log,
    float* __restrict__ Sbuf, float* __restrict__ SDbuf)
{
    const int blk = blockIdx.x;
    const int dblock = blk & 63;
    const int bc = blk >> 6;
    const int bb = bc / 3;
    const int c  = bc - bb * 3;
    const int wave = threadIdx.x >> 6;
    const int lane = threadIdx.x & 63;
    const int dd = lane >> 4;
    const int s4 = lane & 15;
    const int d = dblock * 16 + wave * 4 + dd;
    const float LOG2E = 1.4426950408889634f;

    float A2[4], h[4];
    #pragma unroll
    for (int k = 0; k < 4; ++k) {
        A2[k] = -__expf(A_log[d * DSTATE + s4 * 4 + k]) * LOG2E;
        h[k] = 0.f;
    }
    float sumdt = 0.f;
    const int T0 = c * 256;
    const size_t rb = (size_t)bb * SEQL * DI + (size_t)T0 * DI + d;
    const float* Bb = xdbl + ((size_t)bb * SEQL + T0) * XDBL_N + 32 + s4 * 4;

    float dt0[4], xc0[4]; float4 B0[4];
    float dt1[4], xc1[4]; float4 B1[4];

#define L1(t0, dt_, xc_, B_)                                           \
    { _Pragma("unroll")                                                \
      for (int i = 0; i < 4; ++i) {                                    \
        size_t ro = rb + (size_t)((t0) + i) * DI;                      \
        dt_[i] = dtp[ro];                                              \
        xc_[i] = xcp[ro];                                              \
        B_[i] = *(const float4*)(Bb + (size_t)((t0) + i) * XDBL_N);    \
      } }

#define C1(dt_, xc_, B_)                                               \
    { _Pragma("unroll")                                                \
      for (int i = 0; i < 4; ++i) {                                    \
        float dtv = dt_[i];                                            \
        sumdt += dtv;                                                  \
        float dtx = dtv * xc_[i];                                      \
        h[0] = fmaf(exp2f(dtv * A2[0]), h[0], dtx * B_[i].x);          \
        h[1] = fmaf(exp2f(dtv * A2[1]), h[1], dtx * B_[i].y);          \
        h[2] = fmaf(exp2f(dtv * A2[2]), h[2], dtx * B_[i].z);          \
        h[3] = fmaf(exp2f(dtv * A2[3]), h[3], dtx * B_[i].w);          \
      } }

    L1(0, dt0, xc0, B0);
    for (int g = 0; g < 64; g += 2) {
        L1((g + 1) * 4, dt1, xc1, B1);
        C1(dt0, xc0, B0);
        if (g + 2 < 64) L1((g + 2) * 4, dt0, xc0, B0);
        C1(dt1, xc1, B1);
    }
#undef L1
#undef C1

    const size_t so = ((size_t)bc * 1024 + d) * 64 + s4 * 4;
    *(float4*)&Sbuf[so] = make_float4(h[0], h[1], h[2], h[3]);
    if (s4 == 0) SDbuf[bc * 1024 + d] = sumdt;
}

__global__ __launch_bounds__(256, 4) void scan_part2(
    const float* dtp, float* yp,
    const float* __restrict__ xdbl,
    const float* __restrict__ xcp,
    const float* __restrict__ zp,
    const float* __restrict__ A_log,
    const float* __restrict__ Dpar,
    const float* __restrict__ Sbuf,
    const float* __restrict__ SDbuf)
{
    const int blk = blockIdx.x;
    const int dblock = blk & 63;
    const int bc = blk >> 6;
    const int bb = bc >> 2;
    const int c  = bc & 3;
    const int wave = threadIdx.x >> 6;
    const int lane = threadIdx.x & 63;
    const int dd = lane >> 4;
    const int s4 = lane & 15;
    const int d = dblock * 16 + wave * 4 + dd;
    const float LOG2E = 1.4426950408889634f;

    float A2[4], h[4];
    #pragma unroll
    for (int k = 0; k < 4; ++k) {
        A2[k] = -__expf(A_log[d * DSTATE + s4 * 4 + k]) * LOG2E;
        h[k] = 0.f;
    }
    for (int cc = 0; cc < c; ++cc) {
        const int bcc = bb * 3 + cc;
        const size_t so = ((size_t)bcc * 1024 + d) * 64 + s4 * 4;
        float4 S = *(const float4*)&Sbuf[so];
        float sd = SDbuf[bcc * 1024 + d];
        h[0] = fmaf(exp2f(A2[0] * sd), h[0], S.x);
        h[1] = fmaf(exp2f(A2[1] * sd), h[1], S.y);
        h[2] = fmaf(exp2f(A2[2] * sd), h[2], S.z);
        h[3] = fmaf(exp2f(A2[3] * sd), h[3], S.w);
    }

    const float Dv = Dpar[d];
    const int T0 = c * 256;
    const size_t rb = (size_t)bb * SEQL * DI + (size_t)T0 * DI + d;
    const float* Bb = xdbl + ((size_t)bb * SEQL + T0) * XDBL_N + 32 + s4 * 4;

    float dt0[4], xc0[4], z0[4]; float4 B0[4], C0[4];
    float dt1[4], xc1[4], z1[4]; float4 B1[4], C1[4];

#define LOADC(t0, dt_, xc_, z_, B_, C_)                                \
    { _Pragma("unroll")                                                \
      for (int i = 0; i < 4; ++i) {                                    \
        size_t ro = rb + (size_t)((t0) + i) * DI;                      \
        dt_[i] = dtp[ro];                                              \
        xc_[i] = xcp[ro];                                              \
        z_[i]  = zp[ro];                                               \
        const float* bp = Bb + (size_t)((t0) + i) * XDBL_N;            \
        B_[i] = *(const float4*)bp;                                    \
        C_[i] = *(const float4*)(bp + 64);                             \
      } }

#define COMPC(t0, dt_, xc_, z_, B_, C_)                                \
    { _Pragma("unroll")                                                \
      for (int i = 0; i < 4; ++i) {                                    \
        float dtv = dt_[i];                                            \
        float dtx = dtv * xc_[i];                                      \
        h[0] = fmaf(exp2f(dtv * A2[0]), h[0], dtx * B_[i].x);          \
        h[1] = fmaf(exp2f(dtv * A2[1]), h[1], dtx * B_[i].y);          \
        h[2] = fmaf(exp2f(dtv * A2[2]), h[2], dtx * B_[i].z);          \
        h[3] = fmaf(exp2f(dtv * A2[3]), h[3], dtx * B_[i].w);          \
        float p = h[0] * C_[i].x + h[1] * C_[i].y                      \
                + h[2] * C_[i].z + h[3] * C_[i].w;                     \
        p += __shfl_xor(p, 1);                                         \
        p += __shfl_xor(p, 2);                                         \
        p += __shfl_xor(p, 4);                                         \
        p += __shfl_xor(p, 8);                                         \
        float zv = z_[i];                                              \
        float y2 = (p + xc_[i] * Dv)                                   \
                 * __fdividef(zv, 1.f + __expf(-zv));                  \
        if (s4 == 0) yp[rb + (size_t)((t0) + i) * DI] = y2;            \
      } }

    LOADC(0, dt0, xc0, z0, B0, C0);
    for (int g = 0; g < 64; g += 2) {
        LOADC((g + 1) * 4, dt1, xc1, z1, B1, C1);
        COMPC(g * 4, dt0, xc0, z0, B0, C0);
        if (g + 2 < 64) LOADC((g + 2) * 4, dt0, xc0, z0, B0, C0);
        COMPC((g + 1) * 4, dt1, xc1, z1, B1, C1);
    }
#undef LOADC
#undef COMPC
}

// ---------------- combine: out5(4,S,512) -> combined(2,S,512) ----------------
__global__ __launch_bounds__(256) void combine_kernel(
    const float* __restrict__ out5, float* __restrict__ comb)
{
    int idx = blockIdx.x * 256 + threadIdx.x;
    int c = idx & 511;
    int t = (idx >> 9) & 1023;
    int b = idx >> 19;
    float vf = out5[((size_t)(b * SEQL + t)) * 512 + c];
    float vb = out5[((size_t)((2 + b) * SEQL + (1023 - t))) * 512 + c];
    comb[idx] = vf + vb;
}

extern "C" void kernel_launch(void* const* d_in, const int* in_sizes, int n_in,
                              void* d_out, int out_size, void* d_ws, size_t ws_size,
                              hipStream_t stream)
{
    const float* x        = (const float*)d_in[0];
    const float* W_in_bi  = (const float*)d_in[1];
    const float* b_in_bi  = (const float*)d_in[2];
    const float* W_out_bi = (const float*)d_in[3];
    const float* b_out_bi = (const float*)d_in[4];
    const float* W_in     = (const float*)d_in[5];
    const float* b_in     = (const float*)d_in[6];
    const float* conv_w   = (const float*)d_in[7];
    const float* conv_b   = (const float*)d_in[8];
    const float* W_x      = (const float*)d_in[9];
    const float* W_dt     = (const float*)d_in[10];
    const float* b_dt     = (const float*)d_in[11];
    const float* A_log    = (const float*)d_in[12];
    const float* D_param  = (const float*)d_in[13];
    const float* W_out    = (const float*)d_in[14];
    const float* b_out    = (const float*)d_in[15];
    float* outp = (float*)d_out;
    char* ws = (char*)d_ws;
    const size_t MB = (size_t)1 << 20;

    // workspace layout (peak ~53.6 MB):
    float* xp    = (float*)(ws + 0);        // 2048x1024 (8MB), dead after reorder
    float* xboth = (float*)(ws + 8 * MB);   // 4096x512  (8MB), dead after G2/G3
    float* xin   = (float*)(ws + 16 * MB);  // 4096x1024 (16MB), dead after conv
    float* zbuf  = (float*)(ws + 32 * MB);  // 4096x1024 (16MB), alive to scan
    float* xdbl  = (float*)(ws + 48 * MB);  // 4096x160 (2.5MB)
    float* xcb   = (float*)(ws + 0);        // 4096x1024 (16MB) over xp+xboth
    float* dtb   = (float*)(ws + 16 * MB);  // 4096x1024 over xin; scan writes y in-place
    float* Sbuf  = (float*)(ws + 48 * MB + 2621440);            // 4x3x1024x64 (3MB)
    float* SDb   = (float*)(ws + 48 * MB + 2621440 + 3145728);  // 4x3x1024 (48KB)
    float* out5  = (float*)(ws + 0);        // 4096x512 (8MB) over xcb
    float* comb  = (float*)(ws + 8 * MB);   // 2048x512 (4MB)

    dim3 blk(256, 1, 1);
    auto mg = [](int M, int N) {
        return dim3((unsigned)((N + 127) / 128), (unsigned)((M + 127) / 128), 1);
    };
    auto g32 = [](int M, int N) {
        return dim3((unsigned)((N + 31) / 32), (unsigned)((M + 127) / 128), 1);
    };

    // xp = x @ W_in_bi^T + b_in_bi
    mgemm_kernel<0><<<mg(2048, 1024), blk, 0, stream>>>(x, W_in_bi, b_in_bi, xp, 2048, 1024, 512, 512);
    // x_both
    reorder_kernel<<<dim3(8192), blk, 0, stream>>>(xp, xboth);
    // xz split into xin / z
    mgemm_kernel<0><<<mg(4096, 1024), blk, 0, stream>>>(xboth, W_in, b_in, xin, 4096, 1024, 512, 512);
    mgemm_kernel<0><<<mg(4096, 1024), blk, 0, stream>>>(xboth, W_in + 1024 * 512, b_in + 1024, zbuf, 4096, 1024, 512, 512);
    // depthwise conv + silu
    conv_silu_kernel<<<dim3(16384), blk, 0, stream>>>(xin, conv_w, conv_b, xcb);
    // x_dbl = xc @ W_x^T
    mgemm_kernel<0><<<mg(4096, 160), blk, 0, stream>>>(xcb, W_x, nullptr, xdbl, 4096, 160, 1024, 1024);
    // dt = softplus(dt_raw @ W_dt^T + b_dt)
    mgemm_kernel<1><<<mg(4096, 1024), blk, 0, stream>>>(xdbl, W_dt, b_dt, dtb, 4096, 1024, 32, 160);
    // chunked scan
    scan_part1<<<dim3(768), blk, 0, stream>>>(dtb, xcb, xdbl, A_log, Sbuf, SDb);
    scan_part2<<<dim3(1024), blk, 0, stream>>>(dtb, dtb, xdbl, xcb, zbuf, A_log, D_param, Sbuf, SDb);
    // out = y @ W_out^T + b_out
    mgemm_kernel<0><<<mg(4096, 512), blk, 0, stream>>>(dtb, W_out, b_out, out5, 4096, 512, 1024, 1024);
    // combine forward + flipped backward
    combine_kernel<<<dim3(4096), blk, 0, stream>>>(out5, comb);
    // final = combined @ W_out_bi^T + b_out_bi (f32 — accuracy-critical last hop)
    gemm_kernel<0, 2><<<g32(2048, 512), blk, 0, stream>>>(comb, W_out_bi, b_out_bi, outp, 2048, 512, 512, 512);
}

// Round 5
// 606.869 us; speedup vs baseline: 1.9268x; 1.1449x over previous
//
#include <hip/hip_runtime.h>
#include <hip/hip_bf16.h>
#include <math.h>

#define SEQL 1024
#define DI 1024
#define DSTATE 64
#define XDBL_N 160

typedef short bf16x8 __attribute__((ext_vector_type(8)));
typedef float f32x4 __attribute__((ext_vector_type(4)));

__device__ __forceinline__ unsigned short f2bf(float f) {
    unsigned u = __builtin_bit_cast(unsigned, f);
    u += 0x7FFFu + ((u >> 16) & 1u);
    return (unsigned short)(u >> 16);
}
__device__ __forceinline__ float bf2f(unsigned short h) {
    unsigned u = ((unsigned)h) << 16;
    return __builtin_bit_cast(float, u);
}
__device__ __forceinline__ void gload16(const void* g, void* l) {
    __builtin_amdgcn_global_load_lds((const __attribute__((address_space(1))) void*)g,
                                     (__attribute__((address_space(3))) void*)l, 16, 0, 0);
}

// ---------------- generic f32 -> bf16 hi/lo split ----------------
__global__ __launch_bounds__(256) void split_kernel(
    const float* __restrict__ src, unsigned short* __restrict__ h,
    unsigned short* __restrict__ l, int n4)
{
    int i = blockIdx.x * 256 + threadIdx.x;
    if (i >= n4) return;
    float4 v = ((const float4*)src)[i];
    unsigned short h0 = f2bf(v.x), h1 = f2bf(v.y), h2 = f2bf(v.z), h3 = f2bf(v.w);
    unsigned short l0 = f2bf(v.x - bf2f(h0)), l1 = f2bf(v.y - bf2f(h1));
    unsigned short l2 = f2bf(v.z - bf2f(h2)), l3 = f2bf(v.w - bf2f(h3));
    ((uint2*)h)[i] = make_uint2((unsigned)h0 | ((unsigned)h1 << 16), (unsigned)h2 | ((unsigned)h3 << 16));
    ((uint2*)l)[i] = make_uint2((unsigned)l0 | ((unsigned)l1 << 16), (unsigned)l2 | ((unsigned)l3 << 16));
}

// ---------- pre-split bf16 MFMA GEMM (pure, global_load_lds, dbuf) ----------
// A: Ah/Al (M,K) bf16 lda; W: Wh/Wl (N,K) bf16. C = act(A@W^T + bias) f32.
// Requires: M%128==0, N%128==0 (no masking), K%32==0. Tile 128x128, BK=32.
template<int ACT>
__global__ __launch_bounds__(256) void pgemm_kernel(
    const unsigned short* __restrict__ Ah, const unsigned short* __restrict__ Al,
    const unsigned short* __restrict__ Wh, const unsigned short* __restrict__ Wl,
    const float* __restrict__ bias, float* __restrict__ C,
    int M, int N, int K, int lda)
{
    __shared__ unsigned short L[2][4][128 * 32];   // [buf][Ah,Al,Wh,Wl]
    const int tid = threadIdx.x;
    const int bm = blockIdx.y * 128, bn = blockIdx.x * 128;
    const int wv = tid >> 6, lane = tid & 63;
    const int wm = (wv & 1) * 64, wn = (wv >> 1) * 64;
    const int fr = lane & 15, fg = lane >> 4;
    const int r0 = lane >> 2;            // row within 16-row slab
    const int csl = (lane & 3) * 8;      // ushort col offset (16B slot)
    const int wrow = wv * 32;            // wave's 32-row slab

    const unsigned short* gA[2] = {Ah, Al};
    const unsigned short* gW[2] = {Wh, Wl};

    f32x4 acc[4][4];
    #pragma unroll
    for (int i = 0; i < 4; ++i)
        #pragma unroll
        for (int j = 0; j < 4; ++j) acc[i][j] = (f32x4){0.f, 0.f, 0.f, 0.f};

    auto stage = [&](int buf, int kt) {
        const int kc = kt * 32 + csl;
        #pragma unroll
        for (int t = 0; t < 2; ++t) {
            const unsigned short* g = gA[t] + (size_t)(bm + wrow + r0) * lda + kc;
            unsigned short* lp = &L[buf][t][wrow * 32];
            gload16(g, lp);
            gload16(g + (size_t)16 * lda, lp + 16 * 32);
        }
        #pragma unroll
        for (int t = 0; t < 2; ++t) {
            const unsigned short* g = gW[t] + (size_t)(bn + wrow + r0) * K + kc;
            unsigned short* lp = &L[buf][2 + t][wrow * 32];
            gload16(g, lp);
            gload16(g + (size_t)16 * K, lp + 16 * 32);
        }
    };

    const int NT = K / 32;
    stage(0, 0);
    for (int kt = 0;;) {
        __syncthreads();                 // drains vmcnt: buf(kt) ready; prior reads done
        if (kt + 1 < NT) stage((kt + 1) & 1, kt + 1);
        const unsigned short* lah = &L[kt & 1][0][0];
        const unsigned short* lal = &L[kt & 1][1][0];
        const unsigned short* lbh = &L[kt & 1][2][0];
        const unsigned short* lbl = &L[kt & 1][3][0];
        bf16x8 fah[4], fal[4], fbh[4], fbl[4];
        #pragma unroll
        for (int i = 0; i < 4; ++i) {
            const int ra = (wm + i * 16 + fr) * 32 + fg * 8;
            const int rb = (wn + i * 16 + fr) * 32 + fg * 8;
            fah[i] = *(const bf16x8*)&lah[ra];
            fal[i] = *(const bf16x8*)&lal[ra];
            fbh[i] = *(const bf16x8*)&lbh[rb];
            fbl[i] = *(const bf16x8*)&lbl[rb];
        }
        #pragma unroll
        for (int i = 0; i < 4; ++i)
            #pragma unroll
            for (int j = 0; j < 4; ++j) {
                acc[i][j] = __builtin_amdgcn_mfma_f32_16x16x32_bf16(fal[i], fbh[j], acc[i][j], 0, 0, 0);
                acc[i][j] = __builtin_amdgcn_mfma_f32_16x16x32_bf16(fah[i], fbl[j], acc[i][j], 0, 0, 0);
                acc[i][j] = __builtin_amdgcn_mfma_f32_16x16x32_bf16(fah[i], fbh[j], acc[i][j], 0, 0, 0);
            }
        ++kt;
        if (kt >= NT) break;
    }

    #pragma unroll
    for (int i = 0; i < 4; ++i) {
        const int gmb = bm + wm + i * 16 + fg * 4;
        #pragma unroll
        for (int j = 0; j < 4; ++j) {
            const int gn = bn + wn + j * 16 + fr;
            const float bv = bias ? bias[gn] : 0.f;
            #pragma unroll
            for (int r = 0; r < 4; ++r) {
                float v = acc[i][j][r] + bv;
                if (ACT == 1) v = (v > 20.f) ? v : log1pf(__expf(v));
                C[(size_t)(gmb + r) * N + gn] = v;
            }
        }
    }
}

// ---------- A-f32 MFMA GEMM: A converted in-kernel, W pre-split ----------
// GATE: A-elem = A * silu(Z). DUAL: also emit bf16 hi/lo of C for gn<32.
template<int ACT, bool DUAL, bool GATE>
__global__ __launch_bounds__(256) void agemm_kernel(
    const float* __restrict__ A, const float* __restrict__ Z,
    const unsigned short* __restrict__ Wh, const unsigned short* __restrict__ Wl,
    const float* __restrict__ bias, float* __restrict__ C,
    unsigned short* __restrict__ dh, unsigned short* __restrict__ dl,
    int M, int N, int K, int lda)
{
    __shared__ unsigned short LAh[128 * 40];
    __shared__ unsigned short LAl[128 * 40];
    __shared__ unsigned short LBh[128 * 40];
    __shared__ unsigned short LBl[128 * 40];
    const int tid = threadIdx.x;
    const int bm = blockIdx.y * 128, bn = blockIdx.x * 128;
    const int srow = tid >> 1, sco = (tid & 1) * 16;
    const int wv = tid >> 6, lane = tid & 63;
    const int wm = (wv & 1) * 64, wn = (wv >> 1) * 64;
    const int fr = lane & 15, fg = lane >> 4;

    const float* Ap = A + (size_t)(bm + srow) * lda + sco;
    const float* Zp = GATE ? (Z + (size_t)(bm + srow) * lda + sco) : nullptr;
    const unsigned short* Whp = Wh + (size_t)(bn + srow) * K + sco;
    const unsigned short* Wlp = Wl + (size_t)(bn + srow) * K + sco;
    const bool wok = (bn + srow) < N;
    const uint4 zu = {0u, 0u, 0u, 0u};

    f32x4 acc[4][4];
    #pragma unroll
    for (int i = 0; i < 4; ++i)
        #pragma unroll
        for (int j = 0; j < 4; ++j) acc[i][j] = (f32x4){0.f, 0.f, 0.f, 0.f};

    alignas(16) float pa[16], pz[16];
    uint4 pbh[2], pbl[2];

    auto prefetch = [&](int k) {
        #pragma unroll
        for (int q = 0; q < 4; ++q) *(float4*)&pa[q * 4] = *(const float4*)(Ap + k + q * 4);
        if (GATE) {
            #pragma unroll
            for (int q = 0; q < 4; ++q) *(float4*)&pz[q * 4] = *(const float4*)(Zp + k + q * 4);
        }
        if (wok) {
            pbh[0] = *(const uint4*)(Whp + k); pbh[1] = *(const uint4*)(Whp + k + 8);
            pbl[0] = *(const uint4*)(Wlp + k); pbl[1] = *(const uint4*)(Wlp + k + 8);
        } else { pbh[0] = zu; pbh[1] = zu; pbl[0] = zu; pbl[1] = zu; }
    };

    prefetch(0);
    const int NT = K / 32;
    for (int kt = 0;;) {
        __syncthreads();
        {
            alignas(16) unsigned short hh[16], ll[16];
            #pragma unroll
            for (int i = 0; i < 16; ++i) {
                float v = pa[i];
                if (GATE) { float zz = pz[i]; v = v * (zz / (1.f + __expf(-zz))); }
                unsigned short h = f2bf(v);
                hh[i] = h; ll[i] = f2bf(v - bf2f(h));
            }
            const int wb = srow * 40 + sco;
            *(uint4*)&LAh[wb + 0] = *(uint4*)&hh[0];
            *(uint4*)&LAh[wb + 8] = *(uint4*)&hh[8];
            *(uint4*)&LAl[wb + 0] = *(uint4*)&ll[0];
            *(uint4*)&LAl[wb + 8] = *(uint4*)&ll[8];
            *(uint4*)&LBh[wb + 0] = pbh[0];
            *(uint4*)&LBh[wb + 8] = pbh[1];
            *(uint4*)&LBl[wb + 0] = pbl[0];
            *(uint4*)&LBl[wb + 8] = pbl[1];
        }
        __syncthreads();
        if (kt + 1 < NT) prefetch((kt + 1) * 32);
        bf16x8 fah[4], fal[4], fbh[4], fbl[4];
        #pragma unroll
        for (int i = 0; i < 4; ++i) {
            const int ra = (wm + i * 16 + fr) * 40 + fg * 8;
            const int rb = (wn + i * 16 + fr) * 40 + fg * 8;
            fah[i] = *(const bf16x8*)&LAh[ra];
            fal[i] = *(const bf16x8*)&LAl[ra];
            fbh[i] = *(const bf16x8*)&LBh[rb];
            fbl[i] = *(const bf16x8*)&LBl[rb];
        }
        #pragma unroll
        for (int i = 0; i < 4; ++i)
            #pragma unroll
            for (int j = 0; j < 4; ++j) {
                acc[i][j] = __builtin_amdgcn_mfma_f32_16x16x32_bf16(fal[i], fbh[j], acc[i][j], 0, 0, 0);
                acc[i][j] = __builtin_amdgcn_mfma_f32_16x16x32_bf16(fah[i], fbl[j], acc[i][j], 0, 0, 0);
                acc[i][j] = __builtin_amdgcn_mfma_f32_16x16x32_bf16(fah[i], fbh[j], acc[i][j], 0, 0, 0);
            }
        ++kt;
        if (kt >= NT) break;
    }

    #pragma unroll
    for (int i = 0; i < 4; ++i) {
        const int gmb = bm + wm + i * 16 + fg * 4;
        #pragma unroll
        for (int j = 0; j < 4; ++j) {
            const int gn = bn + wn + j * 16 + fr;
            if (gn >= N) continue;
            const float bv = bias ? bias[gn] : 0.f;
            #pragma unroll
            for (int r = 0; r < 4; ++r) {
                float v = acc[i][j][r] + bv;
                if (ACT == 1) v = (v > 20.f) ? v : log1pf(__expf(v));
                C[(size_t)(gmb + r) * N + gn] = v;
                if (DUAL && gn < 32) {
                    unsigned short h = f2bf(v);
                    dh[(size_t)(gmb + r) * 32 + gn] = h;
                    dl[(size_t)(gmb + r) * 32 + gn] = f2bf(v - bf2f(h));
                }
            }
        }
    }
}

// ---------------- f32 GEMM (accuracy-critical final projection) ----------------
template<int ACT, int NJ>
__global__ __launch_bounds__(256, 2) void gemm_kernel(
    const float* __restrict__ A, const float* __restrict__ W,
    const float* __restrict__ bias, float* __restrict__ C,
    int M, int N, int K, int lda)
{
    constexpr int TN = 16 * NJ;
    __shared__ float As[128 * 18];
    __shared__ float Ws[TN * 20];
    const int tid = threadIdx.x;
    const int bm = blockIdx.y * 128;
    const int bn = blockIdx.x * TN;
    const int tx = tid & 15;
    const int ty = tid >> 4;
    const int srow = tid >> 1;
    const int sc = (tid & 1) * 8;

    const float* Ap = A + (size_t)(bm + srow) * lda + sc;
    const float* Wp = W + (size_t)(bn + srow) * K + sc;
    const bool aok = (bm + srow) < M;
    const bool wok = (srow < TN) && ((bn + srow) < N);
    const float4 f0 = make_float4(0.f, 0.f, 0.f, 0.f);

    float4 na0 = f0, na1 = f0, nw0 = f0, nw1 = f0;
    if (aok) { na0 = *(const float4*)(Ap + 0); na1 = *(const float4*)(Ap + 4); }
    if (wok) { nw0 = *(const float4*)(Wp + 0); nw1 = *(const float4*)(Wp + 4); }

    float acc[8][NJ];
    #pragma unroll
    for (int i = 0; i < 8; ++i)
        #pragma unroll
        for (int j = 0; j < NJ; ++j) acc[i][j] = 0.f;

    for (int k0 = 0;;) {
        __syncthreads();
        {
            int wa = srow * 18 + sc;
            *(float2*)&As[wa + 0] = make_float2(na0.x, na0.y);
            *(float2*)&As[wa + 2] = make_float2(na0.z, na0.w);
            *(float2*)&As[wa + 4] = make_float2(na1.x, na1.y);
            *(float2*)&As[wa + 6] = make_float2(na1.z, na1.w);
            if (srow < TN) {
                int ww = srow * 20 + sc;
                *(float4*)&Ws[ww + 0] = nw0;
                *(float4*)&Ws[ww + 4] = nw1;
            }
        }
        __syncthreads();
        const int kn = k0 + 16;
        if (kn < K) {
            na0 = f0; na1 = f0;
            if (aok) { na0 = *(const float4*)(Ap + kn); na1 = *(const float4*)(Ap + kn + 4); }
            if (wok) { nw0 = *(const float4*)(Wp + kn); nw1 = *(const float4*)(Wp + kn + 4); }
        }
        #pragma unroll
        for (int k = 0; k < 16; k += 2) {
            float2 a2[8], b2[NJ];
            #pragma unroll
            for (int i = 0; i < 8; ++i)
                a2[i] = *(const float2*)&As[(ty * 8 + i) * 18 + k];
            #pragma unroll
            for (int j = 0; j < NJ; ++j)
                b2[j] = *(const float2*)&Ws[(tx + j * 16) * 20 + k];
            #pragma unroll
            for (int i = 0; i < 8; ++i)
                #pragma unroll
                for (int j = 0; j < NJ; ++j) {
                    acc[i][j] = fmaf(a2[i].x, b2[j].x, acc[i][j]);
                    acc[i][j] = fmaf(a2[i].y, b2[j].y, acc[i][j]);
                }
        }
        k0 = kn;
        if (k0 >= K) break;
    }

    #pragma unroll
    for (int i = 0; i < 8; ++i) {
        int gm = bm + ty * 8 + i;
        if (gm >= M) continue;
        #pragma unroll
        for (int j = 0; j < NJ; ++j) {
            int gn = bn + tx + j * 16;
            if (gn >= N) continue;
            float v = acc[i][j];
            if (bias) v += bias[gn];
            if (ACT == 1) v = (v > 20.f) ? v : log1pf(__expf(v));
            C[(size_t)gm * N + gn] = v;
        }
    }
}

// ------- reorder + split: xp(2,S,1024) -> xboth(4,S,512) bf16 hi/lo -------
__global__ __launch_bounds__(256) void reorder_split_kernel(
    const float* __restrict__ xp, unsigned short* __restrict__ xh,
    unsigned short* __restrict__ xl)
{
    int idx = blockIdx.x * 256 + threadIdx.x;    // over 4*1024*128 float4 groups
    int c4 = idx & 127;
    int t  = (idx >> 7) & 1023;
    int b4 = idx >> 17;
    float4 v;
    if (b4 < 2) v = *(const float4*)&xp[((size_t)(b4 * SEQL + t)) * DI + c4 * 4];
    else        v = *(const float4*)&xp[((size_t)((b4 - 2) * SEQL + (1023 - t))) * DI + 512 + c4 * 4];
    unsigned short h0 = f2bf(v.x), h1 = f2bf(v.y), h2 = f2bf(v.z), h3 = f2bf(v.w);
    unsigned short l0 = f2bf(v.x - bf2f(h0)), l1 = f2bf(v.y - bf2f(h1));
    unsigned short l2 = f2bf(v.z - bf2f(h2)), l3 = f2bf(v.w - bf2f(h3));
    ((uint2*)xh)[idx] = make_uint2((unsigned)h0 | ((unsigned)h1 << 16), (unsigned)h2 | ((unsigned)h3 << 16));
    ((uint2*)xl)[idx] = make_uint2((unsigned)l0 | ((unsigned)l1 << 16), (unsigned)l2 | ((unsigned)l3 << 16));
}

// ---------------- depthwise causal conv (k=4) + silu ----------------
__global__ __launch_bounds__(256) void conv_silu_kernel(
    const float* __restrict__ xin, const float* __restrict__ cw,
    const float* __restrict__ cb, float* __restrict__ xc)
{
    int idx = blockIdx.x * 256 + threadIdx.x;
    int c = idx & (DI - 1);
    int t = (idx >> 10) & (SEQL - 1);
    int b = idx >> 20;
    float acc = cb[c];
    #pragma unroll
    for (int k = 0; k < 4; ++k) {
        int tt = t - 3 + k;
        if (tt >= 0) acc = fmaf(xin[((size_t)(b * SEQL + tt)) * DI + c], cw[c * 4 + k], acc);
    }
    float s = 1.f / (1.f + __expf(-acc));
    xc[idx] = acc * s;
}

// ============ chunked selective scan ============
__global__ __launch_bounds__(256, 3) void scan_part1(
    const float* __restrict__ dtp, const float* __restrict__ xcp,
    const float* __restrict__ xdbl, const float* __restrict__ A_log,
    float* __restrict__ Sbuf, float* __restrict__ SDbuf)
{
    const int blk = blockIdx.x;
    const int dblock = blk & 63;
    const int bc = blk >> 6;
    const int bb = bc / 3;
    const int c  = bc - bb * 3;
    const int wave = threadIdx.x >> 6;
    const int lane = threadIdx.x & 63;
    const int dd = lane >> 4;
    const int s4 = lane & 15;
    const int d = dblock * 16 + wave * 4 + dd;
    const float LOG2E = 1.4426950408889634f;

    float A2[4], h[4];
    #pragma unroll
    for (int k = 0; k < 4; ++k) {
        A2[k] = -__expf(A_log[d * DSTATE + s4 * 4 + k]) * LOG2E;
        h[k] = 0.f;
    }
    float sumdt = 0.f;
    const int T0 = c * 256;
    const size_t rb = (size_t)bb * SEQL * DI + (size_t)T0 * DI + d;
    const float* Bb = xdbl + ((size_t)bb * SEQL + T0) * XDBL_N + 32 + s4 * 4;

    float dt0[4], xc0[4]; float4 B0[4];
    float dt1[4], xc1[4]; float4 B1[4];

#define L1(t0, dt_, xc_, B_)                                           \
    { _Pragma("unroll")                                                \
      for (int i = 0; i < 4; ++i) {                                    \
        size_t ro = rb + (size_t)((t0) + i) * DI;                      \
        dt_[i] = dtp[ro];                                              \
        xc_[i] = xcp[ro];                                              \
        B_[i] = *(const float4*)(Bb + (size_t)((t0) + i) * XDBL_N);    \
      } }

#define C1(dt_, xc_, B_)                                               \
    { _Pragma("unroll")                                                \
      for (int i = 0; i < 4; ++i) {                                    \
        float dtv = dt_[i];                                            \
        sumdt += dtv;                                                  \
        float dtx = dtv * xc_[i];                                      \
        h[0] = fmaf(exp2f(dtv * A2[0]), h[0], dtx * B_[i].x);          \
        h[1] = fmaf(exp2f(dtv * A2[1]), h[1], dtx * B_[i].y);          \
        h[2] = fmaf(exp2f(dtv * A2[2]), h[2], dtx * B_[i].z);          \
        h[3] = fmaf(exp2f(dtv * A2[3]), h[3], dtx * B_[i].w);          \
      } }

    L1(0, dt0, xc0, B0);
    for (int g = 0; g < 64; g += 2) {
        L1((g + 1) * 4, dt1, xc1, B1);
        C1(dt0, xc0, B0);
        if (g + 2 < 64) L1((g + 2) * 4, dt0, xc0, B0);
        C1(dt1, xc1, B1);
    }
#undef L1
#undef C1

    const size_t so = ((size_t)bc * 1024 + d) * 64 + s4 * 4;
    *(float4*)&Sbuf[so] = make_float4(h[0], h[1], h[2], h[3]);
    if (s4 == 0) SDbuf[bc * 1024 + d] = sumdt;
}

// pass 2: full scan + reduce; epilogue y = p + xc*D (gate applied in Gout).
// yp may alias dtp (stores trail prefetched reads; disjoint regions per block).
__global__ __launch_bounds__(256, 4) void scan_part2(
    const float* dtp, float* yp,
    const float* __restrict__ xdbl,
    const float* __restrict__ xcp,
    const float* __restrict__ A_log,
    const float* __restrict__ Dpar,
    const float* __restrict__ Sbuf,
    const float* __restrict__ SDbuf)
{
    const int blk = blockIdx.x;
    const int dblock = blk & 63;
    const int bc = blk >> 6;
    const int bb = bc >> 2;
    const int c  = bc & 3;
    const int wave = threadIdx.x >> 6;
    const int lane = threadIdx.x & 63;
    const int dd = lane >> 4;
    const int s4 = lane & 15;
    const int d = dblock * 16 + wave * 4 + dd;
    const float LOG2E = 1.4426950408889634f;

    float A2[4], h[4];
    #pragma unroll
    for (int k = 0; k < 4; ++k) {
        A2[k] = -__expf(A_log[d * DSTATE + s4 * 4 + k]) * LOG2E;
        h[k] = 0.f;
    }
    for (int cc = 0; cc < c; ++cc) {
        const int bcc = bb * 3 + cc;
        const size_t so = ((size_t)bcc * 1024 + d) * 64 + s4 * 4;
        float4 S = *(const float4*)&Sbuf[so];
        float sd = SDbuf[bcc * 1024 + d];
        h[0] = fmaf(exp2f(A2[0] * sd), h[0], S.x);
        h[1] = fmaf(exp2f(A2[1] * sd), h[1], S.y);
        h[2] = fmaf(exp2f(A2[2] * sd), h[2], S.z);
        h[3] = fmaf(exp2f(A2[3] * sd), h[3], S.w);
    }

    const float Dv = Dpar[d];
    const int T0 = c * 256;
    const size_t rb = (size_t)bb * SEQL * DI + (size_t)T0 * DI + d;
    const float* Bb = xdbl + ((size_t)bb * SEQL + T0) * XDBL_N + 32 + s4 * 4;

    float dt0[4], xc0[4]; float4 B0[4], C0[4];
    float dt1[4], xc1[4]; float4 B1[4], C1[4];

#define LOADC(t0, dt_, xc_, B_, C_)                                    \
    { _Pragma("unroll")                                                \
      for (int i = 0; i < 4; ++i) {                                    \
        size_t ro = rb + (size_t)((t0) + i) * DI;                      \
        dt_[i] = dtp[ro];                                              \
        xc_[i] = xcp[ro];                                              \
        const float* bp = Bb + (size_t)((t0) + i) * XDBL_N;            \
        B_[i] = *(const float4*)bp;                                    \
        C_[i] = *(const float4*)(bp + 64);                             \
      } }

#define COMPC(t0, dt_, xc_, B_, C_)                                    \
    { _Pragma("unroll")                                                \
      for (int i = 0; i < 4; ++i) {                                    \
        float dtv = dt_[i];                                            \
        float dtx = dtv * xc_[i];                                      \
        h[0] = fmaf(exp2f(dtv * A2[0]), h[0], dtx * B_[i].x);          \
        h[1] = fmaf(exp2f(dtv * A2[1]), h[1], dtx * B_[i].y);          \
        h[2] = fmaf(exp2f(dtv * A2[2]), h[2], dtx * B_[i].z);          \
        h[3] = fmaf(exp2f(dtv * A2[3]), h[3], dtx * B_[i].w);          \
        float p = h[0] * C_[i].x + h[1] * C_[i].y                      \
                + h[2] * C_[i].z + h[3] * C_[i].w;                     \
        p += __shfl_xor(p, 1);                                         \
        p += __shfl_xor(p, 2);                                         \
        p += __shfl_xor(p, 4);                                         \
        p += __shfl_xor(p, 8);                                         \
        float y2 = p + xc_[i] * Dv;                                    \
        if (s4 == 0) yp[rb + (size_t)((t0) + i) * DI] = y2;            \
      } }

    LOADC(0, dt0, xc0, B0, C0);
    for (int g = 0; g < 64; g += 2) {
        LOADC((g + 1) * 4, dt1, xc1, B1, C1);
        COMPC(g * 4, dt0, xc0, B0, C0);
        if (g + 2 < 64) LOADC((g + 2) * 4, dt0, xc0, B0, C0);
        COMPC((g + 1) * 4, dt1, xc1, B1, C1);
    }
#undef LOADC
#undef COMPC
}

// ---------------- combine: out5(4,S,512) -> combined(2,S,512) ----------------
__global__ __launch_bounds__(256) void combine_kernel(
    const float* __restrict__ out5, float* __restrict__ comb)
{
    int idx = blockIdx.x * 256 + threadIdx.x;
    int c = idx & 511;
    int t = (idx >> 9) & 1023;
    int b = idx >> 19;
    float vf = out5[((size_t)(b * SEQL + t)) * 512 + c];
    float vb = out5[((size_t)((2 + b) * SEQL + (1023 - t))) * 512 + c];
    comb[idx] = vf + vb;
}

extern "C" void kernel_launch(void* const* d_in, const int* in_sizes, int n_in,
                              void* d_out, int out_size, void* d_ws, size_t ws_size,
                              hipStream_t stream)
{
    const float* x        = (const float*)d_in[0];
    const float* W_in_bi  = (const float*)d_in[1];
    const float* b_in_bi  = (const float*)d_in[2];
    const float* W_out_bi = (const float*)d_in[3];
    const float* b_out_bi = (const float*)d_in[4];
    const float* W_in     = (const float*)d_in[5];
    const float* b_in     = (const float*)d_in[6];
    const float* conv_w   = (const float*)d_in[7];
    const float* conv_b   = (const float*)d_in[8];
    const float* W_x      = (const float*)d_in[9];
    const float* W_dt     = (const float*)d_in[10];
    const float* b_dt     = (const float*)d_in[11];
    const float* A_log    = (const float*)d_in[12];
    const float* D_param  = (const float*)d_in[13];
    const float* W_out    = (const float*)d_in[14];
    const float* b_out    = (const float*)d_in[15];
    float* outp = (float*)d_out;
    char* ws = (char*)d_ws;
    const size_t MB = (size_t)1 << 20;
    typedef unsigned short us;

    // ---- workspace layout (max offset 53.55 MB; lifetime-packed) ----
    float* zbuf = (float*)(ws + 0);          // 16MB [G3 -> Gout]
    float* xcb  = (float*)(ws + 16 * MB);    // 16MB [conv -> part2]
    float* dtb  = (float*)(ws + 32 * MB);    // 16MB [Gdt -> part2; y in place -> Gout]
    float* xdbl = (float*)(ws + 48 * MB);    // 2.5MB [Gx -> part2]
    float* Sbuf = (float*)(ws + 48 * MB + 2621440);             // 3MB [part1 -> part2]
    float* SDb  = (float*)(ws + 48 * MB + 2621440 + 3145728);   // 48KB
    // early tenants of zbuf region:
    float* xp   = (float*)(ws + 0);          // 8MB [G1 -> reorder]
    // early tenants of xcb region:
    us* xbh   = (us*)(ws + 16 * MB);         // 4MB [reorder -> G3]
    us* xbl   = (us*)(ws + 20 * MB);
    us* Win_h = (us*)(ws + 24 * MB);         // 2MB [-> G3]
    us* Win_l = (us*)(ws + 26 * MB);
    us* Wbi_h = (us*)(ws + 28 * MB);         // 1MB [-> G1]
    us* Wbi_l = (us*)(ws + 29 * MB);
    // late tenants of xcb region (after part2):
    us* Wout_h = (us*)(ws + 16 * MB);        // 1MB [-> Gout]
    us* Wout_l = (us*)(ws + 17 * MB);
    float* out5 = (float*)(ws + 18 * MB);    // 8MB [Gout -> combine]
    float* comb = (float*)(ws + 26 * MB);    // 4MB [combine -> final]
    // early tenant of dtb region:
    float* xin = (float*)(ws + 32 * MB);     // 16MB [G2 -> conv]
    // early tenants of Sbuf region (dead before part1):
    us* Wx_h  = (us*)(ws + 48 * MB + 2621440);            // 320KB [-> Gx]
    us* Wx_l  = (us*)(ws + 48 * MB + 2621440 + 327680);
    us* Wdt_h = (us*)(ws + 48 * MB + 2621440 + 655360);   // 64KB [-> Gdt]
    us* Wdt_l = (us*)(ws + 48 * MB + 2621440 + 720896);
    us* dtr_h = (us*)(ws + 48 * MB + 2621440 + 786432);   // 256KB [Gx -> Gdt]
    us* dtr_l = (us*)(ws + 48 * MB + 2621440 + 1048576);

    dim3 blk(256, 1, 1);

    // weight splits (cheap, inputs only)
    split_kernel<<<dim3(512), blk, 0, stream>>>(W_in_bi, Wbi_h, Wbi_l, 131072);
    split_kernel<<<dim3(1024), blk, 0, stream>>>(W_in, Win_h, Win_l, 262144);
    split_kernel<<<dim3(160), blk, 0, stream>>>(W_x, Wx_h, Wx_l, 40960);
    split_kernel<<<dim3(32), blk, 0, stream>>>(W_dt, Wdt_h, Wdt_l, 8192);

    // G1: xp = x @ W_in_bi^T + b_in_bi   (A f32, W pre-split)
    agemm_kernel<0, false, false><<<dim3(8, 16), blk, 0, stream>>>(
        x, nullptr, Wbi_h, Wbi_l, b_in_bi, xp, nullptr, nullptr, 2048, 1024, 512, 512);
    // reorder + split -> bf16 hi/lo
    reorder_split_kernel<<<dim3(2048), blk, 0, stream>>>(xp, xbh, xbl);
    // G2/G3: pure pre-split GEMMs
    pgemm_kernel<0><<<dim3(8, 32), blk, 0, stream>>>(
        xbh, xbl, Win_h, Win_l, b_in, xin, 4096, 1024, 512, 512);
    pgemm_kernel<0><<<dim3(8, 32), blk, 0, stream>>>(
        xbh, xbl, Win_h + 1024 * 512, Win_l + 1024 * 512, b_in + 1024, zbuf, 4096, 1024, 512, 512);
    // depthwise conv + silu
    conv_silu_kernel<<<dim3(16384), blk, 0, stream>>>(xin, conv_w, conv_b, xcb);
    // Gx: x_dbl = xc @ W_x^T  (+ fused bf16 split of dt_raw cols 0..31)
    agemm_kernel<0, true, false><<<dim3(2, 32), blk, 0, stream>>>(
        xcb, nullptr, Wx_h, Wx_l, nullptr, xdbl, dtr_h, dtr_l, 4096, 160, 1024, 1024);
    // Gdt: dt = softplus(dt_raw @ W_dt^T + b_dt)
    pgemm_kernel<1><<<dim3(8, 32), blk, 0, stream>>>(
        dtr_h, dtr_l, Wdt_h, Wdt_l, b_dt, dtb, 4096, 1024, 32, 32);
    // chunked scan (y = p + xc*D written over dtb; gate deferred to Gout)
    scan_part1<<<dim3(768), blk, 0, stream>>>(dtb, xcb, xdbl, A_log, Sbuf, SDb);
    scan_part2<<<dim3(1024), blk, 0, stream>>>(dtb, dtb, xdbl, xcb, A_log, D_param, Sbuf, SDb);
    // W_out split (into dead xcb region), then Gout with fused silu(z) gate
    split_kernel<<<dim3(512), blk, 0, stream>>>(W_out, Wout_h, Wout_l, 131072);
    agemm_kernel<0, false, true><<<dim3(4, 32), blk, 0, stream>>>(
        dtb, zbuf, Wout_h, Wout_l, b_out, out5, nullptr, nullptr, 4096, 512, 1024, 1024);
    // combine forward + flipped backward
    combine_kernel<<<dim3(4096), blk, 0, stream>>>(out5, comb);
    // final = combined @ W_out_bi^T + b_out_bi (f32 — accuracy-critical last hop)
    gemm_kernel<0, 2><<<dim3(16, 16), blk, 0, stream>>>(comb, W_out_bi, b_out_bi, outp, 2048, 512, 512, 512);
}

// Round 6
// 603.152 us; speedup vs baseline: 1.9387x; 1.0062x over previous
//
#include <hip/hip_runtime.h>
#include <hip/hip_bf16.h>
#include <math.h>

#define SEQL 1024
#define DI 1024
#define DSTATE 64
#define XDBL_N 160

typedef short bf16x8 __attribute__((ext_vector_type(8)));
typedef float f32x4 __attribute__((ext_vector_type(4)));

__device__ __forceinline__ unsigned short f2bf(float f) {
    unsigned u = __builtin_bit_cast(unsigned, f);
    u += 0x7FFFu + ((u >> 16) & 1u);
    return (unsigned short)(u >> 16);
}
__device__ __forceinline__ float bf2f(unsigned short h) {
    unsigned u = ((unsigned)h) << 16;
    return __builtin_bit_cast(float, u);
}
__device__ __forceinline__ void gload16(const void* g, void* l) {
    __builtin_amdgcn_global_load_lds((const __attribute__((address_space(1))) void*)g,
                                     (__attribute__((address_space(3))) void*)l, 16, 0, 0);
}
// 16-lane row-sum via DPP row_shr (full-rate VALU, no LDS). Sum lands in
// lane (row*16+0); other lanes hold partials. 0x110|n = row_shr:n.
__device__ __forceinline__ float dppsum16(float p) {
    int q;
    q = __builtin_amdgcn_update_dpp(0, __builtin_bit_cast(int, p), 0x118, 0xF, 0xF, true);
    p += __builtin_bit_cast(float, q);
    q = __builtin_amdgcn_update_dpp(0, __builtin_bit_cast(int, p), 0x114, 0xF, 0xF, true);
    p += __builtin_bit_cast(float, q);
    q = __builtin_amdgcn_update_dpp(0, __builtin_bit_cast(int, p), 0x112, 0xF, 0xF, true);
    p += __builtin_bit_cast(float, q);
    q = __builtin_amdgcn_update_dpp(0, __builtin_bit_cast(int, p), 0x111, 0xF, 0xF, true);
    p += __builtin_bit_cast(float, q);
    return p;
}

// ---------------- generic f32 -> bf16 hi/lo split ----------------
__global__ __launch_bounds__(256) void split_kernel(
    const float* __restrict__ src, unsigned short* __restrict__ h,
    unsigned short* __restrict__ l, int n4)
{
    int i = blockIdx.x * 256 + threadIdx.x;
    if (i >= n4) return;
    float4 v = ((const float4*)src)[i];
    unsigned short h0 = f2bf(v.x), h1 = f2bf(v.y), h2 = f2bf(v.z), h3 = f2bf(v.w);
    unsigned short l0 = f2bf(v.x - bf2f(h0)), l1 = f2bf(v.y - bf2f(h1));
    unsigned short l2 = f2bf(v.z - bf2f(h2)), l3 = f2bf(v.w - bf2f(h3));
    ((uint2*)h)[i] = make_uint2((unsigned)h0 | ((unsigned)h1 << 16), (unsigned)h2 | ((unsigned)h3 << 16));
    ((uint2*)l)[i] = make_uint2((unsigned)l0 | ((unsigned)l1 << 16), (unsigned)l2 | ((unsigned)l3 << 16));
}

// ---------- pre-split bf16 MFMA GEMM (pure, global_load_lds, dbuf) ----------
template<int ACT>
__global__ __launch_bounds__(256) void pgemm_kernel(
    const unsigned short* __restrict__ Ah, const unsigned short* __restrict__ Al,
    const unsigned short* __restrict__ Wh, const unsigned short* __restrict__ Wl,
    const float* __restrict__ bias, float* __restrict__ C,
    int M, int N, int K, int lda)
{
    __shared__ unsigned short L[2][4][128 * 32];   // [buf][Ah,Al,Wh,Wl]
    const int tid = threadIdx.x;
    const int bm = blockIdx.y * 128, bn = blockIdx.x * 128;
    const int wv = tid >> 6, lane = tid & 63;
    const int wm = (wv & 1) * 64, wn = (wv >> 1) * 64;
    const int fr = lane & 15, fg = lane >> 4;
    const int r0 = lane >> 2;
    const int csl = (lane & 3) * 8;
    const int wrow = wv * 32;

    const unsigned short* gA[2] = {Ah, Al};
    const unsigned short* gW[2] = {Wh, Wl};

    f32x4 acc[4][4];
    #pragma unroll
    for (int i = 0; i < 4; ++i)
        #pragma unroll
        for (int j = 0; j < 4; ++j) acc[i][j] = (f32x4){0.f, 0.f, 0.f, 0.f};

    auto stage = [&](int buf, int kt) {
        const int kc = kt * 32 + csl;
        #pragma unroll
        for (int t = 0; t < 2; ++t) {
            const unsigned short* g = gA[t] + (size_t)(bm + wrow + r0) * lda + kc;
            unsigned short* lp = &L[buf][t][wrow * 32];
            gload16(g, lp);
            gload16(g + (size_t)16 * lda, lp + 16 * 32);
        }
        #pragma unroll
        for (int t = 0; t < 2; ++t) {
            const unsigned short* g = gW[t] + (size_t)(bn + wrow + r0) * K + kc;
            unsigned short* lp = &L[buf][2 + t][wrow * 32];
            gload16(g, lp);
            gload16(g + (size_t)16 * K, lp + 16 * 32);
        }
    };

    const int NT = K / 32;
    stage(0, 0);
    for (int kt = 0;;) {
        __syncthreads();
        if (kt + 1 < NT) stage((kt + 1) & 1, kt + 1);
        const unsigned short* lah = &L[kt & 1][0][0];
        const unsigned short* lal = &L[kt & 1][1][0];
        const unsigned short* lbh = &L[kt & 1][2][0];
        const unsigned short* lbl = &L[kt & 1][3][0];
        bf16x8 fah[4], fal[4], fbh[4], fbl[4];
        #pragma unroll
        for (int i = 0; i < 4; ++i) {
            const int ra = (wm + i * 16 + fr) * 32 + fg * 8;
            const int rb = (wn + i * 16 + fr) * 32 + fg * 8;
            fah[i] = *(const bf16x8*)&lah[ra];
            fal[i] = *(const bf16x8*)&lal[ra];
            fbh[i] = *(const bf16x8*)&lbh[rb];
            fbl[i] = *(const bf16x8*)&lbl[rb];
        }
        #pragma unroll
        for (int i = 0; i < 4; ++i)
            #pragma unroll
            for (int j = 0; j < 4; ++j) {
                acc[i][j] = __builtin_amdgcn_mfma_f32_16x16x32_bf16(fal[i], fbh[j], acc[i][j], 0, 0, 0);
                acc[i][j] = __builtin_amdgcn_mfma_f32_16x16x32_bf16(fah[i], fbl[j], acc[i][j], 0, 0, 0);
                acc[i][j] = __builtin_amdgcn_mfma_f32_16x16x32_bf16(fah[i], fbh[j], acc[i][j], 0, 0, 0);
            }
        ++kt;
        if (kt >= NT) break;
    }

    #pragma unroll
    for (int i = 0; i < 4; ++i) {
        const int gmb = bm + wm + i * 16 + fg * 4;
        #pragma unroll
        for (int j = 0; j < 4; ++j) {
            const int gn = bn + wn + j * 16 + fr;
            const float bv = bias ? bias[gn] : 0.f;
            #pragma unroll
            for (int r = 0; r < 4; ++r) {
                float v = acc[i][j][r] + bv;
                if (ACT == 1) v = (v > 20.f) ? v : log1pf(__expf(v));
                C[(size_t)(gmb + r) * N + gn] = v;
            }
        }
    }
}

// ---------- A-f32 MFMA GEMM: A converted in-kernel, W pre-split ----------
template<int ACT, bool DUAL, bool GATE>
__global__ __launch_bounds__(256) void agemm_kernel(
    const float* __restrict__ A, const float* __restrict__ Z,
    const unsigned short* __restrict__ Wh, const unsigned short* __restrict__ Wl,
    const float* __restrict__ bias, float* __restrict__ C,
    unsigned short* __restrict__ dh, unsigned short* __restrict__ dl,
    int M, int N, int K, int lda)
{
    __shared__ unsigned short LAh[128 * 40];
    __shared__ unsigned short LAl[128 * 40];
    __shared__ unsigned short LBh[128 * 40];
    __shared__ unsigned short LBl[128 * 40];
    const int tid = threadIdx.x;
    const int bm = blockIdx.y * 128, bn = blockIdx.x * 128;
    const int srow = tid >> 1, sco = (tid & 1) * 16;
    const int wv = tid >> 6, lane = tid & 63;
    const int wm = (wv & 1) * 64, wn = (wv >> 1) * 64;
    const int fr = lane & 15, fg = lane >> 4;

    const float* Ap = A + (size_t)(bm + srow) * lda + sco;
    const float* Zp = GATE ? (Z + (size_t)(bm + srow) * lda + sco) : nullptr;
    const unsigned short* Whp = Wh + (size_t)(bn + srow) * K + sco;
    const unsigned short* Wlp = Wl + (size_t)(bn + srow) * K + sco;
    const bool wok = (bn + srow) < N;
    const uint4 zu = {0u, 0u, 0u, 0u};

    f32x4 acc[4][4];
    #pragma unroll
    for (int i = 0; i < 4; ++i)
        #pragma unroll
        for (int j = 0; j < 4; ++j) acc[i][j] = (f32x4){0.f, 0.f, 0.f, 0.f};

    alignas(16) float pa[16], pz[16];
    uint4 pbh[2], pbl[2];

    auto prefetch = [&](int k) {
        #pragma unroll
        for (int q = 0; q < 4; ++q) *(float4*)&pa[q * 4] = *(const float4*)(Ap + k + q * 4);
        if (GATE) {
            #pragma unroll
            for (int q = 0; q < 4; ++q) *(float4*)&pz[q * 4] = *(const float4*)(Zp + k + q * 4);
        }
        if (wok) {
            pbh[0] = *(const uint4*)(Whp + k); pbh[1] = *(const uint4*)(Whp + k + 8);
            pbl[0] = *(const uint4*)(Wlp + k); pbl[1] = *(const uint4*)(Wlp + k + 8);
        } else { pbh[0] = zu; pbh[1] = zu; pbl[0] = zu; pbl[1] = zu; }
    };

    prefetch(0);
    const int NT = K / 32;
    for (int kt = 0;;) {
        __syncthreads();
        {
            alignas(16) unsigned short hh[16], ll[16];
            #pragma unroll
            for (int i = 0; i < 16; ++i) {
                float v = pa[i];
                if (GATE) { float zz = pz[i]; v = v * (zz / (1.f + __expf(-zz))); }
                unsigned short h = f2bf(v);
                hh[i] = h; ll[i] = f2bf(v - bf2f(h));
            }
            const int wb = srow * 40 + sco;
            *(uint4*)&LAh[wb + 0] = *(uint4*)&hh[0];
            *(uint4*)&LAh[wb + 8] = *(uint4*)&hh[8];
            *(uint4*)&LAl[wb + 0] = *(uint4*)&ll[0];
            *(uint4*)&LAl[wb + 8] = *(uint4*)&ll[8];
            *(uint4*)&LBh[wb + 0] = pbh[0];
            *(uint4*)&LBh[wb + 8] = pbh[1];
            *(uint4*)&LBl[wb + 0] = pbl[0];
            *(uint4*)&LBl[wb + 8] = pbl[1];
        }
        __syncthreads();
        if (kt + 1 < NT) prefetch((kt + 1) * 32);
        bf16x8 fah[4], fal[4], fbh[4], fbl[4];
        #pragma unroll
        for (int i = 0; i < 4; ++i) {
            const int ra = (wm + i * 16 + fr) * 40 + fg * 8;
            const int rb = (wn + i * 16 + fr) * 40 + fg * 8;
            fah[i] = *(const bf16x8*)&LAh[ra];
            fal[i] = *(const bf16x8*)&LAl[ra];
            fbh[i] = *(const bf16x8*)&LBh[rb];
            fbl[i] = *(const bf16x8*)&LBl[rb];
        }
        #pragma unroll
        for (int i = 0; i < 4; ++i)
            #pragma unroll
            for (int j = 0; j < 4; ++j) {
                acc[i][j] = __builtin_amdgcn_mfma_f32_16x16x32_bf16(fal[i], fbh[j], acc[i][j], 0, 0, 0);
                acc[i][j] = __builtin_amdgcn_mfma_f32_16x16x32_bf16(fah[i], fbl[j], acc[i][j], 0, 0, 0);
                acc[i][j] = __builtin_amdgcn_mfma_f32_16x16x32_bf16(fah[i], fbh[j], acc[i][j], 0, 0, 0);
            }
        ++kt;
        if (kt >= NT) break;
    }

    #pragma unroll
    for (int i = 0; i < 4; ++i) {
        const int gmb = bm + wm + i * 16 + fg * 4;
        #pragma unroll
        for (int j = 0; j < 4; ++j) {
            const int gn = bn + wn + j * 16 + fr;
            if (gn >= N) continue;
            const float bv = bias ? bias[gn] : 0.f;
            #pragma unroll
            for (int r = 0; r < 4; ++r) {
                float v = acc[i][j][r] + bv;
                if (ACT == 1) v = (v > 20.f) ? v : log1pf(__expf(v));
                C[(size_t)(gmb + r) * N + gn] = v;
                if (DUAL && gn < 32) {
                    unsigned short h = f2bf(v);
                    dh[(size_t)(gmb + r) * 32 + gn] = h;
                    dl[(size_t)(gmb + r) * 32 + gn] = f2bf(v - bf2f(h));
                }
            }
        }
    }
}

// ---------------- f32 GEMM (accuracy-critical final projection) ----------------
template<int ACT, int NJ>
__global__ __launch_bounds__(256, 2) void gemm_kernel(
    const float* __restrict__ A, const float* __restrict__ W,
    const float* __restrict__ bias, float* __restrict__ C,
    int M, int N, int K, int lda)
{
    constexpr int TN = 16 * NJ;
    __shared__ float As[128 * 18];
    __shared__ float Ws[TN * 20];
    const int tid = threadIdx.x;
    const int bm = blockIdx.y * 128;
    const int bn = blockIdx.x * TN;
    const int tx = tid & 15;
    const int ty = tid >> 4;
    const int srow = tid >> 1;
    const int sc = (tid & 1) * 8;

    const float* Ap = A + (size_t)(bm + srow) * lda + sc;
    const float* Wp = W + (size_t)(bn + srow) * K + sc;
    const bool aok = (bm + srow) < M;
    const bool wok = (srow < TN) && ((bn + srow) < N);
    const float4 f0 = make_float4(0.f, 0.f, 0.f, 0.f);

    float4 na0 = f0, na1 = f0, nw0 = f0, nw1 = f0;
    if (aok) { na0 = *(const float4*)(Ap + 0); na1 = *(const float4*)(Ap + 4); }
    if (wok) { nw0 = *(const float4*)(Wp + 0); nw1 = *(const float4*)(Wp + 4); }

    float acc[8][NJ];
    #pragma unroll
    for (int i = 0; i < 8; ++i)
        #pragma unroll
        for (int j = 0; j < NJ; ++j) acc[i][j] = 0.f;

    for (int k0 = 0;;) {
        __syncthreads();
        {
            int wa = srow * 18 + sc;
            *(float2*)&As[wa + 0] = make_float2(na0.x, na0.y);
            *(float2*)&As[wa + 2] = make_float2(na0.z, na0.w);
            *(float2*)&As[wa + 4] = make_float2(na1.x, na1.y);
            *(float2*)&As[wa + 6] = make_float2(na1.z, na1.w);
            if (srow < TN) {
                int ww = srow * 20 + sc;
                *(float4*)&Ws[ww + 0] = nw0;
                *(float4*)&Ws[ww + 4] = nw1;
            }
        }
        __syncthreads();
        const int kn = k0 + 16;
        if (kn < K) {
            na0 = f0; na1 = f0;
            if (aok) { na0 = *(const float4*)(Ap + kn); na1 = *(const float4*)(Ap + kn + 4); }
            if (wok) { nw0 = *(const float4*)(Wp + kn); nw1 = *(const float4*)(Wp + kn + 4); }
        }
        #pragma unroll
        for (int k = 0; k < 16; k += 2) {
            float2 a2[8], b2[NJ];
            #pragma unroll
            for (int i = 0; i < 8; ++i)
                a2[i] = *(const float2*)&As[(ty * 8 + i) * 18 + k];
            #pragma unroll
            for (int j = 0; j < NJ; ++j)
                b2[j] = *(const float2*)&Ws[(tx + j * 16) * 20 + k];
            #pragma unroll
            for (int i = 0; i < 8; ++i)
                #pragma unroll
                for (int j = 0; j < NJ; ++j) {
                    acc[i][j] = fmaf(a2[i].x, b2[j].x, acc[i][j]);
                    acc[i][j] = fmaf(a2[i].y, b2[j].y, acc[i][j]);
                }
        }
        k0 = kn;
        if (k0 >= K) break;
    }

    #pragma unroll
    for (int i = 0; i < 8; ++i) {
        int gm = bm + ty * 8 + i;
        if (gm >= M) continue;
        #pragma unroll
        for (int j = 0; j < NJ; ++j) {
            int gn = bn + tx + j * 16;
            if (gn >= N) continue;
            float v = acc[i][j];
            if (bias) v += bias[gn];
            if (ACT == 1) v = (v > 20.f) ? v : log1pf(__expf(v));
            C[(size_t)gm * N + gn] = v;
        }
    }
}

// ------- reorder + split: xp(2,S,1024) -> xboth(4,S,512) bf16 hi/lo -------
__global__ __launch_bounds__(256) void reorder_split_kernel(
    const float* __restrict__ xp, unsigned short* __restrict__ xh,
    unsigned short* __restrict__ xl)
{
    int idx = blockIdx.x * 256 + threadIdx.x;
    int c4 = idx & 127;
    int t  = (idx >> 7) & 1023;
    int b4 = idx >> 17;
    float4 v;
    if (b4 < 2) v = *(const float4*)&xp[((size_t)(b4 * SEQL + t)) * DI + c4 * 4];
    else        v = *(const float4*)&xp[((size_t)((b4 - 2) * SEQL + (1023 - t))) * DI + 512 + c4 * 4];
    unsigned short h0 = f2bf(v.x), h1 = f2bf(v.y), h2 = f2bf(v.z), h3 = f2bf(v.w);
    unsigned short l0 = f2bf(v.x - bf2f(h0)), l1 = f2bf(v.y - bf2f(h1));
    unsigned short l2 = f2bf(v.z - bf2f(h2)), l3 = f2bf(v.w - bf2f(h3));
    ((uint2*)xh)[idx] = make_uint2((unsigned)h0 | ((unsigned)h1 << 16), (unsigned)h2 | ((unsigned)h3 << 16));
    ((uint2*)xl)[idx] = make_uint2((unsigned)l0 | ((unsigned)l1 << 16), (unsigned)l2 | ((unsigned)l3 << 16));
}

// ---------------- depthwise causal conv (k=4) + silu ----------------
__global__ __launch_bounds__(256) void conv_silu_kernel(
    const float* __restrict__ xin, const float* __restrict__ cw,
    const float* __restrict__ cb, float* __restrict__ xc)
{
    int idx = blockIdx.x * 256 + threadIdx.x;
    int c = idx & (DI - 1);
    int t = (idx >> 10) & (SEQL - 1);
    int b = idx >> 20;
    float acc = cb[c];
    #pragma unroll
    for (int k = 0; k < 4; ++k) {
        int tt = t - 3 + k;
        if (tt >= 0) acc = fmaf(xin[((size_t)(b * SEQL + tt)) * DI + c], cw[c * 4 + k], acc);
    }
    float s = 1.f / (1.f + __expf(-acc));
    xc[idx] = acc * s;
}

// ============ chunked selective scan (NC chunks of 1024/NC steps) ============
// Streams (b,d)=4096; wave = 4 d's, 16 lanes/d, 4 states/lane.
// part1: chunks 0..NC-2 local scan from h=0 -> S_c (final state), sum(dt).
// part2: all NC chunks; h_in composed via exp2(A2*sumdt) (diagonal, exact).
template<int NC>
__global__ __launch_bounds__(256, 4) void scan_part1(
    const float* __restrict__ dtp, const float* __restrict__ xcp,
    const float* __restrict__ xdbl, const float* __restrict__ A_log,
    float* __restrict__ Sbuf, float* __restrict__ SDbuf)
{
    constexpr int TCH = SEQL / NC;
    const int blk = blockIdx.x;          // (bb*(NC-1) + c)*64 + dblock
    const int dblock = blk & 63;
    const int bc = blk >> 6;
    const int bb = bc / (NC - 1);
    const int c  = bc - bb * (NC - 1);
    const int wave = threadIdx.x >> 6;
    const int lane = threadIdx.x & 63;
    const int dd = lane >> 4;
    const int s4 = lane & 15;
    const int d = dblock * 16 + wave * 4 + dd;
    const float LOG2E = 1.4426950408889634f;

    float A2[4], h[4];
    #pragma unroll
    for (int k = 0; k < 4; ++k) {
        A2[k] = -__expf(A_log[d * DSTATE + s4 * 4 + k]) * LOG2E;
        h[k] = 0.f;
    }
    float sumdt = 0.f;
    const int T0 = c * TCH;
    const size_t rb = (size_t)bb * SEQL * DI + (size_t)T0 * DI + d;
    const float* Bb = xdbl + ((size_t)bb * SEQL + T0) * XDBL_N + 32 + s4 * 4;

    float dt0[4], xc0[4]; float4 B0[4];
    float dt1[4], xc1[4]; float4 B1[4];

#define L1(t0, dt_, xc_, B_)                                           \
    { _Pragma("unroll")                                                \
      for (int i = 0; i < 4; ++i) {                                    \
        size_t ro = rb + (size_t)((t0) + i) * DI;                      \
        dt_[i] = dtp[ro];                                              \
        xc_[i] = xcp[ro];                                              \
        B_[i] = *(const float4*)(Bb + (size_t)((t0) + i) * XDBL_N);    \
      } }

#define C1(dt_, xc_, B_)                                               \
    { _Pragma("unroll")                                                \
      for (int i = 0; i < 4; ++i) {                                    \
        float dtv = dt_[i];                                            \
        sumdt += dtv;                                                  \
        float dtx = dtv * xc_[i];                                      \
        h[0] = fmaf(exp2f(dtv * A2[0]), h[0], dtx * B_[i].x);          \
        h[1] = fmaf(exp2f(dtv * A2[1]), h[1], dtx * B_[i].y);          \
        h[2] = fmaf(exp2f(dtv * A2[2]), h[2], dtx * B_[i].z);          \
        h[3] = fmaf(exp2f(dtv * A2[3]), h[3], dtx * B_[i].w);          \
      } }

    L1(0, dt0, xc0, B0);
    for (int g = 0; g < TCH / 4; g += 2) {
        L1((g + 1) * 4, dt1, xc1, B1);
        C1(dt0, xc0, B0);
        if (g + 2 < TCH / 4) L1((g + 2) * 4, dt0, xc0, B0);
        C1(dt1, xc1, B1);
    }
#undef L1
#undef C1

    const size_t so = ((size_t)bc * 1024 + d) * 64 + s4 * 4;
    *(float4*)&Sbuf[so] = make_float4(h[0], h[1], h[2], h[3]);
    if (s4 == 0) SDbuf[bc * 1024 + d] = sumdt;
}

// pass 2: full scan + DPP reduce; epilogue y = p + xc*D (gate in Gout).
// yp may alias dtp (stores trail prefetched reads; disjoint per block).
template<int NC>
__global__ __launch_bounds__(256, 4) void scan_part2(
    const float* dtp, float* yp,
    const float* __restrict__ xdbl,
    const float* __restrict__ xcp,
    const float* __restrict__ A_log,
    const float* __restrict__ Dpar,
    const float* __restrict__ Sbuf,
    const float* __restrict__ SDbuf)
{
    constexpr int TCH = SEQL / NC;
    const int blk = blockIdx.x;          // (bb*NC + c)*64 + dblock
    const int dblock = blk & 63;
    const int bc = blk >> 6;
    const int bb = bc / NC;
    const int c  = bc - bb * NC;
    const int wave = threadIdx.x >> 6;
    const int lane = threadIdx.x & 63;
    const int dd = lane >> 4;
    const int s4 = lane & 15;
    const int d = dblock * 16 + wave * 4 + dd;
    const float LOG2E = 1.4426950408889634f;

    float A2[4], h[4];
    #pragma unroll
    for (int k = 0; k < 4; ++k) {
        A2[k] = -__expf(A_log[d * DSTATE + s4 * 4 + k]) * LOG2E;
        h[k] = 0.f;
    }
    for (int cc = 0; cc < c; ++cc) {
        const int bcc = bb * (NC - 1) + cc;
        const size_t so = ((size_t)bcc * 1024 + d) * 64 + s4 * 4;
        float4 S = *(const float4*)&Sbuf[so];
        float sd = SDbuf[bcc * 1024 + d];
        h[0] = fmaf(exp2f(A2[0] * sd), h[0], S.x);
        h[1] = fmaf(exp2f(A2[1] * sd), h[1], S.y);
        h[2] = fmaf(exp2f(A2[2] * sd), h[2], S.z);
        h[3] = fmaf(exp2f(A2[3] * sd), h[3], S.w);
    }

    const float Dv = Dpar[d];
    const int T0 = c * TCH;
    const size_t rb = (size_t)bb * SEQL * DI + (size_t)T0 * DI + d;
    const float* Bb = xdbl + ((size_t)bb * SEQL + T0) * XDBL_N + 32 + s4 * 4;

    float dt0[4], xc0[4]; float4 B0[4], C0[4];
    float dt1[4], xc1[4]; float4 B1[4], C1[4];

#define LOADC(t0, dt_, xc_, B_, C_)                                    \
    { _Pragma("unroll")                                                \
      for (int i = 0; i < 4; ++i) {                                    \
        size_t ro = rb + (size_t)((t0) + i) * DI;                      \
        dt_[i] = dtp[ro];                                              \
        xc_[i] = xcp[ro];                                              \
        const float* bp = Bb + (size_t)((t0) + i) * XDBL_N;            \
        B_[i] = *(const float4*)bp;                                    \
        C_[i] = *(const float4*)(bp + 64);                             \
      } }

#define COMPC(t0, dt_, xc_, B_, C_)                                    \
    { _Pragma("unroll")                                                \
      for (int i = 0; i < 4; ++i) {                                    \
        float dtv = dt_[i];                                            \
        float dtx = dtv * xc_[i];                                      \
        h[0] = fmaf(exp2f(dtv * A2[0]), h[0], dtx * B_[i].x);          \
        h[1] = fmaf(exp2f(dtv * A2[1]), h[1], dtx * B_[i].y);          \
        h[2] = fmaf(exp2f(dtv * A2[2]), h[2], dtx * B_[i].z);          \
        h[3] = fmaf(exp2f(dtv * A2[3]), h[3], dtx * B_[i].w);          \
        float p = h[0] * C_[i].x + h[1] * C_[i].y                      \
                + h[2] * C_[i].z + h[3] * C_[i].w;                     \
        p = dppsum16(p);                                               \
        float y2 = p + xc_[i] * Dv;                                    \
        if (s4 == 0) yp[rb + (size_t)((t0) + i) * DI] = y2;            \
      } }

    LOADC(0, dt0, xc0, B0, C0);
    for (int g = 0; g < TCH / 4; g += 2) {
        LOADC((g + 1) * 4, dt1, xc1, B1, C1);
        COMPC(g * 4, dt0, xc0, B0, C0);
        if (g + 2 < TCH / 4) LOADC((g + 2) * 4, dt0, xc0, B0, C0);
        COMPC((g + 1) * 4, dt1, xc1, B1, C1);
    }
#undef LOADC
#undef COMPC
}

// ---------------- combine: out5(4,S,512) -> combined(2,S,512) ----------------
__global__ __launch_bounds__(256) void combine_kernel(
    const float* __restrict__ out5, float* __restrict__ comb)
{
    int idx = blockIdx.x * 256 + threadIdx.x;
    int c = idx & 511;
    int t = (idx >> 9) & 1023;
    int b = idx >> 19;
    float vf = out5[((size_t)(b * SEQL + t)) * 512 + c];
    float vb = out5[((size_t)((2 + b) * SEQL + (1023 - t))) * 512 + c];
    comb[idx] = vf + vb;
}

extern "C" void kernel_launch(void* const* d_in, const int* in_sizes, int n_in,
                              void* d_out, int out_size, void* d_ws, size_t ws_size,
                              hipStream_t stream)
{
    const float* x        = (const float*)d_in[0];
    const float* W_in_bi  = (const float*)d_in[1];
    const float* b_in_bi  = (const float*)d_in[2];
    const float* W_out_bi = (const float*)d_in[3];
    const float* b_out_bi = (const float*)d_in[4];
    const float* W_in     = (const float*)d_in[5];
    const float* b_in     = (const float*)d_in[6];
    const float* conv_w   = (const float*)d_in[7];
    const float* conv_b   = (const float*)d_in[8];
    const float* W_x      = (const float*)d_in[9];
    const float* W_dt     = (const float*)d_in[10];
    const float* b_dt     = (const float*)d_in[11];
    const float* A_log    = (const float*)d_in[12];
    const float* D_param  = (const float*)d_in[13];
    const float* W_out    = (const float*)d_in[14];
    const float* b_out    = (const float*)d_in[15];
    float* outp = (float*)d_out;
    char* ws = (char*)d_ws;
    const size_t MB = (size_t)1 << 20;
    typedef unsigned short us;

    // ---- workspace layout (lifetime-packed) ----
    float* zbuf = (float*)(ws + 0);          // 16MB [G3 -> Gout]
    float* xcb  = (float*)(ws + 16 * MB);    // 16MB [conv -> part2]
    float* dtb  = (float*)(ws + 32 * MB);    // 16MB [Gdt -> part2; y in place -> Gout]
    float* xdbl = (float*)(ws + 48 * MB);    // 2.5MB [Gx -> part2]
    const size_t sb_off = 48 * MB + 2621440;
    float* Sbuf = (float*)(ws + sb_off);     // (NC-1)MB [part1 -> part2]
    // early tenants of zbuf region:
    float* xp   = (float*)(ws + 0);          // 8MB [G1 -> reorder]
    // early tenants of xcb region:
    us* xbh   = (us*)(ws + 16 * MB);         // 4MB [reorder -> G3]
    us* xbl   = (us*)(ws + 20 * MB);
    us* Win_h = (us*)(ws + 24 * MB);         // 2MB [-> G3]
    us* Win_l = (us*)(ws + 26 * MB);
    us* Wbi_h = (us*)(ws + 28 * MB);         // 1MB [-> G1]
    us* Wbi_l = (us*)(ws + 29 * MB);
    // late tenants of xcb region (after part2):
    us* Wout_h = (us*)(ws + 16 * MB);        // 1MB [-> Gout]
    us* Wout_l = (us*)(ws + 17 * MB);
    float* out5 = (float*)(ws + 18 * MB);    // 8MB [Gout -> combine]
    float* comb = (float*)(ws + 26 * MB);    // 4MB [combine -> final]
    // early tenant of dtb region:
    float* xin = (float*)(ws + 32 * MB);     // 16MB [G2 -> conv]
    // early tenants of Sbuf region (all dead before part1 writes Sbuf):
    us* Wx_h  = (us*)(ws + sb_off);                       // 320KB [-> Gx]
    us* Wx_l  = (us*)(ws + sb_off + 327680);
    us* Wdt_h = (us*)(ws + sb_off + 655360);              // 64KB [-> Gdt]
    us* Wdt_l = (us*)(ws + sb_off + 720896);
    us* dtr_h = (us*)(ws + sb_off + 786432);              // 256KB [Gx -> Gdt]
    us* dtr_l = (us*)(ws + sb_off + 1048576);

    dim3 blk(256, 1, 1);

    // weight splits (cheap, inputs only)
    split_kernel<<<dim3(512), blk, 0, stream>>>(W_in_bi, Wbi_h, Wbi_l, 131072);
    split_kernel<<<dim3(1024), blk, 0, stream>>>(W_in, Win_h, Win_l, 262144);
    split_kernel<<<dim3(160), blk, 0, stream>>>(W_x, Wx_h, Wx_l, 40960);
    split_kernel<<<dim3(32), blk, 0, stream>>>(W_dt, Wdt_h, Wdt_l, 8192);

    // G1: xp = x @ W_in_bi^T + b_in_bi
    agemm_kernel<0, false, false><<<dim3(8, 16), blk, 0, stream>>>(
        x, nullptr, Wbi_h, Wbi_l, b_in_bi, xp, nullptr, nullptr, 2048, 1024, 512, 512);
    // reorder + split -> bf16 hi/lo
    reorder_split_kernel<<<dim3(2048), blk, 0, stream>>>(xp, xbh, xbl);
    // G2/G3: pure pre-split GEMMs
    pgemm_kernel<0><<<dim3(8, 32), blk, 0, stream>>>(
        xbh, xbl, Win_h, Win_l, b_in, xin, 4096, 1024, 512, 512);
    pgemm_kernel<0><<<dim3(8, 32), blk, 0, stream>>>(
        xbh, xbl, Win_h + 1024 * 512, Win_l + 1024 * 512, b_in + 1024, zbuf, 4096, 1024, 512, 512);
    // depthwise conv + silu
    conv_silu_kernel<<<dim3(16384), blk, 0, stream>>>(xin, conv_w, conv_b, xcb);
    // Gx: x_dbl = xc @ W_x^T  (+ fused bf16 split of dt_raw cols 0..31)
    agemm_kernel<0, true, false><<<dim3(2, 32), blk, 0, stream>>>(
        xcb, nullptr, Wx_h, Wx_l, nullptr, xdbl, dtr_h, dtr_l, 4096, 160, 1024, 1024);
    // Gdt: dt = softplus(dt_raw @ W_dt^T + b_dt)
    pgemm_kernel<1><<<dim3(8, 32), blk, 0, stream>>>(
        dtr_h, dtr_l, Wdt_h, Wdt_l, b_dt, dtb, 4096, 1024, 32, 32);

    // chunked scan: NC=8 if scratch allows (Sbuf 7MB + SDb), else NC=4
    if (ws_size >= sb_off + 7 * 1048576 + 114688) {
        float* SDb = (float*)(ws + sb_off + 7 * 1048576);
        scan_part1<8><<<dim3(4 * 7 * 64), blk, 0, stream>>>(dtb, xcb, xdbl, A_log, Sbuf, SDb);
        scan_part2<8><<<dim3(4 * 8 * 64), blk, 0, stream>>>(dtb, dtb, xdbl, xcb, A_log, D_param, Sbuf, SDb);
    } else {
        float* SDb = (float*)(ws + sb_off + 3 * 1048576);
        scan_part1<4><<<dim3(4 * 3 * 64), blk, 0, stream>>>(dtb, xcb, xdbl, A_log, Sbuf, SDb);
        scan_part2<4><<<dim3(4 * 4 * 64), blk, 0, stream>>>(dtb, dtb, xdbl, xcb, A_log, D_param, Sbuf, SDb);
    }

    // W_out split (into dead xcb region), then Gout with fused silu(z) gate
    split_kernel<<<dim3(512), blk, 0, stream>>>(W_out, Wout_h, Wout_l, 131072);
    agemm_kernel<0, false, true><<<dim3(4, 32), blk, 0, stream>>>(
        dtb, zbuf, Wout_h, Wout_l, b_out, out5, nullptr, nullptr, 4096, 512, 1024, 1024);
    // combine forward + flipped backward
    combine_kernel<<<dim3(4096), blk, 0, stream>>>(out5, comb);
    // final = combined @ W_out_bi^T + b_out_bi (f32 — accuracy-critical last hop)
    gemm_kernel<0, 2><<<dim3(16, 16), blk, 0, stream>>>(comb, W_out_bi, b_out_bi, outp, 2048, 512, 512, 512);
}

// Round 7
// 558.355 us; speedup vs baseline: 2.0943x; 1.0802x over previous
//
#include <hip/hip_runtime.h>
#include <hip/hip_bf16.h>
#include <math.h>

#define SEQL 1024
#define DI 1024
#define DSTATE 64
#define XDBL_N 160
#define MT 4096   // total m rows (4 batches x 1024 t) for T-layout buffers

typedef short bf16x8 __attribute__((ext_vector_type(8)));
typedef float f32x4 __attribute__((ext_vector_type(4)));

__device__ __forceinline__ unsigned short f2bf(float f) {
    unsigned u = __builtin_bit_cast(unsigned, f);
    u += 0x7FFFu + ((u >> 16) & 1u);
    return (unsigned short)(u >> 16);
}
__device__ __forceinline__ float bf2f(unsigned short h) {
    unsigned u = ((unsigned)h) << 16;
    return __builtin_bit_cast(float, u);
}
__device__ __forceinline__ void gload16(const void* g, void* l) {
    __builtin_amdgcn_global_load_lds((const __attribute__((address_space(1))) void*)g,
                                     (__attribute__((address_space(3))) void*)l, 16, 0, 0);
}
// 16-lane row-sum via DPP row_shr; total lands in lane (row16*16+0).
__device__ __forceinline__ float dppsum16(float p) {
    int q;
    q = __builtin_amdgcn_update_dpp(0, __builtin_bit_cast(int, p), 0x118, 0xF, 0xF, true);
    p += __builtin_bit_cast(float, q);
    q = __builtin_amdgcn_update_dpp(0, __builtin_bit_cast(int, p), 0x114, 0xF, 0xF, true);
    p += __builtin_bit_cast(float, q);
    q = __builtin_amdgcn_update_dpp(0, __builtin_bit_cast(int, p), 0x112, 0xF, 0xF, true);
    p += __builtin_bit_cast(float, q);
    q = __builtin_amdgcn_update_dpp(0, __builtin_bit_cast(int, p), 0x111, 0xF, 0xF, true);
    p += __builtin_bit_cast(float, q);
    return p;
}

// ---------------- generic f32 -> bf16 hi/lo split ----------------
__global__ __launch_bounds__(256) void split_kernel(
    const float* __restrict__ src, unsigned short* __restrict__ h,
    unsigned short* __restrict__ l, int n4)
{
    int i = blockIdx.x * 256 + threadIdx.x;
    if (i >= n4) return;
    float4 v = ((const float4*)src)[i];
    unsigned short h0 = f2bf(v.x), h1 = f2bf(v.y), h2 = f2bf(v.z), h3 = f2bf(v.w);
    unsigned short l0 = f2bf(v.x - bf2f(h0)), l1 = f2bf(v.y - bf2f(h1));
    unsigned short l2 = f2bf(v.z - bf2f(h2)), l3 = f2bf(v.w - bf2f(h3));
    ((uint2*)h)[i] = make_uint2((unsigned)h0 | ((unsigned)h1 << 16), (unsigned)h2 | ((unsigned)h3 << 16));
    ((uint2*)l)[i] = make_uint2((unsigned)l0 | ((unsigned)l1 << 16), (unsigned)l2 | ((unsigned)l3 << 16));
}

// ---------- pre-split bf16 MFMA GEMM (pure, global_load_lds, dbuf) ----------
// TRANS: store C transposed as CT[n][m] (float4 along m, free transpose).
template<int ACT, bool TRANS>
__global__ __launch_bounds__(256) void pgemm_kernel(
    const unsigned short* __restrict__ Ah, const unsigned short* __restrict__ Al,
    const unsigned short* __restrict__ Wh, const unsigned short* __restrict__ Wl,
    const float* __restrict__ bias, float* __restrict__ C,
    int M, int N, int K, int lda)
{
    __shared__ unsigned short L[2][4][128 * 32];   // [buf][Ah,Al,Wh,Wl]
    const int tid = threadIdx.x;
    const int bm = blockIdx.y * 128, bn = blockIdx.x * 128;
    const int wv = tid >> 6, lane = tid & 63;
    const int wm = (wv & 1) * 64, wn = (wv >> 1) * 64;
    const int fr = lane & 15, fg = lane >> 4;
    const int r0 = lane >> 2;
    const int csl = (lane & 3) * 8;
    const int wrow = wv * 32;

    const unsigned short* gA[2] = {Ah, Al};
    const unsigned short* gW[2] = {Wh, Wl};

    f32x4 acc[4][4];
    #pragma unroll
    for (int i = 0; i < 4; ++i)
        #pragma unroll
        for (int j = 0; j < 4; ++j) acc[i][j] = (f32x4){0.f, 0.f, 0.f, 0.f};

    auto stage = [&](int buf, int kt) {
        const int kc = kt * 32 + csl;
        #pragma unroll
        for (int t = 0; t < 2; ++t) {
            const unsigned short* g = gA[t] + (size_t)(bm + wrow + r0) * lda + kc;
            unsigned short* lp = &L[buf][t][wrow * 32];
            gload16(g, lp);
            gload16(g + (size_t)16 * lda, lp + 16 * 32);
        }
        #pragma unroll
        for (int t = 0; t < 2; ++t) {
            const unsigned short* g = gW[t] + (size_t)(bn + wrow + r0) * K + kc;
            unsigned short* lp = &L[buf][2 + t][wrow * 32];
            gload16(g, lp);
            gload16(g + (size_t)16 * K, lp + 16 * 32);
        }
    };

    const int NT = K / 32;
    stage(0, 0);
    for (int kt = 0;;) {
        __syncthreads();
        if (kt + 1 < NT) stage((kt + 1) & 1, kt + 1);
        const unsigned short* lah = &L[kt & 1][0][0];
        const unsigned short* lal = &L[kt & 1][1][0];
        const unsigned short* lbh = &L[kt & 1][2][0];
        const unsigned short* lbl = &L[kt & 1][3][0];
        bf16x8 fah[4], fal[4], fbh[4], fbl[4];
        #pragma unroll
        for (int i = 0; i < 4; ++i) {
            const int ra = (wm + i * 16 + fr) * 32 + fg * 8;
            const int rb = (wn + i * 16 + fr) * 32 + fg * 8;
            fah[i] = *(const bf16x8*)&lah[ra];
            fal[i] = *(const bf16x8*)&lal[ra];
            fbh[i] = *(const bf16x8*)&lbh[rb];
            fbl[i] = *(const bf16x8*)&lbl[rb];
        }
        #pragma unroll
        for (int i = 0; i < 4; ++i)
            #pragma unroll
            for (int j = 0; j < 4; ++j) {
                acc[i][j] = __builtin_amdgcn_mfma_f32_16x16x32_bf16(fal[i], fbh[j], acc[i][j], 0, 0, 0);
                acc[i][j] = __builtin_amdgcn_mfma_f32_16x16x32_bf16(fah[i], fbl[j], acc[i][j], 0, 0, 0);
                acc[i][j] = __builtin_amdgcn_mfma_f32_16x16x32_bf16(fah[i], fbh[j], acc[i][j], 0, 0, 0);
            }
        ++kt;
        if (kt >= NT) break;
    }

    #pragma unroll
    for (int i = 0; i < 4; ++i) {
        const int gmb = bm + wm + i * 16 + fg * 4;
        #pragma unroll
        for (int j = 0; j < 4; ++j) {
            const int gn = bn + wn + j * 16 + fr;
            const float bv = bias ? bias[gn] : 0.f;
            float4 v4;
            float* vp = &v4.x;
            #pragma unroll
            for (int r = 0; r < 4; ++r) {
                float v = acc[i][j][r] + bv;
                if (ACT == 1) v = (v > 20.f) ? v : log1pf(__expf(v));
                vp[r] = v;
            }
            if (TRANS) {
                *(float4*)&C[(size_t)gn * M + gmb] = v4;
            } else {
                #pragma unroll
                for (int r = 0; r < 4; ++r) C[(size_t)(gmb + r) * N + gn] = vp[r];
            }
        }
    }
}

// ---------- A-f32 MFMA GEMM: A converted in-kernel, W pre-split ----------
// ATRANS: A given as AT[k][m] (stride M); staged via LDS transpose with
// 16B-granule XOR swizzle. GATE: A *= silu(Z) (Z same layout as A).
// DUAL: also emit bf16 hi/lo of C for gn<32 (t-major).
template<int ACT, bool DUAL, bool GATE, bool ATRANS, int BN>
__global__ __launch_bounds__(256) void agemm_kernel(
    const float* __restrict__ A, const float* __restrict__ Z,
    const unsigned short* __restrict__ Wh, const unsigned short* __restrict__ Wl,
    const float* __restrict__ bias, float* __restrict__ C,
    unsigned short* __restrict__ dh, unsigned short* __restrict__ dl,
    int M, int N, int K, int lda)
{
    constexpr int MI = (BN == 128) ? 4 : 2;
    __shared__ unsigned short LAh[128 * 40];
    __shared__ unsigned short LAl[128 * 40];
    __shared__ unsigned short LBh[BN * 40];
    __shared__ unsigned short LBl[BN * 40];
    const int tid = threadIdx.x;
    const int bm = blockIdx.y * 128, bn = blockIdx.x * BN;
    const int wv = tid >> 6, lane = tid & 63;
    const int wm = (BN == 128) ? (wv & 1) * 64 : wv * 32;
    const int wn = (BN == 128) ? (wv >> 1) * 64 : 0;
    const int fr = lane & 15, fg = lane >> 4;

    // B staging coords
    const int srow = tid >> 1, sco = (tid & 1) * 16;
    const unsigned short* Whp = Wh + (size_t)(bn + srow) * K + sco;
    const unsigned short* Wlp = Wl + (size_t)(bn + srow) * K + sco;
    const bool wok = (srow < BN) && ((bn + srow) < N);
    const uint4 zu = {0u, 0u, 0u, 0u};

    // A staging coords (ATRANS)
    const int kp = tid >> 4;           // k-pair 0..15
    const int mo = (tid & 15) * 8;     // m offset 0..120
    const float* At0 = ATRANS ? (A + (size_t)(2 * kp) * M + bm + mo) : nullptr;
    const float* At1 = ATRANS ? (At0 + M) : nullptr;
    const float* Zt0 = (ATRANS && GATE) ? (Z + (size_t)(2 * kp) * M + bm + mo) : nullptr;
    const float* Zt1 = (ATRANS && GATE) ? (Zt0 + M) : nullptr;
    const int swbase = (((kp >> 2) ^ (tid & 3)) * 8) + (kp & 3) * 2;
    // A staging coords (!ATRANS)
    const float* Ap = ATRANS ? nullptr : (A + (size_t)(bm + srow) * lda + sco);

    f32x4 acc[MI][4];
    #pragma unroll
    for (int i = 0; i < MI; ++i)
        #pragma unroll
        for (int j = 0; j < 4; ++j) acc[i][j] = (f32x4){0.f, 0.f, 0.f, 0.f};

    alignas(16) float pa0[8], pa1[8], pz0[8], pz1[8];
    alignas(16) float pa[16];
    uint4 pbh[2], pbl[2];

    auto prefetch = [&](int k0) {
        if (ATRANS) {
            const size_t off = (size_t)k0 * M;
            *(float4*)&pa0[0] = *(const float4*)(At0 + off);
            *(float4*)&pa0[4] = *(const float4*)(At0 + off + 4);
            *(float4*)&pa1[0] = *(const float4*)(At1 + off);
            *(float4*)&pa1[4] = *(const float4*)(At1 + off + 4);
            if (GATE) {
                *(float4*)&pz0[0] = *(const float4*)(Zt0 + off);
                *(float4*)&pz0[4] = *(const float4*)(Zt0 + off + 4);
                *(float4*)&pz1[0] = *(const float4*)(Zt1 + off);
                *(float4*)&pz1[4] = *(const float4*)(Zt1 + off + 4);
            }
        } else {
            #pragma unroll
            for (int q = 0; q < 4; ++q) *(float4*)&pa[q * 4] = *(const float4*)(Ap + k0 + q * 4);
        }
        if (wok) {
            pbh[0] = *(const uint4*)(Whp + k0); pbh[1] = *(const uint4*)(Whp + k0 + 8);
            pbl[0] = *(const uint4*)(Wlp + k0); pbl[1] = *(const uint4*)(Wlp + k0 + 8);
        } else { pbh[0] = zu; pbh[1] = zu; pbl[0] = zu; pbl[1] = zu; }
    };

    prefetch(0);
    const int NT = K / 32;
    for (int kt = 0;;) {
        __syncthreads();
        if (ATRANS) {
            #pragma unroll
            for (int j = 0; j < 8; ++j) {
                float v0 = pa0[j], v1 = pa1[j];
                if (GATE) {
                    float z0 = pz0[j], z1 = pz1[j];
                    v0 *= z0 / (1.f + __expf(-z0));
                    v1 *= z1 / (1.f + __expf(-z1));
                }
                unsigned short h0 = f2bf(v0), h1 = f2bf(v1);
                unsigned short l0 = f2bf(v0 - bf2f(h0)), l1 = f2bf(v1 - bf2f(h1));
                const int a = (mo + j) * 40 + swbase;
                *(unsigned*)&LAh[a] = (unsigned)h0 | ((unsigned)h1 << 16);
                *(unsigned*)&LAl[a] = (unsigned)l0 | ((unsigned)l1 << 16);
            }
            if (srow < BN) {
                const int wb = srow * 40 + sco;
                *(uint4*)&LBh[wb + 0] = pbh[0];
                *(uint4*)&LBh[wb + 8] = pbh[1];
                *(uint4*)&LBl[wb + 0] = pbl[0];
                *(uint4*)&LBl[wb + 8] = pbl[1];
            }
        } else {
            alignas(16) unsigned short hh[16], ll[16];
            #pragma unroll
            for (int i = 0; i < 16; ++i) {
                float v = pa[i];
                unsigned short h = f2bf(v);
                hh[i] = h; ll[i] = f2bf(v - bf2f(h));
            }
            const int wb = srow * 40 + sco;
            *(uint4*)&LAh[wb + 0] = *(uint4*)&hh[0];
            *(uint4*)&LAh[wb + 8] = *(uint4*)&hh[8];
            *(uint4*)&LAl[wb + 0] = *(uint4*)&ll[0];
            *(uint4*)&LAl[wb + 8] = *(uint4*)&ll[8];
            if (srow < BN) {
                *(uint4*)&LBh[wb + 0] = pbh[0];
                *(uint4*)&LBh[wb + 8] = pbh[1];
                *(uint4*)&LBl[wb + 0] = pbl[0];
                *(uint4*)&LBl[wb + 8] = pbl[1];
            }
        }
        __syncthreads();
        if (kt + 1 < NT) prefetch((kt + 1) * 32);
        bf16x8 fah[MI], fal[MI], fbh[4], fbl[4];
        #pragma unroll
        for (int i = 0; i < MI; ++i) {
            const int mrow = wm + i * 16 + fr;
            const int g = ATRANS ? (fg ^ ((mrow >> 3) & 3)) : fg;
            const int ra = mrow * 40 + g * 8;
            fah[i] = *(const bf16x8*)&LAh[ra];
            fal[i] = *(const bf16x8*)&LAl[ra];
        }
        #pragma unroll
        for (int j = 0; j < 4; ++j) {
            const int rb = (wn + j * 16 + fr) * 40 + fg * 8;
            fbh[j] = *(const bf16x8*)&LBh[rb];
            fbl[j] = *(const bf16x8*)&LBl[rb];
        }
        #pragma unroll
        for (int i = 0; i < MI; ++i)
            #pragma unroll
            for (int j = 0; j < 4; ++j) {
                acc[i][j] = __builtin_amdgcn_mfma_f32_16x16x32_bf16(fal[i], fbh[j], acc[i][j], 0, 0, 0);
                acc[i][j] = __builtin_amdgcn_mfma_f32_16x16x32_bf16(fah[i], fbl[j], acc[i][j], 0, 0, 0);
                acc[i][j] = __builtin_amdgcn_mfma_f32_16x16x32_bf16(fah[i], fbh[j], acc[i][j], 0, 0, 0);
            }
        ++kt;
        if (kt >= NT) break;
    }

    #pragma unroll
    for (int i = 0; i < MI; ++i) {
        const int gmb = bm + wm + i * 16 + fg * 4;
        #pragma unroll
        for (int j = 0; j < 4; ++j) {
            const int gn = bn + wn + j * 16 + fr;
            if (gn >= N) continue;
            const float bv = bias ? bias[gn] : 0.f;
            #pragma unroll
            for (int r = 0; r < 4; ++r) {
                float v = acc[i][j][r] + bv;
                if (ACT == 1) v = (v > 20.f) ? v : log1pf(__expf(v));
                C[(size_t)(gmb + r) * N + gn] = v;
                if (DUAL && gn < 32) {
                    unsigned short h = f2bf(v);
                    dh[(size_t)(gmb + r) * 32 + gn] = h;
                    dl[(size_t)(gmb + r) * 32 + gn] = f2bf(v - bf2f(h));
                }
            }
        }
    }
}

// ---------------- f32 GEMM (accuracy-critical final projection) ----------------
template<int ACT, int NJ>
__global__ __launch_bounds__(256, 2) void gemm_kernel(
    const float* __restrict__ A, const float* __restrict__ W,
    const float* __restrict__ bias, float* __restrict__ C,
    int M, int N, int K, int lda)
{
    constexpr int TN = 16 * NJ;
    __shared__ float As[128 * 18];
    __shared__ float Ws[TN * 20];
    const int tid = threadIdx.x;
    const int bm = blockIdx.y * 128;
    const int bn = blockIdx.x * TN;
    const int tx = tid & 15;
    const int ty = tid >> 4;
    const int srow = tid >> 1;
    const int sc = (tid & 1) * 8;

    const float* Ap = A + (size_t)(bm + srow) * lda + sc;
    const float* Wp = W + (size_t)(bn + srow) * K + sc;
    const bool aok = (bm + srow) < M;
    const bool wok = (srow < TN) && ((bn + srow) < N);
    const float4 f0 = make_float4(0.f, 0.f, 0.f, 0.f);

    float4 na0 = f0, na1 = f0, nw0 = f0, nw1 = f0;
    if (aok) { na0 = *(const float4*)(Ap + 0); na1 = *(const float4*)(Ap + 4); }
    if (wok) { nw0 = *(const float4*)(Wp + 0); nw1 = *(const float4*)(Wp + 4); }

    float acc[8][NJ];
    #pragma unroll
    for (int i = 0; i < 8; ++i)
        #pragma unroll
        for (int j = 0; j < NJ; ++j) acc[i][j] = 0.f;

    for (int k0 = 0;;) {
        __syncthreads();
        {
            int wa = srow * 18 + sc;
            *(float2*)&As[wa + 0] = make_float2(na0.x, na0.y);
            *(float2*)&As[wa + 2] = make_float2(na0.z, na0.w);
            *(float2*)&As[wa + 4] = make_float2(na1.x, na1.y);
            *(float2*)&As[wa + 6] = make_float2(na1.z, na1.w);
            if (srow < TN) {
                int ww = srow * 20 + sc;
                *(float4*)&Ws[ww + 0] = nw0;
                *(float4*)&Ws[ww + 4] = nw1;
            }
        }
        __syncthreads();
        const int kn = k0 + 16;
        if (kn < K) {
            na0 = f0; na1 = f0;
            if (aok) { na0 = *(const float4*)(Ap + kn); na1 = *(const float4*)(Ap + kn + 4); }
            if (wok) { nw0 = *(const float4*)(Wp + kn); nw1 = *(const float4*)(Wp + kn + 4); }
        }
        #pragma unroll
        for (int k = 0; k < 16; k += 2) {
            float2 a2[8], b2[NJ];
            #pragma unroll
            for (int i = 0; i < 8; ++i)
                a2[i] = *(const float2*)&As[(ty * 8 + i) * 18 + k];
            #pragma unroll
            for (int j = 0; j < NJ; ++j)
                b2[j] = *(const float2*)&Ws[(tx + j * 16) * 20 + k];
            #pragma unroll
            for (int i = 0; i < 8; ++i)
                #pragma unroll
                for (int j = 0; j < NJ; ++j) {
                    acc[i][j] = fmaf(a2[i].x, b2[j].x, acc[i][j]);
                    acc[i][j] = fmaf(a2[i].y, b2[j].y, acc[i][j]);
                }
        }
        k0 = kn;
        if (k0 >= K) break;
    }

    #pragma unroll
    for (int i = 0; i < 8; ++i) {
        int gm = bm + ty * 8 + i;
        if (gm >= M) continue;
        #pragma unroll
        for (int j = 0; j < NJ; ++j) {
            int gn = bn + tx + j * 16;
            if (gn >= N) continue;
            float v = acc[i][j];
            if (bias) v += bias[gn];
            if (ACT == 1) v = (v > 20.f) ? v : log1pf(__expf(v));
            C[(size_t)gm * N + gn] = v;
        }
    }
}

// ------- reorder + split: xp(2,S,1024) -> xboth(4,S,512) bf16 hi/lo -------
__global__ __launch_bounds__(256) void reorder_split_kernel(
    const float* __restrict__ xp, unsigned short* __restrict__ xh,
    unsigned short* __restrict__ xl)
{
    int idx = blockIdx.x * 256 + threadIdx.x;
    int c4 = idx & 127;
    int t  = (idx >> 7) & 1023;
    int b4 = idx >> 17;
    float4 v;
    if (b4 < 2) v = *(const float4*)&xp[((size_t)(b4 * SEQL + t)) * DI + c4 * 4];
    else        v = *(const float4*)&xp[((size_t)((b4 - 2) * SEQL + (1023 - t))) * DI + 512 + c4 * 4];
    unsigned short h0 = f2bf(v.x), h1 = f2bf(v.y), h2 = f2bf(v.z), h3 = f2bf(v.w);
    unsigned short l0 = f2bf(v.x - bf2f(h0)), l1 = f2bf(v.y - bf2f(h1));
    unsigned short l2 = f2bf(v.z - bf2f(h2)), l3 = f2bf(v.w - bf2f(h3));
    ((uint2*)xh)[idx] = make_uint2((unsigned)h0 | ((unsigned)h1 << 16), (unsigned)h2 | ((unsigned)h3 << 16));
    ((uint2*)xl)[idx] = make_uint2((unsigned)l0 | ((unsigned)l1 << 16), (unsigned)l2 | ((unsigned)l3 << 16));
}

// ------- depthwise causal conv (k=4) + silu, T layout [d][b*1024+t] -------
__global__ __launch_bounds__(256) void conv_silu_T_kernel(
    const float* __restrict__ xinT, const float* __restrict__ cw,
    const float* __restrict__ cb, float* __restrict__ xcT)
{
    int idx = blockIdx.x * 256 + threadIdx.x;   // (d, b, t4); t4 fastest
    int t4 = idx & 255;
    int b  = (idx >> 8) & 3;
    int d  = idx >> 10;
    const float* row = xinT + (size_t)d * MT + b * 1024 + t4 * 4;
    float4 cur = *(const float4*)row;
    float p1 = 0.f, p2 = 0.f, p3 = 0.f;
    if (t4 > 0) { float4 pv = *(const float4*)(row - 4); p1 = pv.y; p2 = pv.z; p3 = pv.w; }
    float w0 = cw[d * 4 + 0], w1 = cw[d * 4 + 1], w2 = cw[d * 4 + 2], w3 = cw[d * 4 + 3];
    float bv = cb[d];
    float x0 = p1, x1 = p2, x2 = p3, x3 = cur.x, x4 = cur.y, x5 = cur.z, x6 = cur.w;
    float4 o;
    o.x = bv + w0 * x0 + w1 * x1 + w2 * x2 + w3 * x3;
    o.y = bv + w0 * x1 + w1 * x2 + w2 * x3 + w3 * x4;
    o.z = bv + w0 * x2 + w1 * x3 + w2 * x4 + w3 * x5;
    o.w = bv + w0 * x3 + w1 * x4 + w2 * x5 + w3 * x6;
    o.x *= 1.f / (1.f + __expf(-o.x));
    o.y *= 1.f / (1.f + __expf(-o.y));
    o.z *= 1.f / (1.f + __expf(-o.z));
    o.w *= 1.f / (1.f + __expf(-o.w));
    *(float4*)(xcT + (size_t)d * MT + b * 1024 + t4 * 4) = o;
}

// ============ chunked selective scan, 4 chunks of 256, T-layout dt/xc ============
// Streams (b,d)=4096; wave = 4 d's, 16 lanes/d, 4 states/lane.
__global__ __launch_bounds__(256, 4) void scan_part1(
    const float* __restrict__ dtT, const float* __restrict__ xcT,
    const float* __restrict__ xdbl, const float* __restrict__ A_log,
    float* __restrict__ Sbuf, float* __restrict__ SDbuf)
{
    const int blk = blockIdx.x;          // (bb*3 + c)*64 + dblock
    const int dblock = blk & 63;
    const int bc = blk >> 6;
    const int bb = bc / 3;
    const int c  = bc - bb * 3;
    const int wave = threadIdx.x >> 6;
    const int lane = threadIdx.x & 63;
    const int dd = lane >> 4;
    const int s4 = lane & 15;
    const int d = dblock * 16 + wave * 4 + dd;
    const float LOG2E = 1.4426950408889634f;

    float A2[4], h[4];
    #pragma unroll
    for (int k = 0; k < 4; ++k) {
        A2[k] = -__expf(A_log[d * DSTATE + s4 * 4 + k]) * LOG2E;
        h[k] = 0.f;
    }
    float sumdt = 0.f;
    const int T0 = c * 256;
    const float* dtR = dtT + (size_t)d * MT + bb * 1024 + T0;
    const float* xcR = xcT + (size_t)d * MT + bb * 1024 + T0;
    const float* Bb = xdbl + ((size_t)bb * SEQL + T0) * XDBL_N + 32 + s4 * 4;

    float4 dt0, xc0, B0[4];
    float4 dt1, xc1, B1[4];

#define L1(t0, dt_, xc_, B_)                                           \
    { dt_ = *(const float4*)(dtR + (t0));                              \
      xc_ = *(const float4*)(xcR + (t0));                              \
      _Pragma("unroll")                                                \
      for (int i = 0; i < 4; ++i)                                      \
        B_[i] = *(const float4*)(Bb + (size_t)((t0) + i) * XDBL_N); }

#define S1(dtv, xcv, Bv)                                               \
    { float dtx = (dtv) * (xcv);                                       \
      sumdt += (dtv);                                                  \
      h[0] = fmaf(exp2f((dtv) * A2[0]), h[0], dtx * Bv.x);             \
      h[1] = fmaf(exp2f((dtv) * A2[1]), h[1], dtx * Bv.y);             \
      h[2] = fmaf(exp2f((dtv) * A2[2]), h[2], dtx * Bv.z);             \
      h[3] = fmaf(exp2f((dtv) * A2[3]), h[3], dtx * Bv.w); }

#define C1(dt_, xc_, B_)                                               \
    { S1(dt_.x, xc_.x, B_[0]); S1(dt_.y, xc_.y, B_[1]);                \
      S1(dt_.z, xc_.z, B_[2]); S1(dt_.w, xc_.w, B_[3]); }

    L1(0, dt0, xc0, B0);
    for (int g = 0; g < 64; g += 2) {
        L1((g + 1) * 4, dt1, xc1, B1);
        C1(dt0, xc0, B0);
        if (g + 2 < 64) L1((g + 2) * 4, dt0, xc0, B0);
        C1(dt1, xc1, B1);
    }
#undef L1
#undef S1
#undef C1

    const size_t so = ((size_t)bc * 1024 + d) * 64 + s4 * 4;
    *(float4*)&Sbuf[so] = make_float4(h[0], h[1], h[2], h[3]);
    if (s4 == 0) SDbuf[bc * 1024 + d] = sumdt;
}

// pass 2: full scan + DPP reduce; y = p + xc*D written as float4 into yT
// IN PLACE over dtT (each wave's stores trail its prefetched reads;
// blocks own disjoint (d, chunk) regions).
__global__ __launch_bounds__(256, 4) void scan_part2(
    const float* dtT, float* yT,
    const float* __restrict__ xdbl,
    const float* __restrict__ xcT,
    const float* __restrict__ A_log,
    const float* __restrict__ Dpar,
    const float* __restrict__ Sbuf,
    const float* __restrict__ SDbuf)
{
    const int blk = blockIdx.x;          // (bb*4 + c)*64 + dblock
    const int dblock = blk & 63;
    const int bc = blk >> 6;
    const int bb = bc >> 2;
    const int c  = bc & 3;
    const int wave = threadIdx.x >> 6;
    const int lane = threadIdx.x & 63;
    const int dd = lane >> 4;
    const int s4 = lane & 15;
    const int d = dblock * 16 + wave * 4 + dd;
    const float LOG2E = 1.4426950408889634f;

    float A2[4], h[4];
    #pragma unroll
    for (int k = 0; k < 4; ++k) {
        A2[k] = -__expf(A_log[d * DSTATE + s4 * 4 + k]) * LOG2E;
        h[k] = 0.f;
    }
    for (int cc = 0; cc < c; ++cc) {
        const int bcc = bb * 3 + cc;
        const size_t so = ((size_t)bcc * 1024 + d) * 64 + s4 * 4;
        float4 S = *(const float4*)&Sbuf[so];
        float sd = SDbuf[bcc * 1024 + d];
        h[0] = fmaf(exp2f(A2[0] * sd), h[0], S.x);
        h[1] = fmaf(exp2f(A2[1] * sd), h[1], S.y);
        h[2] = fmaf(exp2f(A2[2] * sd), h[2], S.z);
        h[3] = fmaf(exp2f(A2[3] * sd), h[3], S.w);
    }

    const float Dv = Dpar[d];
    const int T0 = c * 256;
    const float* dtR = dtT + (size_t)d * MT + bb * 1024 + T0;
    const float* xcR = xcT + (size_t)d * MT + bb * 1024 + T0;
    float* yR = yT + (size_t)d * MT + bb * 1024 + T0;
    const float* Bb = xdbl + ((size_t)bb * SEQL + T0) * XDBL_N + 32 + s4 * 4;

    float4 dt0, xc0, B0[4], C0[4];
    float4 dt1, xc1, B1[4], C1[4];

#define LOADC(t0, dt_, xc_, B_, C_)                                    \
    { dt_ = *(const float4*)(dtR + (t0));                              \
      xc_ = *(const float4*)(xcR + (t0));                              \
      _Pragma("unroll")                                                \
      for (int i = 0; i < 4; ++i) {                                    \
        const float* bp = Bb + (size_t)((t0) + i) * XDBL_N;            \
        B_[i] = *(const float4*)bp;                                    \
        C_[i] = *(const float4*)(bp + 64);                             \
      } }

#define STEP2(dtv, xcv, Bv, Cv, yref)                                  \
    { float dtx = (dtv) * (xcv);                                       \
      h[0] = fmaf(exp2f((dtv) * A2[0]), h[0], dtx * Bv.x);             \
      h[1] = fmaf(exp2f((dtv) * A2[1]), h[1], dtx * Bv.y);             \
      h[2] = fmaf(exp2f((dtv) * A2[2]), h[2], dtx * Bv.z);             \
      h[3] = fmaf(exp2f((dtv) * A2[3]), h[3], dtx * Bv.w);             \
      float p = h[0] * Cv.x + h[1] * Cv.y + h[2] * Cv.z + h[3] * Cv.w; \
      p = dppsum16(p);                                                 \
      yref = p + (xcv) * Dv; }

#define COMPC(t0, dt_, xc_, B_, C_)                                    \
    { float4 y4;                                                       \
      STEP2(dt_.x, xc_.x, B_[0], C_[0], y4.x);                         \
      STEP2(dt_.y, xc_.y, B_[1], C_[1], y4.y);                         \
      STEP2(dt_.z, xc_.z, B_[2], C_[2], y4.z);                         \
      STEP2(dt_.w, xc_.w, B_[3], C_[3], y4.w);                         \
      if (s4 == 0) *(float4*)(yR + (t0)) = y4; }

    LOADC(0, dt0, xc0, B0, C0);
    for (int g = 0; g < 64; g += 2) {
        LOADC((g + 1) * 4, dt1, xc1, B1, C1);
        COMPC(g * 4, dt0, xc0, B0, C0);
        if (g + 2 < 64) LOADC((g + 2) * 4, dt0, xc0, B0, C0);
        COMPC((g + 1) * 4, dt1, xc1, B1, C1);
    }
#undef LOADC
#undef STEP2
#undef COMPC
}

// ---------------- combine: out5(4,S,512) -> combined(2,S,512) ----------------
__global__ __launch_bounds__(256) void combine_kernel(
    const float* __restrict__ out5, float* __restrict__ comb)
{
    int idx = blockIdx.x * 256 + threadIdx.x;
    int c = idx & 511;
    int t = (idx >> 9) & 1023;
    int b = idx >> 19;
    float vf = out5[((size_t)(b * SEQL + t)) * 512 + c];
    float vb = out5[((size_t)((2 + b) * SEQL + (1023 - t))) * 512 + c];
    comb[idx] = vf + vb;
}

extern "C" void kernel_launch(void* const* d_in, const int* in_sizes, int n_in,
                              void* d_out, int out_size, void* d_ws, size_t ws_size,
                              hipStream_t stream)
{
    const float* x        = (const float*)d_in[0];
    const float* W_in_bi  = (const float*)d_in[1];
    const float* b_in_bi  = (const float*)d_in[2];
    const float* W_out_bi = (const float*)d_in[3];
    const float* b_out_bi = (const float*)d_in[4];
    const float* W_in     = (const float*)d_in[5];
    const float* b_in     = (const float*)d_in[6];
    const float* conv_w   = (const float*)d_in[7];
    const float* conv_b   = (const float*)d_in[8];
    const float* W_x      = (const float*)d_in[9];
    const float* W_dt     = (const float*)d_in[10];
    const float* b_dt     = (const float*)d_in[11];
    const float* A_log    = (const float*)d_in[12];
    const float* D_param  = (const float*)d_in[13];
    const float* W_out    = (const float*)d_in[14];
    const float* b_out    = (const float*)d_in[15];
    float* outp = (float*)d_out;
    char* ws = (char*)d_ws;
    const size_t MB = (size_t)1 << 20;
    typedef unsigned short us;

    // ---- regions (peak 53.55 MiB, same as proven) ----
    // A [0,16): xp[0,8)+Wbi[8,10) early -> zT (G3 -> Gout)
    // B [16,32): xbh/l[16,24)+Win[24,28) early -> xcT (conv -> part2)
    //            -> out5[16,24)+Wout[24,26)+comb[26,30) late
    // C [32,48): xinT (G2 -> conv) -> dtT (Gdt -> part2, yT in place -> Gout)
    // D [48,50.5): xdbl (Gx -> part2)
    // E [50.5,53.55): Wx/Wdt/dtr early -> Sbuf(3MB)+SDb (part1 -> part2)
    float* zT   = (float*)(ws + 0);
    float* xp   = (float*)(ws + 0);
    us* Wbi_h   = (us*)(ws + 8 * MB);
    us* Wbi_l   = (us*)(ws + 9 * MB);
    float* xcT  = (float*)(ws + 16 * MB);
    us* xbh     = (us*)(ws + 16 * MB);
    us* xbl     = (us*)(ws + 20 * MB);
    us* Win_h   = (us*)(ws + 24 * MB);
    us* Win_l   = (us*)(ws + 26 * MB);
    float* out5 = (float*)(ws + 16 * MB);
    us* Wout_h  = (us*)(ws + 24 * MB);
    us* Wout_l  = (us*)(ws + 25 * MB);
    float* comb = (float*)(ws + 26 * MB);
    float* xinT = (float*)(ws + 32 * MB);
    float* dtT  = (float*)(ws + 32 * MB);
    float* xdbl = (float*)(ws + 48 * MB);
    const size_t eb = 48 * MB + 2621440;
    us* Wx_h    = (us*)(ws + eb);
    us* Wx_l    = (us*)(ws + eb + 327680);
    us* Wdt_h   = (us*)(ws + eb + 655360);
    us* Wdt_l   = (us*)(ws + eb + 720896);
    us* dtr_h   = (us*)(ws + eb + 786432);
    us* dtr_l   = (us*)(ws + eb + 1048576);
    float* Sbuf = (float*)(ws + eb);
    float* SDb  = (float*)(ws + eb + 3145728);

    dim3 blk(256, 1, 1);

    // weight splits
    split_kernel<<<dim3(512), blk, 0, stream>>>(W_in_bi, Wbi_h, Wbi_l, 131072);
    split_kernel<<<dim3(1024), blk, 0, stream>>>(W_in, Win_h, Win_l, 262144);
    split_kernel<<<dim3(160), blk, 0, stream>>>(W_x, Wx_h, Wx_l, 40960);
    split_kernel<<<dim3(32), blk, 0, stream>>>(W_dt, Wdt_h, Wdt_l, 8192);

    // G1: xp = x @ W_in_bi^T + b_in_bi  (row-major A, BN=64 -> 256 blocks)
    agemm_kernel<0, false, false, false, 64><<<dim3(16, 16), blk, 0, stream>>>(
        x, nullptr, Wbi_h, Wbi_l, b_in_bi, xp, nullptr, nullptr, 2048, 1024, 512, 512);
    // reorder + split -> bf16 hi/lo
    reorder_split_kernel<<<dim3(2048), blk, 0, stream>>>(xp, xbh, xbl);
    // G2: xinT (transposed store); G3: zT (transposed store)
    pgemm_kernel<0, true><<<dim3(8, 32), blk, 0, stream>>>(
        xbh, xbl, Win_h, Win_l, b_in, xinT, 4096, 1024, 512, 512);
    pgemm_kernel<0, true><<<dim3(8, 32), blk, 0, stream>>>(
        xbh, xbl, Win_h + 1024 * 512, Win_l + 1024 * 512, b_in + 1024, zT, 4096, 1024, 512, 512);
    // depthwise conv + silu in T layout
    conv_silu_T_kernel<<<dim3(4096), blk, 0, stream>>>(xinT, conv_w, conv_b, xcT);
    // Gx: x_dbl = xc @ W_x^T  (A from xcT via transpose staging; fused dtr split)
    agemm_kernel<0, true, false, true, 64><<<dim3(3, 32), blk, 0, stream>>>(
        xcT, nullptr, Wx_h, Wx_l, nullptr, xdbl, dtr_h, dtr_l, 4096, 160, 1024, 0);
    // Gdt: dtT = softplus(dt_raw @ W_dt^T + b_dt) (transposed store)
    pgemm_kernel<1, true><<<dim3(8, 32), blk, 0, stream>>>(
        dtr_h, dtr_l, Wdt_h, Wdt_l, b_dt, dtT, 4096, 1024, 32, 32);
    // chunked scan (4 chunks); y written in place over dtT (T layout)
    scan_part1<<<dim3(768), blk, 0, stream>>>(dtT, xcT, xdbl, A_log, Sbuf, SDb);
    scan_part2<<<dim3(1024), blk, 0, stream>>>(dtT, dtT, xdbl, xcT, A_log, D_param, Sbuf, SDb);
    // W_out split, then Gout: A=yT (transpose-staged) with fused silu(zT) gate
    split_kernel<<<dim3(512), blk, 0, stream>>>(W_out, Wout_h, Wout_l, 131072);
    agemm_kernel<0, false, true, true, 64><<<dim3(8, 32), blk, 0, stream>>>(
        dtT, zT, Wout_h, Wout_l, b_out, out5, nullptr, nullptr, 4096, 512, 1024, 0);
    // combine forward + flipped backward
    combine_kernel<<<dim3(4096), blk, 0, stream>>>(out5, comb);
    // final = combined @ W_out_bi^T + b_out_bi (f32, accuracy-critical)
    gemm_kernel<0, 2><<<dim3(16, 16), blk, 0, stream>>>(comb, W_out_bi, b_out_bi, outp, 2048, 512, 512, 512);
}

// Round 9
// 372.247 us; speedup vs baseline: 3.1413x; 1.5000x over previous
//
#include <hip/hip_runtime.h>
#include <hip/hip_bf16.h>
#include <math.h>

#define SEQL 1024
#define DI 1024
#define DSTATE 64
#define XDBL_N 160
#define MT 4096   // total m rows (4 batches x 1024 t) for T-layout buffers

typedef short bf16x8 __attribute__((ext_vector_type(8)));
typedef float f32x4 __attribute__((ext_vector_type(4)));

__device__ __forceinline__ unsigned short f2bf(float f) {
    unsigned u = __builtin_bit_cast(unsigned, f);
    u += 0x7FFFu + ((u >> 16) & 1u);
    return (unsigned short)(u >> 16);
}
__device__ __forceinline__ float bf2f(unsigned short h) {
    unsigned u = ((unsigned)h) << 16;
    return __builtin_bit_cast(float, u);
}
__device__ __forceinline__ void gload16(const void* g, void* l) {
    __builtin_amdgcn_global_load_lds((const __attribute__((address_space(1))) void*)g,
                                     (__attribute__((address_space(3))) void*)l, 16, 0, 0);
}
// 16-lane row-sum via DPP row_shr; total lands in lane (row16*16+0).
__device__ __forceinline__ float dppsum16(float p) {
    int q;
    q = __builtin_amdgcn_update_dpp(0, __builtin_bit_cast(int, p), 0x118, 0xF, 0xF, true);
    p += __builtin_bit_cast(float, q);
    q = __builtin_amdgcn_update_dpp(0, __builtin_bit_cast(int, p), 0x114, 0xF, 0xF, true);
    p += __builtin_bit_cast(float, q);
    q = __builtin_amdgcn_update_dpp(0, __builtin_bit_cast(int, p), 0x112, 0xF, 0xF, true);
    p += __builtin_bit_cast(float, q);
    q = __builtin_amdgcn_update_dpp(0, __builtin_bit_cast(int, p), 0x111, 0xF, 0xF, true);
    p += __builtin_bit_cast(float, q);
    return p;
}

// ---------------- generic f32 -> bf16 hi/lo split ----------------
__global__ __launch_bounds__(256) void split_kernel(
    const float* __restrict__ src, unsigned short* __restrict__ h,
    unsigned short* __restrict__ l, int n4)
{
    int i = blockIdx.x * 256 + threadIdx.x;
    if (i >= n4) return;
    float4 v = ((const float4*)src)[i];
    unsigned short h0 = f2bf(v.x), h1 = f2bf(v.y), h2 = f2bf(v.z), h3 = f2bf(v.w);
    unsigned short l0 = f2bf(v.x - bf2f(h0)), l1 = f2bf(v.y - bf2f(h1));
    unsigned short l2 = f2bf(v.z - bf2f(h2)), l3 = f2bf(v.w - bf2f(h3));
    ((uint2*)h)[i] = make_uint2((unsigned)h0 | ((unsigned)h1 << 16), (unsigned)h2 | ((unsigned)h3 << 16));
    ((uint2*)l)[i] = make_uint2((unsigned)l0 | ((unsigned)l1 << 16), (unsigned)l2 | ((unsigned)l3 << 16));
}

// ---------- pre-split bf16 MFMA GEMM, 64x64 tile (4 blocks/CU) ----------
// A: Ah/Al (M,K) bf16 lda; W: Wh/Wl (N,K) bf16. C = act(A@W^T + bias) f32.
// M%64==0, N%64==0, K%32==0. 4 waves x 32x32 outputs. TRANS: C stored CT[n][m].
template<int ACT, bool TRANS>
__global__ __launch_bounds__(256) void pgemm_kernel(
    const unsigned short* __restrict__ Ah, const unsigned short* __restrict__ Al,
    const unsigned short* __restrict__ Wh, const unsigned short* __restrict__ Wl,
    const float* __restrict__ bias, float* __restrict__ C,
    int M, int N, int K, int lda)
{
    __shared__ unsigned short L[2][4][64 * 32];   // [buf][Ah,Al,Wh,Wl]
    const int tid = threadIdx.x;
    const int bm = blockIdx.y * 64, bn = blockIdx.x * 64;
    const int wv = tid >> 6, lane = tid & 63;
    const int wm = (wv & 1) * 32, wn = (wv >> 1) * 32;
    const int fr = lane & 15, fg = lane >> 4;
    const int srow = tid >> 2, scol = (tid & 3) * 8;   // LDS dst = tid*16B (linear)

    f32x4 acc[2][2];
    #pragma unroll
    for (int i = 0; i < 2; ++i)
        #pragma unroll
        for (int j = 0; j < 2; ++j) acc[i][j] = (f32x4){0.f, 0.f, 0.f, 0.f};

    const int lo = srow * 32 + scol;
    auto stage = [&](int buf, int kt) {
        const int kc = kt * 32 + scol;
        gload16(Ah + (size_t)(bm + srow) * lda + kc, &L[buf][0][lo]);
        gload16(Al + (size_t)(bm + srow) * lda + kc, &L[buf][1][lo]);
        gload16(Wh + (size_t)(bn + srow) * K + kc, &L[buf][2][lo]);
        gload16(Wl + (size_t)(bn + srow) * K + kc, &L[buf][3][lo]);
    };

    const int NT = K / 32;
    stage(0, 0);
    for (int kt = 0;;) {
        __syncthreads();                 // drains vmcnt: buf(kt) ready
        if (kt + 1 < NT) stage((kt + 1) & 1, kt + 1);
        const unsigned short* lah = &L[kt & 1][0][0];
        const unsigned short* lal = &L[kt & 1][1][0];
        const unsigned short* lbh = &L[kt & 1][2][0];
        const unsigned short* lbl = &L[kt & 1][3][0];
        bf16x8 fah[2], fal[2], fbh[2], fbl[2];
        #pragma unroll
        for (int i = 0; i < 2; ++i) {
            const int ra = (wm + i * 16 + fr) * 32 + fg * 8;
            const int rb = (wn + i * 16 + fr) * 32 + fg * 8;
            fah[i] = *(const bf16x8*)&lah[ra];
            fal[i] = *(const bf16x8*)&lal[ra];
            fbh[i] = *(const bf16x8*)&lbh[rb];
            fbl[i] = *(const bf16x8*)&lbl[rb];
        }
        #pragma unroll
        for (int i = 0; i < 2; ++i)
            #pragma unroll
            for (int j = 0; j < 2; ++j) {
                acc[i][j] = __builtin_amdgcn_mfma_f32_16x16x32_bf16(fal[i], fbh[j], acc[i][j], 0, 0, 0);
                acc[i][j] = __builtin_amdgcn_mfma_f32_16x16x32_bf16(fah[i], fbl[j], acc[i][j], 0, 0, 0);
                acc[i][j] = __builtin_amdgcn_mfma_f32_16x16x32_bf16(fah[i], fbh[j], acc[i][j], 0, 0, 0);
            }
        ++kt;
        if (kt >= NT) break;
    }

    #pragma unroll
    for (int i = 0; i < 2; ++i) {
        const int gmb = bm + wm + i * 16 + fg * 4;
        #pragma unroll
        for (int j = 0; j < 2; ++j) {
            const int gn = bn + wn + j * 16 + fr;
            const float bv = bias ? bias[gn] : 0.f;
            float4 v4;
            float* vp = &v4.x;
            #pragma unroll
            for (int r = 0; r < 4; ++r) {
                float v = acc[i][j][r] + bv;
                if (ACT == 1) v = (v > 20.f) ? v : log1pf(__expf(v));
                vp[r] = v;
            }
            if (TRANS) {
                *(float4*)&C[(size_t)gn * M + gmb] = v4;
            } else {
                #pragma unroll
                for (int r = 0; r < 4; ++r) C[(size_t)(gmb + r) * N + gn] = vp[r];
            }
        }
    }
}

// ---------- A-f32 MFMA GEMM, 64x64 tile: A converted in-kernel, W pre-split ----------
// ATRANS: A given as AT[k][m] (stride M), LDS-transposed with XOR group swizzle.
// GATE: A *= silu(Z) (Z same layout). DUAL: also emit bf16 hi/lo of C for gn<32.
template<int ACT, bool DUAL, bool GATE, bool ATRANS>
__global__ __launch_bounds__(256) void agemm_kernel(
    const float* __restrict__ A, const float* __restrict__ Z,
    const unsigned short* __restrict__ Wh, const unsigned short* __restrict__ Wl,
    const float* __restrict__ bias, float* __restrict__ C,
    unsigned short* __restrict__ dh, unsigned short* __restrict__ dl,
    int M, int N, int K, int lda)
{
    __shared__ unsigned short LAh[64 * 40];
    __shared__ unsigned short LAl[64 * 40];
    __shared__ unsigned short LBh[64 * 40];
    __shared__ unsigned short LBl[64 * 40];
    const int tid = threadIdx.x;
    const int bm = blockIdx.y * 64, bn = blockIdx.x * 64;
    const int wv = tid >> 6, lane = tid & 63;
    const int wm = (wv & 1) * 32, wn = (wv >> 1) * 32;
    const int fr = lane & 15, fg = lane >> 4;

    // B staging (row-major W): 4 threads/row x 8 ushorts
    const int srow = tid >> 2, sc = (tid & 3) * 8;
    const unsigned short* Whp = Wh + (size_t)(bn + srow) * K + sc;
    const unsigned short* Wlp = Wl + (size_t)(bn + srow) * K + sc;
    const bool wok = (bn + srow) < N;
    const uint4 zu = {0u, 0u, 0u, 0u};

    // A staging (ATRANS): k-pair kp = tid>>4 (k=2kp,2kp+1), m = mo..mo+3
    const int kp = tid >> 4;
    const int mo = (tid & 15) * 4;
    const float* At0 = ATRANS ? (A + (size_t)(2 * kp) * M + bm + mo) : nullptr;
    const float* At1 = ATRANS ? (At0 + M) : nullptr;
    const float* Zt0 = (ATRANS && GATE) ? (Z + (size_t)(2 * kp) * M + bm + mo) : nullptr;
    const float* Zt1 = (ATRANS && GATE) ? (Zt0 + M) : nullptr;
    const int swg = (kp >> 2) ^ (((tid & 15) >> 1) & 3);   // == (kp>>2) ^ ((m>>3)&3)
    const int swoff = swg * 8 + (kp & 3) * 2;
    // A staging (!ATRANS): row-major A
    const float* Ap = ATRANS ? nullptr : (A + (size_t)(bm + srow) * lda + sc);

    f32x4 acc[2][2];
    #pragma unroll
    for (int i = 0; i < 2; ++i)
        #pragma unroll
        for (int j = 0; j < 2; ++j) acc[i][j] = (f32x4){0.f, 0.f, 0.f, 0.f};

    alignas(16) float pa0[4], pa1[4], pz0[4], pz1[4];
    alignas(16) float pa[8];
    uint4 pbh, pbl;

    auto prefetch = [&](int k0) {
        if (ATRANS) {
            const size_t off = (size_t)k0 * M;
            *(float4*)&pa0[0] = *(const float4*)(At0 + off);
            *(float4*)&pa1[0] = *(const float4*)(At1 + off);
            if (GATE) {
                *(float4*)&pz0[0] = *(const float4*)(Zt0 + off);
                *(float4*)&pz1[0] = *(const float4*)(Zt1 + off);
            }
        } else {
            *(float4*)&pa[0] = *(const float4*)(Ap + k0);
            *(float4*)&pa[4] = *(const float4*)(Ap + k0 + 4);
        }
        if (wok) {
            pbh = *(const uint4*)(Whp + k0);
            pbl = *(const uint4*)(Wlp + k0);
        } else { pbh = zu; pbl = zu; }
    };

    prefetch(0);
    const int NT = K / 32;
    for (int kt = 0;;) {
        __syncthreads();
        if (ATRANS) {
            #pragma unroll
            for (int j = 0; j < 4; ++j) {
                float v0 = pa0[j], v1 = pa1[j];
                if (GATE) {
                    float z0 = pz0[j], z1 = pz1[j];
                    v0 *= z0 / (1.f + __expf(-z0));
                    v1 *= z1 / (1.f + __expf(-z1));
                }
                unsigned short h0 = f2bf(v0), h1 = f2bf(v1);
                unsigned short l0 = f2bf(v0 - bf2f(h0)), l1 = f2bf(v1 - bf2f(h1));
                const int a = (mo + j) * 40 + swoff;
                *(unsigned*)&LAh[a] = (unsigned)h0 | ((unsigned)h1 << 16);
                *(unsigned*)&LAl[a] = (unsigned)l0 | ((unsigned)l1 << 16);
            }
        } else {
            alignas(16) unsigned short hh[8], ll[8];
            #pragma unroll
            for (int i = 0; i < 8; ++i) {
                float v = pa[i];
                unsigned short h = f2bf(v);
                hh[i] = h; ll[i] = f2bf(v - bf2f(h));
            }
            const int wb = srow * 40 + sc;
            *(uint4*)&LAh[wb] = *(uint4*)&hh[0];
            *(uint4*)&LAl[wb] = *(uint4*)&ll[0];
        }
        {
            const int wb = srow * 40 + sc;
            *(uint4*)&LBh[wb] = pbh;
            *(uint4*)&LBl[wb] = pbl;
        }
        __syncthreads();
        if (kt + 1 < NT) prefetch((kt + 1) * 32);
        bf16x8 fah[2], fal[2], fbh[2], fbl[2];
        #pragma unroll
        for (int i = 0; i < 2; ++i) {
            const int mrow = wm + i * 16 + fr;
            const int g = ATRANS ? (fg ^ ((mrow >> 3) & 3)) : fg;
            const int ra = mrow * 40 + g * 8;
            fah[i] = *(const bf16x8*)&LAh[ra];
            fal[i] = *(const bf16x8*)&LAl[ra];
        }
        #pragma unroll
        for (int j = 0; j < 2; ++j) {
            const int rb = (wn + j * 16 + fr) * 40 + fg * 8;
            fbh[j] = *(const bf16x8*)&LBh[rb];
            fbl[j] = *(const bf16x8*)&LBl[rb];
        }
        #pragma unroll
        for (int i = 0; i < 2; ++i)
            #pragma unroll
            for (int j = 0; j < 2; ++j) {
                acc[i][j] = __builtin_amdgcn_mfma_f32_16x16x32_bf16(fal[i], fbh[j], acc[i][j], 0, 0, 0);
                acc[i][j] = __builtin_amdgcn_mfma_f32_16x16x32_bf16(fah[i], fbl[j], acc[i][j], 0, 0, 0);
                acc[i][j] = __builtin_amdgcn_mfma_f32_16x16x32_bf16(fah[i], fbh[j], acc[i][j], 0, 0, 0);
            }
        ++kt;
        if (kt >= NT) break;
    }

    #pragma unroll
    for (int i = 0; i < 2; ++i) {
        const int gmb = bm + wm + i * 16 + fg * 4;
        #pragma unroll
        for (int j = 0; j < 2; ++j) {
            const int gn = bn + wn + j * 16 + fr;
            if (gn >= N) continue;
            const float bv = bias ? bias[gn] : 0.f;
            #pragma unroll
            for (int r = 0; r < 4; ++r) {
                float v = acc[i][j][r] + bv;
                if (ACT == 1) v = (v > 20.f) ? v : log1pf(__expf(v));
                C[(size_t)(gmb + r) * N + gn] = v;
                if (DUAL && gn < 32) {
                    unsigned short h = f2bf(v);
                    dh[(size_t)(gmb + r) * 32 + gn] = h;
                    dl[(size_t)(gmb + r) * 32 + gn] = f2bf(v - bf2f(h));
                }
            }
        }
    }
}

// ------- reorder + split: xp(2,S,1024) -> xboth(4,S,512) bf16 hi/lo -------
__global__ __launch_bounds__(256) void reorder_split_kernel(
    const float* __restrict__ xp, unsigned short* __restrict__ xh,
    unsigned short* __restrict__ xl)
{
    int idx = blockIdx.x * 256 + threadIdx.x;
    int c4 = idx & 127;
    int t  = (idx >> 7) & 1023;
    int b4 = idx >> 17;
    float4 v;
    if (b4 < 2) v = *(const float4*)&xp[((size_t)(b4 * SEQL + t)) * DI + c4 * 4];
    else        v = *(const float4*)&xp[((size_t)((b4 - 2) * SEQL + (1023 - t))) * DI + 512 + c4 * 4];
    unsigned short h0 = f2bf(v.x), h1 = f2bf(v.y), h2 = f2bf(v.z), h3 = f2bf(v.w);
    unsigned short l0 = f2bf(v.x - bf2f(h0)), l1 = f2bf(v.y - bf2f(h1));
    unsigned short l2 = f2bf(v.z - bf2f(h2)), l3 = f2bf(v.w - bf2f(h3));
    ((uint2*)xh)[idx] = make_uint2((unsigned)h0 | ((unsigned)h1 << 16), (unsigned)h2 | ((unsigned)h3 << 16));
    ((uint2*)xl)[idx] = make_uint2((unsigned)l0 | ((unsigned)l1 << 16), (unsigned)l2 | ((unsigned)l3 << 16));
}

// ------- depthwise causal conv (k=4) + silu, T layout [d][b*1024+t] -------
__global__ __launch_bounds__(256) void conv_silu_T_kernel(
    const float* __restrict__ xinT, const float* __restrict__ cw,
    const float* __restrict__ cb, float* __restrict__ xcT)
{
    int idx = blockIdx.x * 256 + threadIdx.x;   // (d, b, t4); t4 fastest
    int t4 = idx & 255;
    int b  = (idx >> 8) & 3;
    int d  = idx >> 10;
    const float* row = xinT + (size_t)d * MT + b * 1024 + t4 * 4;
    float4 cur = *(const float4*)row;
    float p1 = 0.f, p2 = 0.f, p3 = 0.f;
    if (t4 > 0) { float4 pv = *(const float4*)(row - 4); p1 = pv.y; p2 = pv.z; p3 = pv.w; }
    float w0 = cw[d * 4 + 0], w1 = cw[d * 4 + 1], w2 = cw[d * 4 + 2], w3 = cw[d * 4 + 3];
    float bv = cb[d];
    float x0 = p1, x1 = p2, x2 = p3, x3 = cur.x, x4 = cur.y, x5 = cur.z, x6 = cur.w;
    float4 o;
    o.x = bv + w0 * x0 + w1 * x1 + w2 * x2 + w3 * x3;
    o.y = bv + w0 * x1 + w1 * x2 + w2 * x3 + w3 * x4;
    o.z = bv + w0 * x2 + w1 * x3 + w2 * x4 + w3 * x5;
    o.w = bv + w0 * x3 + w1 * x4 + w2 * x5 + w3 * x6;
    o.x *= 1.f / (1.f + __expf(-o.x));
    o.y *= 1.f / (1.f + __expf(-o.y));
    o.z *= 1.f / (1.f + __expf(-o.z));
    o.w *= 1.f / (1.f + __expf(-o.w));
    *(float4*)(xcT + (size_t)d * MT + b * 1024 + t4 * 4) = o;
}

// ============ chunked selective scan, 4 chunks of 256, T-layout dt/xc ============
__global__ __launch_bounds__(256, 4) void scan_part1(
    const float* __restrict__ dtT, const float* __restrict__ xcT,
    const float* __restrict__ xdbl, const float* __restrict__ A_log,
    float* __restrict__ Sbuf, float* __restrict__ SDbuf)
{
    const int blk = blockIdx.x;          // (bb*3 + c)*64 + dblock
    const int dblock = blk & 63;
    const int bc = blk >> 6;
    const int bb = bc / 3;
    const int c  = bc - bb * 3;
    const int wave = threadIdx.x >> 6;
    const int lane = threadIdx.x & 63;
    const int dd = lane >> 4;
    const int s4 = lane & 15;
    const int d = dblock * 16 + wave * 4 + dd;
    const float LOG2E = 1.4426950408889634f;

    float A2[4], h[4];
    #pragma unroll
    for (int k = 0; k < 4; ++k) {
        A2[k] = -__expf(A_log[d * DSTATE + s4 * 4 + k]) * LOG2E;
        h[k] = 0.f;
    }
    float sumdt = 0.f;
    const int T0 = c * 256;
    const float* dtR = dtT + (size_t)d * MT + bb * 1024 + T0;
    const float* xcR = xcT + (size_t)d * MT + bb * 1024 + T0;
    const float* Bb = xdbl + ((size_t)bb * SEQL + T0) * XDBL_N + 32 + s4 * 4;

    float4 dt0, xc0, B0[4];
    float4 dt1, xc1, B1[4];

#define L1(t0, dt_, xc_, B_)                                           \
    { dt_ = *(const float4*)(dtR + (t0));                              \
      xc_ = *(const float4*)(xcR + (t0));                              \
      _Pragma("unroll")                                                \
      for (int i = 0; i < 4; ++i)                                      \
        B_[i] = *(const float4*)(Bb + (size_t)((t0) + i) * XDBL_N); }

#define S1(dtv, xcv, Bv)                                               \
    { float dtx = (dtv) * (xcv);                                       \
      sumdt += (dtv);                                                  \
      h[0] = fmaf(exp2f((dtv) * A2[0]), h[0], dtx * Bv.x);             \
      h[1] = fmaf(exp2f((dtv) * A2[1]), h[1], dtx * Bv.y);             \
      h[2] = fmaf(exp2f((dtv) * A2[2]), h[2], dtx * Bv.z);             \
      h[3] = fmaf(exp2f((dtv) * A2[3]), h[3], dtx * Bv.w); }

#define C1(dt_, xc_, B_)                                               \
    { S1(dt_.x, xc_.x, B_[0]); S1(dt_.y, xc_.y, B_[1]);                \
      S1(dt_.z, xc_.z, B_[2]); S1(dt_.w, xc_.w, B_[3]); }

    L1(0, dt0, xc0, B0);
    for (int g = 0; g < 64; g += 2) {
        L1((g + 1) * 4, dt1, xc1, B1);
        C1(dt0, xc0, B0);
        if (g + 2 < 64) L1((g + 2) * 4, dt0, xc0, B0);
        C1(dt1, xc1, B1);
    }
#undef L1
#undef S1
#undef C1

    const size_t so = ((size_t)bc * 1024 + d) * 64 + s4 * 4;
    *(float4*)&Sbuf[so] = make_float4(h[0], h[1], h[2], h[3]);
    if (s4 == 0) SDbuf[bc * 1024 + d] = sumdt;
}

// pass 2: full scan + DPP reduce; y = p + xc*D written float4 into yT
// IN PLACE over dtT (stores trail prefetched reads; disjoint regions per block).
__global__ __launch_bounds__(256, 4) void scan_part2(
    const float* dtT, float* yT,
    const float* __restrict__ xdbl,
    const float* __restrict__ xcT,
    const float* __restrict__ A_log,
    const float* __restrict__ Dpar,
    const float* __restrict__ Sbuf,
    const float* __restrict__ SDbuf)
{
    const int blk = blockIdx.x;          // (bb*4 + c)*64 + dblock
    const int dblock = blk & 63;
    const int bc = blk >> 6;
    const int bb = bc >> 2;
    const int c  = bc & 3;
    const int wave = threadIdx.x >> 6;
    const int lane = threadIdx.x & 63;
    const int dd = lane >> 4;
    const int s4 = lane & 15;
    const int d = dblock * 16 + wave * 4 + dd;
    const float LOG2E = 1.4426950408889634f;

    float A2[4], h[4];
    #pragma unroll
    for (int k = 0; k < 4; ++k) {
        A2[k] = -__expf(A_log[d * DSTATE + s4 * 4 + k]) * LOG2E;
        h[k] = 0.f;
    }
    for (int cc = 0; cc < c; ++cc) {
        const int bcc = bb * 3 + cc;
        const size_t so = ((size_t)bcc * 1024 + d) * 64 + s4 * 4;
        float4 S = *(const float4*)&Sbuf[so];
        float sd = SDbuf[bcc * 1024 + d];
        h[0] = fmaf(exp2f(A2[0] * sd), h[0], S.x);
        h[1] = fmaf(exp2f(A2[1] * sd), h[1], S.y);
        h[2] = fmaf(exp2f(A2[2] * sd), h[2], S.z);
        h[3] = fmaf(exp2f(A2[3] * sd), h[3], S.w);
    }

    const float Dv = Dpar[d];
    const int T0 = c * 256;
    const float* dtR = dtT + (size_t)d * MT + bb * 1024 + T0;
    const float* xcR = xcT + (size_t)d * MT + bb * 1024 + T0;
    float* yR = yT + (size_t)d * MT + bb * 1024 + T0;
    const float* Bb = xdbl + ((size_t)bb * SEQL + T0) * XDBL_N + 32 + s4 * 4;

    float4 dt0, xc0, B0[4], C0[4];
    float4 dt1, xc1, B1[4], C1[4];

#define LOADC(t0, dt_, xc_, B_, C_)                                    \
    { dt_ = *(const float4*)(dtR + (t0));                              \
      xc_ = *(const float4*)(xcR + (t0));                              \
      _Pragma("unroll")                                                \
      for (int i = 0; i < 4; ++i) {                                    \
        const float* bp = Bb + (size_t)((t0) + i) * XDBL_N;            \
        B_[i] = *(const float4*)bp;                                    \
        C_[i] = *(const float4*)(bp + 64);                             \
      } }

#define STEP2(dtv, xcv, Bv, Cv, yref)                                  \
    { float dtx = (dtv) * (xcv);                                       \
      h[0] = fmaf(exp2f((dtv) * A2[0]), h[0], dtx * Bv.x);             \
      h[1] = fmaf(exp2f((dtv) * A2[1]), h[1], dtx * Bv.y);             \
      h[2] = fmaf(exp2f((dtv) * A2[2]), h[2], dtx * Bv.z);             \
      h[3] = fmaf(exp2f((dtv) * A2[3]), h[3], dtx * Bv.w);             \
      float p = h[0] * Cv.x + h[1] * Cv.y + h[2] * Cv.z + h[3] * Cv.w; \
      p = dppsum16(p);                                                 \
      yref = p + (xcv) * Dv; }

#define COMPC(t0, dt_, xc_, B_, C_)                                    \
    { float4 y4;                                                       \
      STEP2(dt_.x, xc_.x, B_[0], C_[0], y4.x);                         \
      STEP2(dt_.y, xc_.y, B_[1], C_[1], y4.y);                         \
      STEP2(dt_.z, xc_.z, B_[2], C_[2], y4.z);                         \
      STEP2(dt_.w, xc_.w, B_[3], C_[3], y4.w);                         \
      if (s4 == 0) *(float4*)(yR + (t0)) = y4; }

    LOADC(0, dt0, xc0, B0, C0);
    for (int g = 0; g < 64; g += 2) {
        LOADC((g + 1) * 4, dt1, xc1, B1, C1);
        COMPC(g * 4, dt0, xc0, B0, C0);
        if (g + 2 < 64) LOADC((g + 2) * 4, dt0, xc0, B0, C0);
        COMPC((g + 1) * 4, dt1, xc1, B1, C1);
    }
#undef LOADC
#undef STEP2
#undef COMPC
}

// ---------------- combine: out5(4,S,512) -> combined(2,S,512) ----------------
__global__ __launch_bounds__(256) void combine_kernel(
    const float* __restrict__ out5, float* __restrict__ comb)
{
    int idx = blockIdx.x * 256 + threadIdx.x;
    int c = idx & 511;
    int t = (idx >> 9) & 1023;
    int b = idx >> 19;
    float vf = out5[((size_t)(b * SEQL + t)) * 512 + c];
    float vb = out5[((size_t)((2 + b) * SEQL + (1023 - t))) * 512 + c];
    comb[idx] = vf + vb;
}

extern "C" void kernel_launch(void* const* d_in, const int* in_sizes, int n_in,
                              void* d_out, int out_size, void* d_ws, size_t ws_size,
                              hipStream_t stream)
{
    const float* x        = (const float*)d_in[0];
    const float* W_in_bi  = (const float*)d_in[1];
    const float* b_in_bi  = (const float*)d_in[2];
    const float* W_out_bi = (const float*)d_in[3];
    const float* b_out_bi = (const float*)d_in[4];
    const float* W_in     = (const float*)d_in[5];
    const float* b_in     = (const float*)d_in[6];
    const float* conv_w   = (const float*)d_in[7];
    const float* conv_b   = (const float*)d_in[8];
    const float* W_x      = (const float*)d_in[9];
    const float* W_dt     = (const float*)d_in[10];
    const float* b_dt     = (const float*)d_in[11];
    const float* A_log    = (const float*)d_in[12];
    const float* D_param  = (const float*)d_in[13];
    const float* W_out    = (const float*)d_in[14];
    const float* b_out    = (const float*)d_in[15];
    float* outp = (float*)d_out;
    char* ws = (char*)d_ws;
    const size_t MB = (size_t)1 << 20;
    typedef unsigned short us;

    // ---- regions (peak 53.55 MiB) ----
    float* zT   = (float*)(ws + 0);          // A [0,16): zT (G3 -> Gout)
    float* xp   = (float*)(ws + 0);          //   early: xp [0,8)
    us* Wbi_h   = (us*)(ws + 8 * MB);        //   early: Wbi [8,10)
    us* Wbi_l   = (us*)(ws + 9 * MB);
    us* Wbi2_h  = (us*)(ws + 0);             //   late (after Gout): W_out_bi split [0,1)
    us* Wbi2_l  = (us*)(ws + 524288);
    float* xcT  = (float*)(ws + 16 * MB);    // B [16,32): xcT (conv -> part2)
    us* xbh     = (us*)(ws + 16 * MB);       //   early: xb [16,24)
    us* xbl     = (us*)(ws + 20 * MB);
    us* Win_h   = (us*)(ws + 24 * MB);       //   early: Win [24,28)
    us* Win_l   = (us*)(ws + 26 * MB);
    float* out5 = (float*)(ws + 16 * MB);    //   late: out5 [16,24)
    us* Wout_h  = (us*)(ws + 24 * MB);       //   late: Wout [24,26)
    us* Wout_l  = (us*)(ws + 25 * MB);
    float* comb = (float*)(ws + 26 * MB);    //   late: comb [26,30)
    float* xinT = (float*)(ws + 32 * MB);    // C [32,48): xinT -> dtT/yT
    float* dtT  = (float*)(ws + 32 * MB);
    float* xdbl = (float*)(ws + 48 * MB);    // D [48,50.5)
    const size_t eb = 48 * MB + 2621440;     // E [50.5,53.55)
    us* Wx_h    = (us*)(ws + eb);
    us* Wx_l    = (us*)(ws + eb + 327680);
    us* Wdt_h   = (us*)(ws + eb + 655360);
    us* Wdt_l   = (us*)(ws + eb + 720896);
    us* dtr_h   = (us*)(ws + eb + 786432);
    us* dtr_l   = (us*)(ws + eb + 1048576);
    float* Sbuf = (float*)(ws + eb);
    float* SDb  = (float*)(ws + eb + 3145728);

    dim3 blk(256, 1, 1);

    // weight splits (Wbi2 deferred until zT region is dead)
    split_kernel<<<dim3(512), blk, 0, stream>>>(W_in_bi, Wbi_h, Wbi_l, 131072);
    split_kernel<<<dim3(1024), blk, 0, stream>>>(W_in, Win_h, Win_l, 262144);
    split_kernel<<<dim3(160), blk, 0, stream>>>(W_x, Wx_h, Wx_l, 40960);
    split_kernel<<<dim3(32), blk, 0, stream>>>(W_dt, Wdt_h, Wdt_l, 8192);

    // G1: xp = x @ W_in_bi^T + b_in_bi  (512 blocks)
    agemm_kernel<0, false, false, false><<<dim3(16, 32), blk, 0, stream>>>(
        x, nullptr, Wbi_h, Wbi_l, b_in_bi, xp, nullptr, nullptr, 2048, 1024, 512, 512);
    // reorder + split -> bf16 hi/lo
    reorder_split_kernel<<<dim3(2048), blk, 0, stream>>>(xp, xbh, xbl);
    // G2: xinT; G3: zT (transposed stores; 1024 blocks each)
    pgemm_kernel<0, true><<<dim3(16, 64), blk, 0, stream>>>(
        xbh, xbl, Win_h, Win_l, b_in, xinT, 4096, 1024, 512, 512);
    pgemm_kernel<0, true><<<dim3(16, 64), blk, 0, stream>>>(
        xbh, xbl, Win_h + 1024 * 512, Win_l + 1024 * 512, b_in + 1024, zT, 4096, 1024, 512, 512);
    // depthwise conv + silu in T layout
    conv_silu_T_kernel<<<dim3(4096), blk, 0, stream>>>(xinT, conv_w, conv_b, xcT);
    // Gx: x_dbl = xc @ W_x^T (A from xcT, transpose staged; fused dtr split)
    agemm_kernel<0, true, false, true><<<dim3(3, 64), blk, 0, stream>>>(
        xcT, nullptr, Wx_h, Wx_l, nullptr, xdbl, dtr_h, dtr_l, 4096, 160, 1024, 0);
    // Gdt: dtT = softplus(dt_raw @ W_dt^T + b_dt) (transposed store; 1024 blocks)
    pgemm_kernel<1, true><<<dim3(16, 64), blk, 0, stream>>>(
        dtr_h, dtr_l, Wdt_h, Wdt_l, b_dt, dtT, 4096, 1024, 32, 32);
    // chunked scan (4 chunks); y written in place over dtT
    scan_part1<<<dim3(768), blk, 0, stream>>>(dtT, xcT, xdbl, A_log, Sbuf, SDb);
    scan_part2<<<dim3(1024), blk, 0, stream>>>(dtT, dtT, xdbl, xcT, A_log, D_param, Sbuf, SDb);
    // W_out split, then Gout: A=yT (transpose-staged) with fused silu(zT) gate
    split_kernel<<<dim3(512), blk, 0, stream>>>(W_out, Wout_h, Wout_l, 131072);
    agemm_kernel<0, false, true, true><<<dim3(8, 64), blk, 0, stream>>>(
        dtT, zT, Wout_h, Wout_l, b_out, out5, nullptr, nullptr, 4096, 512, 1024, 0);
    // zT now dead -> split W_out_bi into [0,1) MB
    split_kernel<<<dim3(256), blk, 0, stream>>>(W_out_bi, Wbi2_h, Wbi2_l, 65536);
    // combine forward + flipped backward
    combine_kernel<<<dim3(4096), blk, 0, stream>>>(out5, comb);
    // final = combined @ W_out_bi^T + b_out_bi (split-bf16 MFMA; 256 blocks)
    agemm_kernel<0, false, false, false><<<dim3(8, 32), blk, 0, stream>>>(
        comb, nullptr, Wbi2_h, Wbi2_l, b_out_bi, outp, nullptr, nullptr, 2048, 512, 512, 512);
}

// Round 10
// 330.701 us; speedup vs baseline: 3.5360x; 1.1256x over previous
//
#include <hip/hip_runtime.h>
#include <hip/hip_bf16.h>
#include <math.h>

#define SEQL 1024
#define DI 1024
#define DSTATE 64
#define XDBL_N 160
#define MT 4096   // total m rows (4 batches x 1024 t) for T-layout buffers

typedef short bf16x8 __attribute__((ext_vector_type(8)));
typedef float f32x4 __attribute__((ext_vector_type(4)));

__device__ __forceinline__ unsigned short f2bf(float f) {
    unsigned u = __builtin_bit_cast(unsigned, f);
    u += 0x7FFFu + ((u >> 16) & 1u);
    return (unsigned short)(u >> 16);
}
__device__ __forceinline__ float bf2f(unsigned short h) {
    unsigned u = ((unsigned)h) << 16;
    return __builtin_bit_cast(float, u);
}
__device__ __forceinline__ void gload16(const void* g, void* l) {
    __builtin_amdgcn_global_load_lds((const __attribute__((address_space(1))) void*)g,
                                     (__attribute__((address_space(3))) void*)l, 16, 0, 0);
}
// raw hardware 2^x (single v_exp_f32; args here stay in normal range,
// large negatives flush to 0 which is the correct limit)
__device__ __forceinline__ float fexp2(float x) {
#if __has_builtin(__builtin_amdgcn_exp2f)
    return __builtin_amdgcn_exp2f(x);
#else
    float r; asm("v_exp_f32 %0, %1" : "=v"(r) : "v"(x)); return r;
#endif
}
// 16-lane row-sum via DPP row_shr; total lands in lane (row16*16+0).
__device__ __forceinline__ float dppsum16(float p) {
    int q;
    q = __builtin_amdgcn_update_dpp(0, __builtin_bit_cast(int, p), 0x118, 0xF, 0xF, true);
    p += __builtin_bit_cast(float, q);
    q = __builtin_amdgcn_update_dpp(0, __builtin_bit_cast(int, p), 0x114, 0xF, 0xF, true);
    p += __builtin_bit_cast(float, q);
    q = __builtin_amdgcn_update_dpp(0, __builtin_bit_cast(int, p), 0x112, 0xF, 0xF, true);
    p += __builtin_bit_cast(float, q);
    q = __builtin_amdgcn_update_dpp(0, __builtin_bit_cast(int, p), 0x111, 0xF, 0xF, true);
    p += __builtin_bit_cast(float, q);
    return p;
}

// ---------------- generic f32 -> bf16 hi/lo split ----------------
__global__ __launch_bounds__(256) void split_kernel(
    const float* __restrict__ src, unsigned short* __restrict__ h,
    unsigned short* __restrict__ l, int n4)
{
    int i = blockIdx.x * 256 + threadIdx.x;
    if (i >= n4) return;
    float4 v = ((const float4*)src)[i];
    unsigned short h0 = f2bf(v.x), h1 = f2bf(v.y), h2 = f2bf(v.z), h3 = f2bf(v.w);
    unsigned short l0 = f2bf(v.x - bf2f(h0)), l1 = f2bf(v.y - bf2f(h1));
    unsigned short l2 = f2bf(v.z - bf2f(h2)), l3 = f2bf(v.w - bf2f(h3));
    ((uint2*)h)[i] = make_uint2((unsigned)h0 | ((unsigned)h1 << 16), (unsigned)h2 | ((unsigned)h3 << 16));
    ((uint2*)l)[i] = make_uint2((unsigned)l0 | ((unsigned)l1 << 16), (unsigned)l2 | ((unsigned)l3 << 16));
}

// ---------- pre-split bf16 MFMA GEMM, 64x64 tile (4 blocks/CU) ----------
// A: Ah/Al (M,K) bf16 lda; W: Wh/Wl (N,K) bf16. C = act(A@W^T + bias) f32.
// M%64==0, N%64==0, K%32==0. 4 waves x 32x32 outputs. TRANS: C stored CT[n][m].
template<int ACT, bool TRANS>
__global__ __launch_bounds__(256) void pgemm_kernel(
    const unsigned short* __restrict__ Ah, const unsigned short* __restrict__ Al,
    const unsigned short* __restrict__ Wh, const unsigned short* __restrict__ Wl,
    const float* __restrict__ bias, float* __restrict__ C,
    int M, int N, int K, int lda)
{
    __shared__ unsigned short L[2][4][64 * 32];   // [buf][Ah,Al,Wh,Wl]
    const int tid = threadIdx.x;
    const int bm = blockIdx.y * 64, bn = blockIdx.x * 64;
    const int wv = tid >> 6, lane = tid & 63;
    const int wm = (wv & 1) * 32, wn = (wv >> 1) * 32;
    const int fr = lane & 15, fg = lane >> 4;
    const int srow = tid >> 2, scol = (tid & 3) * 8;   // LDS dst = tid*16B (linear)

    f32x4 acc[2][2];
    #pragma unroll
    for (int i = 0; i < 2; ++i)
        #pragma unroll
        for (int j = 0; j < 2; ++j) acc[i][j] = (f32x4){0.f, 0.f, 0.f, 0.f};

    const int lo = srow * 32 + scol;
    auto stage = [&](int buf, int kt) {
        const int kc = kt * 32 + scol;
        gload16(Ah + (size_t)(bm + srow) * lda + kc, &L[buf][0][lo]);
        gload16(Al + (size_t)(bm + srow) * lda + kc, &L[buf][1][lo]);
        gload16(Wh + (size_t)(bn + srow) * K + kc, &L[buf][2][lo]);
        gload16(Wl + (size_t)(bn + srow) * K + kc, &L[buf][3][lo]);
    };

    const int NT = K / 32;
    stage(0, 0);
    for (int kt = 0;;) {
        __syncthreads();                 // drains vmcnt: buf(kt) ready
        if (kt + 1 < NT) stage((kt + 1) & 1, kt + 1);
        const unsigned short* lah = &L[kt & 1][0][0];
        const unsigned short* lal = &L[kt & 1][1][0];
        const unsigned short* lbh = &L[kt & 1][2][0];
        const unsigned short* lbl = &L[kt & 1][3][0];
        bf16x8 fah[2], fal[2], fbh[2], fbl[2];
        #pragma unroll
        for (int i = 0; i < 2; ++i) {
            const int ra = (wm + i * 16 + fr) * 32 + fg * 8;
            const int rb = (wn + i * 16 + fr) * 32 + fg * 8;
            fah[i] = *(const bf16x8*)&lah[ra];
            fal[i] = *(const bf16x8*)&lal[ra];
            fbh[i] = *(const bf16x8*)&lbh[rb];
            fbl[i] = *(const bf16x8*)&lbl[rb];
        }
        #pragma unroll
        for (int i = 0; i < 2; ++i)
            #pragma unroll
            for (int j = 0; j < 2; ++j) {
                acc[i][j] = __builtin_amdgcn_mfma_f32_16x16x32_bf16(fal[i], fbh[j], acc[i][j], 0, 0, 0);
                acc[i][j] = __builtin_amdgcn_mfma_f32_16x16x32_bf16(fah[i], fbl[j], acc[i][j], 0, 0, 0);
                acc[i][j] = __builtin_amdgcn_mfma_f32_16x16x32_bf16(fah[i], fbh[j], acc[i][j], 0, 0, 0);
            }
        ++kt;
        if (kt >= NT) break;
    }

    #pragma unroll
    for (int i = 0; i < 2; ++i) {
        const int gmb = bm + wm + i * 16 + fg * 4;
        #pragma unroll
        for (int j = 0; j < 2; ++j) {
            const int gn = bn + wn + j * 16 + fr;
            const float bv = bias ? bias[gn] : 0.f;
            float4 v4;
            float* vp = &v4.x;
            #pragma unroll
            for (int r = 0; r < 4; ++r) {
                float v = acc[i][j][r] + bv;
                if (ACT == 1) v = (v > 20.f) ? v : log1pf(__expf(v));
                vp[r] = v;
            }
            if (TRANS) {
                *(float4*)&C[(size_t)gn * M + gmb] = v4;
            } else {
                #pragma unroll
                for (int r = 0; r < 4; ++r) C[(size_t)(gmb + r) * N + gn] = vp[r];
            }
        }
    }
}

// ---------- A-f32 MFMA GEMM, 64x64 tile: A converted in-kernel, W pre-split ----------
// ATRANS: A given as AT[k][m] (stride M), LDS-transposed with XOR group swizzle.
// GATE: A *= silu(Z) (Z same layout). DUAL: also emit bf16 hi/lo of C for gn<32.
template<int ACT, bool DUAL, bool GATE, bool ATRANS>
__global__ __launch_bounds__(256) void agemm_kernel(
    const float* __restrict__ A, const float* __restrict__ Z,
    const unsigned short* __restrict__ Wh, const unsigned short* __restrict__ Wl,
    const float* __restrict__ bias, float* __restrict__ C,
    unsigned short* __restrict__ dh, unsigned short* __restrict__ dl,
    int M, int N, int K, int lda)
{
    __shared__ unsigned short LAh[64 * 40];
    __shared__ unsigned short LAl[64 * 40];
    __shared__ unsigned short LBh[64 * 40];
    __shared__ unsigned short LBl[64 * 40];
    const int tid = threadIdx.x;
    const int bm = blockIdx.y * 64, bn = blockIdx.x * 64;
    const int wv = tid >> 6, lane = tid & 63;
    const int wm = (wv & 1) * 32, wn = (wv >> 1) * 32;
    const int fr = lane & 15, fg = lane >> 4;

    // B staging (row-major W): 4 threads/row x 8 ushorts
    const int srow = tid >> 2, sc = (tid & 3) * 8;
    const unsigned short* Whp = Wh + (size_t)(bn + srow) * K + sc;
    const unsigned short* Wlp = Wl + (size_t)(bn + srow) * K + sc;
    const bool wok = (bn + srow) < N;
    const uint4 zu = {0u, 0u, 0u, 0u};

    // A staging (ATRANS): k-pair kp = tid>>4 (k=2kp,2kp+1), m = mo..mo+3
    const int kp = tid >> 4;
    const int mo = (tid & 15) * 4;
    const float* At0 = ATRANS ? (A + (size_t)(2 * kp) * M + bm + mo) : nullptr;
    const float* At1 = ATRANS ? (At0 + M) : nullptr;
    const float* Zt0 = (ATRANS && GATE) ? (Z + (size_t)(2 * kp) * M + bm + mo) : nullptr;
    const float* Zt1 = (ATRANS && GATE) ? (Zt0 + M) : nullptr;
    const int swg = (kp >> 2) ^ (((tid & 15) >> 1) & 3);   // == (kp>>2) ^ ((m>>3)&3)
    const int swoff = swg * 8 + (kp & 3) * 2;
    // A staging (!ATRANS): row-major A
    const float* Ap = ATRANS ? nullptr : (A + (size_t)(bm + srow) * lda + sc);

    f32x4 acc[2][2];
    #pragma unroll
    for (int i = 0; i < 2; ++i)
        #pragma unroll
        for (int j = 0; j < 2; ++j) acc[i][j] = (f32x4){0.f, 0.f, 0.f, 0.f};

    alignas(16) float pa0[4], pa1[4], pz0[4], pz1[4];
    alignas(16) float pa[8];
    uint4 pbh, pbl;

    auto prefetch = [&](int k0) {
        if (ATRANS) {
            const size_t off = (size_t)k0 * M;
            *(float4*)&pa0[0] = *(const float4*)(At0 + off);
            *(float4*)&pa1[0] = *(const float4*)(At1 + off);
            if (GATE) {
                *(float4*)&pz0[0] = *(const float4*)(Zt0 + off);
                *(float4*)&pz1[0] = *(const float4*)(Zt1 + off);
            }
        } else {
            *(float4*)&pa[0] = *(const float4*)(Ap + k0);
            *(float4*)&pa[4] = *(const float4*)(Ap + k0 + 4);
        }
        if (wok) {
            pbh = *(const uint4*)(Whp + k0);
            pbl = *(const uint4*)(Wlp + k0);
        } else { pbh = zu; pbl = zu; }
    };

    prefetch(0);
    const int NT = K / 32;
    for (int kt = 0;;) {
        __syncthreads();
        if (ATRANS) {
            #pragma unroll
            for (int j = 0; j < 4; ++j) {
                float v0 = pa0[j], v1 = pa1[j];
                if (GATE) {
                    float z0 = pz0[j], z1 = pz1[j];
                    v0 *= z0 / (1.f + __expf(-z0));
                    v1 *= z1 / (1.f + __expf(-z1));
                }
                unsigned short h0 = f2bf(v0), h1 = f2bf(v1);
                unsigned short l0 = f2bf(v0 - bf2f(h0)), l1 = f2bf(v1 - bf2f(h1));
                const int a = (mo + j) * 40 + swoff;
                *(unsigned*)&LAh[a] = (unsigned)h0 | ((unsigned)h1 << 16);
                *(unsigned*)&LAl[a] = (unsigned)l0 | ((unsigned)l1 << 16);
            }
        } else {
            alignas(16) unsigned short hh[8], ll[8];
            #pragma unroll
            for (int i = 0; i < 8; ++i) {
                float v = pa[i];
                unsigned short h = f2bf(v);
                hh[i] = h; ll[i] = f2bf(v - bf2f(h));
            }
            const int wb = srow * 40 + sc;
            *(uint4*)&LAh[wb] = *(uint4*)&hh[0];
            *(uint4*)&LAl[wb] = *(uint4*)&ll[0];
        }
        {
            const int wb = srow * 40 + sc;
            *(uint4*)&LBh[wb] = pbh;
            *(uint4*)&LBl[wb] = pbl;
        }
        __syncthreads();
        if (kt + 1 < NT) prefetch((kt + 1) * 32);
        bf16x8 fah[2], fal[2], fbh[2], fbl[2];
        #pragma unroll
        for (int i = 0; i < 2; ++i) {
            const int mrow = wm + i * 16 + fr;
            const int g = ATRANS ? (fg ^ ((mrow >> 3) & 3)) : fg;
            const int ra = mrow * 40 + g * 8;
            fah[i] = *(const bf16x8*)&LAh[ra];
            fal[i] = *(const bf16x8*)&LAl[ra];
        }
        #pragma unroll
        for (int j = 0; j < 2; ++j) {
            const int rb = (wn + j * 16 + fr) * 40 + fg * 8;
            fbh[j] = *(const bf16x8*)&LBh[rb];
            fbl[j] = *(const bf16x8*)&LBl[rb];
        }
        #pragma unroll
        for (int i = 0; i < 2; ++i)
            #pragma unroll
            for (int j = 0; j < 2; ++j) {
                acc[i][j] = __builtin_amdgcn_mfma_f32_16x16x32_bf16(fal[i], fbh[j], acc[i][j], 0, 0, 0);
                acc[i][j] = __builtin_amdgcn_mfma_f32_16x16x32_bf16(fah[i], fbl[j], acc[i][j], 0, 0, 0);
                acc[i][j] = __builtin_amdgcn_mfma_f32_16x16x32_bf16(fah[i], fbh[j], acc[i][j], 0, 0, 0);
            }
        ++kt;
        if (kt >= NT) break;
    }

    #pragma unroll
    for (int i = 0; i < 2; ++i) {
        const int gmb = bm + wm + i * 16 + fg * 4;
        #pragma unroll
        for (int j = 0; j < 2; ++j) {
            const int gn = bn + wn + j * 16 + fr;
            if (gn >= N) continue;
            const float bv = bias ? bias[gn] : 0.f;
            #pragma unroll
            for (int r = 0; r < 4; ++r) {
                float v = acc[i][j][r] + bv;
                if (ACT == 1) v = (v > 20.f) ? v : log1pf(__expf(v));
                C[(size_t)(gmb + r) * N + gn] = v;
                if (DUAL && gn < 32) {
                    unsigned short h = f2bf(v);
                    dh[(size_t)(gmb + r) * 32 + gn] = h;
                    dl[(size_t)(gmb + r) * 32 + gn] = f2bf(v - bf2f(h));
                }
            }
        }
    }
}

// ------- reorder + split: xp(2,S,1024) -> xboth(4,S,512) bf16 hi/lo -------
__global__ __launch_bounds__(256) void reorder_split_kernel(
    const float* __restrict__ xp, unsigned short* __restrict__ xh,
    unsigned short* __restrict__ xl)
{
    int idx = blockIdx.x * 256 + threadIdx.x;
    int c4 = idx & 127;
    int t  = (idx >> 7) & 1023;
    int b4 = idx >> 17;
    float4 v;
    if (b4 < 2) v = *(const float4*)&xp[((size_t)(b4 * SEQL + t)) * DI + c4 * 4];
    else        v = *(const float4*)&xp[((size_t)((b4 - 2) * SEQL + (1023 - t))) * DI + 512 + c4 * 4];
    unsigned short h0 = f2bf(v.x), h1 = f2bf(v.y), h2 = f2bf(v.z), h3 = f2bf(v.w);
    unsigned short l0 = f2bf(v.x - bf2f(h0)), l1 = f2bf(v.y - bf2f(h1));
    unsigned short l2 = f2bf(v.z - bf2f(h2)), l3 = f2bf(v.w - bf2f(h3));
    ((uint2*)xh)[idx] = make_uint2((unsigned)h0 | ((unsigned)h1 << 16), (unsigned)h2 | ((unsigned)h3 << 16));
    ((uint2*)xl)[idx] = make_uint2((unsigned)l0 | ((unsigned)l1 << 16), (unsigned)l2 | ((unsigned)l3 << 16));
}

// ------- depthwise causal conv (k=4) + silu, T layout [d][b*1024+t] -------
__global__ __launch_bounds__(256) void conv_silu_T_kernel(
    const float* __restrict__ xinT, const float* __restrict__ cw,
    const float* __restrict__ cb, float* __restrict__ xcT)
{
    int idx = blockIdx.x * 256 + threadIdx.x;   // (d, b, t4); t4 fastest
    int t4 = idx & 255;
    int b  = (idx >> 8) & 3;
    int d  = idx >> 10;
    const float* row = xinT + (size_t)d * MT + b * 1024 + t4 * 4;
    float4 cur = *(const float4*)row;
    float p1 = 0.f, p2 = 0.f, p3 = 0.f;
    if (t4 > 0) { float4 pv = *(const float4*)(row - 4); p1 = pv.y; p2 = pv.z; p3 = pv.w; }
    float w0 = cw[d * 4 + 0], w1 = cw[d * 4 + 1], w2 = cw[d * 4 + 2], w3 = cw[d * 4 + 3];
    float bv = cb[d];
    float x0 = p1, x1 = p2, x2 = p3, x3 = cur.x, x4 = cur.y, x5 = cur.z, x6 = cur.w;
    float4 o;
    o.x = bv + w0 * x0 + w1 * x1 + w2 * x2 + w3 * x3;
    o.y = bv + w0 * x1 + w1 * x2 + w2 * x3 + w3 * x4;
    o.z = bv + w0 * x2 + w1 * x3 + w2 * x4 + w3 * x5;
    o.w = bv + w0 * x3 + w1 * x4 + w2 * x5 + w3 * x6;
    o.x *= 1.f / (1.f + __expf(-o.x));
    o.y *= 1.f / (1.f + __expf(-o.y));
    o.z *= 1.f / (1.f + __expf(-o.z));
    o.w *= 1.f / (1.f + __expf(-o.w));
    *(float4*)(xcT + (size_t)d * MT + b * 1024 + t4 * 4) = o;
}

// ============ chunked selective scan, 4 chunks of 256, T-layout dt/xc ============
__global__ __launch_bounds__(256, 4) void scan_part1(
    const float* __restrict__ dtT, const float* __restrict__ xcT,
    const float* __restrict__ xdbl, const float* __restrict__ A_log,
    float* __restrict__ Sbuf, float* __restrict__ SDbuf)
{
    const int blk = blockIdx.x;          // (bb*3 + c)*64 + dblock
    const int dblock = blk & 63;
    const int bc = blk >> 6;
    const int bb = bc / 3;
    const int c  = bc - bb * 3;
    const int wave = threadIdx.x >> 6;
    const int lane = threadIdx.x & 63;
    const int dd = lane >> 4;
    const int s4 = lane & 15;
    const int d = dblock * 16 + wave * 4 + dd;
    const float LOG2E = 1.4426950408889634f;

    float A2[4], h[4];
    #pragma unroll
    for (int k = 0; k < 4; ++k) {
        A2[k] = -__expf(A_log[d * DSTATE + s4 * 4 + k]) * LOG2E;
        h[k] = 0.f;
    }
    float sumdt = 0.f;
    const int T0 = c * 256;
    const float* dtR = dtT + (size_t)d * MT + bb * 1024 + T0;
    const float* xcR = xcT + (size_t)d * MT + bb * 1024 + T0;
    const float* Bb = xdbl + ((size_t)bb * SEQL + T0) * XDBL_N + 32 + s4 * 4;

    float4 dt0, xc0, B0[4];
    float4 dt1, xc1, B1[4];

#define L1(t0, dt_, xc_, B_)                                           \
    { dt_ = *(const float4*)(dtR + (t0));                              \
      xc_ = *(const float4*)(xcR + (t0));                              \
      _Pragma("unroll")                                                \
      for (int i = 0; i < 4; ++i)                                      \
        B_[i] = *(const float4*)(Bb + (size_t)((t0) + i) * XDBL_N); }

#define S1(dtv, xcv, Bv)                                               \
    { float dtx = (dtv) * (xcv);                                       \
      sumdt += (dtv);                                                  \
      h[0] = fmaf(fexp2((dtv) * A2[0]), h[0], dtx * Bv.x);             \
      h[1] = fmaf(fexp2((dtv) * A2[1]), h[1], dtx * Bv.y);             \
      h[2] = fmaf(fexp2((dtv) * A2[2]), h[2], dtx * Bv.z);             \
      h[3] = fmaf(fexp2((dtv) * A2[3]), h[3], dtx * Bv.w); }

#define C1(dt_, xc_, B_)                                               \
    { S1(dt_.x, xc_.x, B_[0]); S1(dt_.y, xc_.y, B_[1]);                \
      S1(dt_.z, xc_.z, B_[2]); S1(dt_.w, xc_.w, B_[3]); }

    L1(0, dt0, xc0, B0);
    for (int g = 0; g < 64; g += 2) {
        L1((g + 1) * 4, dt1, xc1, B1);
        C1(dt0, xc0, B0);
        if (g + 2 < 64) L1((g + 2) * 4, dt0, xc0, B0);
        C1(dt1, xc1, B1);
    }
#undef L1
#undef S1
#undef C1

    const size_t so = ((size_t)bc * 1024 + d) * 64 + s4 * 4;
    *(float4*)&Sbuf[so] = make_float4(h[0], h[1], h[2], h[3]);
    if (s4 == 0) SDbuf[bc * 1024 + d] = sumdt;
}

// pass 2: full scan + DPP reduce; y = p + xc*D written float4 into yT
// IN PLACE over dtT (stores trail prefetched reads; disjoint regions per block).
__global__ __launch_bounds__(256, 4) void scan_part2(
    const float* dtT, float* yT,
    const float* __restrict__ xdbl,
    const float* __restrict__ xcT,
    const float* __restrict__ A_log,
    const float* __restrict__ Dpar,
    const float* __restrict__ Sbuf,
    const float* __restrict__ SDbuf)
{
    const int blk = blockIdx.x;          // (bb*4 + c)*64 + dblock
    const int dblock = blk & 63;
    const int bc = blk >> 6;
    const int bb = bc >> 2;
    const int c  = bc & 3;
    const int wave = threadIdx.x >> 6;
    const int lane = threadIdx.x & 63;
    const int dd = lane >> 4;
    const int s4 = lane & 15;
    const int d = dblock * 16 + wave * 4 + dd;
    const float LOG2E = 1.4426950408889634f;

    float A2[4], h[4];
    #pragma unroll
    for (int k = 0; k < 4; ++k) {
        A2[k] = -__expf(A_log[d * DSTATE + s4 * 4 + k]) * LOG2E;
        h[k] = 0.f;
    }
    for (int cc = 0; cc < c; ++cc) {
        const int bcc = bb * 3 + cc;
        const size_t so = ((size_t)bcc * 1024 + d) * 64 + s4 * 4;
        float4 S = *(const float4*)&Sbuf[so];
        float sd = SDbuf[bcc * 1024 + d];
        h[0] = fmaf(fexp2(A2[0] * sd), h[0], S.x);
        h[1] = fmaf(fexp2(A2[1] * sd), h[1], S.y);
        h[2] = fmaf(fexp2(A2[2] * sd), h[2], S.z);
        h[3] = fmaf(fexp2(A2[3] * sd), h[3], S.w);
    }

    const float Dv = Dpar[d];
    const int T0 = c * 256;
    const float* dtR = dtT + (size_t)d * MT + bb * 1024 + T0;
    const float* xcR = xcT + (size_t)d * MT + bb * 1024 + T0;
    float* yR = yT + (size_t)d * MT + bb * 1024 + T0;
    const float* Bb = xdbl + ((size_t)bb * SEQL + T0) * XDBL_N + 32 + s4 * 4;

    float4 dt0, xc0, B0[4], C0[4];
    float4 dt1, xc1, B1[4], C1[4];

#define LOADC(t0, dt_, xc_, B_, C_)                                    \
    { dt_ = *(const float4*)(dtR + (t0));                              \
      xc_ = *(const float4*)(xcR + (t0));                              \
      _Pragma("unroll")                                                \
      for (int i = 0; i < 4; ++i) {                                    \
        const float* bp = Bb + (size_t)((t0) + i) * XDBL_N;            \
        B_[i] = *(const float4*)bp;                                    \
        C_[i] = *(const float4*)(bp + 64);                             \
      } }

#define STEP2(dtv, xcv, Bv, Cv, yref)                                  \
    { float dtx = (dtv) * (xcv);                                       \
      h[0] = fmaf(fexp2((dtv) * A2[0]), h[0], dtx * Bv.x);             \
      h[1] = fmaf(fexp2((dtv) * A2[1]), h[1], dtx * Bv.y);             \
      h[2] = fmaf(fexp2((dtv) * A2[2]), h[2], dtx * Bv.z);             \
      h[3] = fmaf(fexp2((dtv) * A2[3]), h[3], dtx * Bv.w);             \
      float p = h[0] * Cv.x + h[1] * Cv.y + h[2] * Cv.z + h[3] * Cv.w; \
      p = dppsum16(p);                                                 \
      yref = p + (xcv) * Dv; }

#define COMPC(t0, dt_, xc_, B_, C_)                                    \
    { float4 y4;                                                       \
      STEP2(dt_.x, xc_.x, B_[0], C_[0], y4.x);                         \
      STEP2(dt_.y, xc_.y, B_[1], C_[1], y4.y);                         \
      STEP2(dt_.z, xc_.z, B_[2], C_[2], y4.z);                         \
      STEP2(dt_.w, xc_.w, B_[3], C_[3], y4.w);                         \
      if (s4 == 0) *(float4*)(yR + (t0)) = y4; }

    LOADC(0, dt0, xc0, B0, C0);
    for (int g = 0; g < 64; g += 2) {
        LOADC((g + 1) * 4, dt1, xc1, B1, C1);
        COMPC(g * 4, dt0, xc0, B0, C0);
        if (g + 2 < 64) LOADC((g + 2) * 4, dt0, xc0, B0, C0);
        COMPC((g + 1) * 4, dt1, xc1, B1, C1);
    }
#undef LOADC
#undef STEP2
#undef COMPC
}

// ---------------- combine: out5(4,S,512) -> combined(2,S,512) ----------------
__global__ __launch_bounds__(256) void combine_kernel(
    const float* __restrict__ out5, float* __restrict__ comb)
{
    int idx = blockIdx.x * 256 + threadIdx.x;
    int c = idx & 511;
    int t = (idx >> 9) & 1023;
    int b = idx >> 19;
    float vf = out5[((size_t)(b * SEQL + t)) * 512 + c];
    float vb = out5[((size_t)((2 + b) * SEQL + (1023 - t))) * 512 + c];
    comb[idx] = vf + vb;
}

extern "C" void kernel_launch(void* const* d_in, const int* in_sizes, int n_in,
                              void* d_out, int out_size, void* d_ws, size_t ws_size,
                              hipStream_t stream)
{
    const float* x        = (const float*)d_in[0];
    const float* W_in_bi  = (const float*)d_in[1];
    const float* b_in_bi  = (const float*)d_in[2];
    const float* W_out_bi = (const float*)d_in[3];
    const float* b_out_bi = (const float*)d_in[4];
    const float* W_in     = (const float*)d_in[5];
    const float* b_in     = (const float*)d_in[6];
    const float* conv_w   = (const float*)d_in[7];
    const float* conv_b   = (const float*)d_in[8];
    const float* W_x      = (const float*)d_in[9];
    const float* W_dt     = (const float*)d_in[10];
    const float* b_dt     = (const float*)d_in[11];
    const float* A_log    = (const float*)d_in[12];
    const float* D_param  = (const float*)d_in[13];
    const float* W_out    = (const float*)d_in[14];
    const float* b_out    = (const float*)d_in[15];
    float* outp = (float*)d_out;
    char* ws = (char*)d_ws;
    const size_t MB = (size_t)1 << 20;
    typedef unsigned short us;

    // ---- regions (peak 53.55 MiB) ----
    float* zT   = (float*)(ws + 0);          // A [0,16): zT (G3 -> Gout)
    float* xp   = (float*)(ws + 0);          //   early: xp [0,8)
    us* Wbi_h   = (us*)(ws + 8 * MB);        //   early: Wbi [8,10)
    us* Wbi_l   = (us*)(ws + 9 * MB);
    us* Wbi2_h  = (us*)(ws + 0);             //   late (after Gout): W_out_bi split [0,1)
    us* Wbi2_l  = (us*)(ws + 524288);
    float* xcT  = (float*)(ws + 16 * MB);    // B [16,32): xcT (conv -> part2)
    us* xbh     = (us*)(ws + 16 * MB);       //   early: xb [16,24)
    us* xbl     = (us*)(ws + 20 * MB);
    us* Win_h   = (us*)(ws + 24 * MB);       //   early: Win [24,28)
    us* Win_l   = (us*)(ws + 26 * MB);
    float* out5 = (float*)(ws + 16 * MB);    //   late: out5 [16,24)
    us* Wout_h  = (us*)(ws + 24 * MB);       //   late: Wout [24,26)
    us* Wout_l  = (us*)(ws + 25 * MB);
    float* comb = (float*)(ws + 26 * MB);    //   late: comb [26,30)
    float* xinT = (float*)(ws + 32 * MB);    // C [32,48): xinT -> dtT/yT
    float* dtT  = (float*)(ws + 32 * MB);
    float* xdbl = (float*)(ws + 48 * MB);    // D [48,50.5)
    const size_t eb = 48 * MB + 2621440;     // E [50.5,53.55)
    us* Wx_h    = (us*)(ws + eb);
    us* Wx_l    = (us*)(ws + eb + 327680);
    us* Wdt_h   = (us*)(ws + eb + 655360);
    us* Wdt_l   = (us*)(ws + eb + 720896);
    us* dtr_h   = (us*)(ws + eb + 786432);
    us* dtr_l   = (us*)(ws + eb + 1048576);
    float* Sbuf = (float*)(ws + eb);
    float* SDb  = (float*)(ws + eb + 3145728);

    dim3 blk(256, 1, 1);

    // weight splits (Wbi2 deferred until zT region is dead)
    split_kernel<<<dim3(512), blk, 0, stream>>>(W_in_bi, Wbi_h, Wbi_l, 131072);
    split_kernel<<<dim3(1024), blk, 0, stream>>>(W_in, Win_h, Win_l, 262144);
    split_kernel<<<dim3(160), blk, 0, stream>>>(W_x, Wx_h, Wx_l, 40960);
    split_kernel<<<dim3(32), blk, 0, stream>>>(W_dt, Wdt_h, Wdt_l, 8192);

    // G1: xp = x @ W_in_bi^T + b_in_bi  (512 blocks)
    agemm_kernel<0, false, false, false><<<dim3(16, 32), blk, 0, stream>>>(
        x, nullptr, Wbi_h, Wbi_l, b_in_bi, xp, nullptr, nullptr, 2048, 1024, 512, 512);
    // reorder + split -> bf16 hi/lo
    reorder_split_kernel<<<dim3(2048), blk, 0, stream>>>(xp, xbh, xbl);
    // G2: xinT; G3: zT (transposed stores; 1024 blocks each)
    pgemm_kernel<0, true><<<dim3(16, 64), blk, 0, stream>>>(
        xbh, xbl, Win_h, Win_l, b_in, xinT, 4096, 1024, 512, 512);
    pgemm_kernel<0, true><<<dim3(16, 64), blk, 0, stream>>>(
        xbh, xbl, Win_h + 1024 * 512, Win_l + 1024 * 512, b_in + 1024, zT, 4096, 1024, 512, 512);
    // depthwise conv + silu in T layout
    conv_silu_T_kernel<<<dim3(4096), blk, 0, stream>>>(xinT, conv_w, conv_b, xcT);
    // Gx: x_dbl = xc @ W_x^T (A from xcT, transpose staged; fused dtr split)
    agemm_kernel<0, true, false, true><<<dim3(3, 64), blk, 0, stream>>>(
        xcT, nullptr, Wx_h, Wx_l, nullptr, xdbl, dtr_h, dtr_l, 4096, 160, 1024, 0);
    // Gdt: dtT = softplus(dt_raw @ W_dt^T + b_dt) (transposed store; 1024 blocks)
    pgemm_kernel<1, true><<<dim3(16, 64), blk, 0, stream>>>(
        dtr_h, dtr_l, Wdt_h, Wdt_l, b_dt, dtT, 4096, 1024, 32, 32);
    // chunked scan (4 chunks); y written in place over dtT
    scan_part1<<<dim3(768), blk, 0, stream>>>(dtT, xcT, xdbl, A_log, Sbuf, SDb);
    scan_part2<<<dim3(1024), blk, 0, stream>>>(dtT, dtT, xdbl, xcT, A_log, D_param, Sbuf, SDb);
    // W_out split, then Gout: A=yT (transpose-staged) with fused silu(zT) gate
    split_kernel<<<dim3(512), blk, 0, stream>>>(W_out, Wout_h, Wout_l, 131072);
    agemm_kernel<0, false, true, true><<<dim3(8, 64), blk, 0, stream>>>(
        dtT, zT, Wout_h, Wout_l, b_out, out5, nullptr, nullptr, 4096, 512, 1024, 0);
    // zT now dead -> split W_out_bi into [0,1) MB
    split_kernel<<<dim3(256), blk, 0, stream>>>(W_out_bi, Wbi2_h, Wbi2_l, 65536);
    // combine forward + flipped backward
    combine_kernel<<<dim3(4096), blk, 0, stream>>>(out5, comb);
    // final = combined @ W_out_bi^T + b_out_bi (split-bf16 MFMA; 256 blocks)
    agemm_kernel<0, false, false, false><<<dim3(8, 32), blk, 0, stream>>>(
        comb, nullptr, Wbi2_h, Wbi2_l, b_out_bi, outp, nullptr, nullptr, 2048, 512, 512, 512);
}